// Round 3
// baseline (2625.085 us; speedup 1.0000x reference)
//
#include <hip/hip_runtime.h>
#include <hip/hip_bf16.h>
#include <math.h>

#define D_MODEL 1024
#define SEQ_L   2048
#define BATCH   2
#define NSTATE  16
#define DCONV   4
#define DINNER  2048
#define DTRANK  64
#define ETA_C   0.1f
#define DECAY_C 0.95f
#define EPS_C   1e-5f
#define MTOK    (BATCH*SEQ_L)   // 4096

// ---------------- rmsnorm: one block per row, D=1024 = 256 threads * float4 ----
__global__ __launch_bounds__(256)
void rmsnorm_kernel(const float* __restrict__ in, const float* __restrict__ w,
                    float* __restrict__ out)
{
    int row = blockIdx.x;
    int t = threadIdx.x;
    const float4* ip = (const float4*)(in + (size_t)row * D_MODEL);
    float4 v = ip[t];
    float ss = v.x*v.x + v.y*v.y + v.z*v.z + v.w*v.w;
    #pragma unroll
    for (int m = 1; m < 64; m <<= 1) ss += __shfl_xor(ss, m);
    __shared__ float red[4];
    if ((t & 63) == 0) red[t >> 6] = ss;
    __syncthreads();
    float total = red[0] + red[1] + red[2] + red[3];
    float sc = rsqrtf(total * (1.0f / D_MODEL) + EPS_C);
    float4 wv = ((const float4*)w)[t];
    float4 o;
    o.x = v.x * sc * wv.x; o.y = v.y * sc * wv.y;
    o.z = v.z * sc * wv.z; o.w = v.w * sc * wv.w;
    ((float4*)(out + (size_t)row * D_MODEL))[t] = o;
}

// ---------------- depthwise causal conv (DC=4) + silu ------------------------
// xm = xz[:, 0:DINNER] of row stride 2*DINNER
__global__ __launch_bounds__(256)
void conv_silu_kernel(const float* __restrict__ xz, const float* __restrict__ cw,
                      const float* __restrict__ cb, float* __restrict__ u)
{
    int idx = blockIdx.x * 256 + threadIdx.x;       // B*L*DI = 2^23
    int d = idx & (DINNER - 1);
    int l = (idx >> 11) & (SEQ_L - 1);
    int b = idx >> 22;
    const float* base = xz + ((size_t)b * SEQ_L) * (2*DINNER) + d;
    float s = cb[d];
    #pragma unroll
    for (int j = 0; j < DCONV; ++j) {
        int lj = l - (DCONV-1) + j;
        if (lj >= 0) s += cw[d*DCONV + j] * base[(size_t)lj * (2*DINNER)];
    }
    u[idx] = s / (1.0f + expf(-s));
}

// ---------------- selective scan: thread = (b,d,s); 16-lane reduce for y -----
// dty: input dt [B,L,DI]; overwritten in place with y. Safe because the s==0
// lane's store to (t,d) is after all 16 lanes of the same lockstep group read
// dt(t,d), and no other group touches that location.
__global__ __launch_bounds__(256)
void scan_kernel(float* dty, const float* __restrict__ u,
                 const float* __restrict__ xdbl, const float* __restrict__ A_log)
{
    int tid = blockIdx.x * 256 + threadIdx.x;       // B*DI*16 = 65536
    int s = tid & 15;
    int d = (tid >> 4) & (DINNER - 1);
    int b = tid >> 15;
    float A = -expf(A_log[d * NSTATE + s]);
    float* dtp = dty + (size_t)b * SEQ_L * DINNER + d;
    const float* up  = u  + (size_t)b * SEQ_L * DINNER + d;
    const float* xdp = xdbl + (size_t)b * SEQ_L * 96;
    float h = 0.0f;
    for (int t = 0; t < SEQ_L; ++t) {
        float dtv = dtp[(size_t)t * DINNER];
        float uv  = up [(size_t)t * DINNER];
        float Bv  = xdp[t * 96 + DTRANK + s];
        float Cv  = xdp[t * 96 + DTRANK + NSTATE + s];
        h = h * __expf(dtv * A) + dtv * uv * Bv;
        float yv = h * Cv;
        yv += __shfl_xor(yv, 1);
        yv += __shfl_xor(yv, 2);
        yv += __shfl_xor(yv, 4);
        yv += __shfl_xor(yv, 8);
        if (s == 0) dtp[(size_t)t * DINNER] = yv;
    }
}

// ---------------- y = (y + u*D) * silu(z) ------------------------------------
__global__ __launch_bounds__(256)
void gate_kernel(float* __restrict__ y, const float* __restrict__ u,
                 const float* __restrict__ Dp, const float* __restrict__ xz)
{
    int idx = blockIdx.x * 256 + threadIdx.x;       // B*L*DI
    int d = idx & (DINNER - 1);
    int row = idx >> 11;
    float z = xz[(size_t)row * (2*DINNER) + DINNER + d];
    float yv = y[idx] + u[idx] * Dp[d];
    y[idx] = yv * (z / (1.0f + expf(-z)));
}

// ---------------- scores *= ETA * DECAY^(t-1-s) * (s<t) ----------------------
__global__ __launch_bounds__(256)
void decay_weight_kernel(float* __restrict__ sc)
{
    long long idx = (long long)blockIdx.x * 256 + threadIdx.x;   // B*L*L
    int s = (int)(idx & (SEQ_L - 1));
    int t = (int)((idx >> 11) & (SEQ_L - 1));
    float w = 0.0f;
    if (s < t) w = ETA_C * exp2f((float)(t - 1 - s) * -0.07400058144377693f); // log2(0.95)
    sc[idx] *= w;
}

// ---------------- generic tiled f32 GEMM -------------------------------------
// C[m,n] = sum_k A[m,k] * Beff[n,k];  Beff[n,k] = TRANSB ? B[n,k] : B[k,n]
// EPI: 0 = store, 1 = softplus(acc + bias[n]), 2 = Src[m,n] + scale*acc
#define BM 64
#define BN 64
#define BK 16

template<int TRANSB, int EPI>
__global__ __launch_bounds__(256)
void gemm_kernel(const float* __restrict__ A, int lda, long long sA,
                 const float* __restrict__ B, int ldb, long long sB,
                 float* __restrict__ C, int ldc, long long sC,
                 int M, int N, int K,
                 const float* __restrict__ bias,
                 const float* __restrict__ Src, int ldsrc, long long sSrc,
                 float scale)
{
    __shared__ float As[BK][BM + 4];
    __shared__ float Bs[BK][BN + 4];
    int bz = blockIdx.z;
    A += bz * sA; B += bz * sB; C += bz * sC;
    if (EPI == 2) Src += bz * sSrc;
    int m0 = blockIdx.y * BM, n0 = blockIdx.x * BN;
    int t = threadIdx.x;
    int tx = t & 15, ty = t >> 4;
    int rA = t >> 2, c4 = (t & 3) << 2;        // A/B-NT loader: row, 4-col
    int kB = t >> 4, nB4 = (t & 15) << 2;      // B-NN loader
    float acc[4][4] = {};
    for (int k0 = 0; k0 < K; k0 += BK) {
        float4 av = make_float4(0.f,0.f,0.f,0.f);
        if (m0 + rA < M) av = *(const float4*)(A + (size_t)(m0 + rA) * lda + k0 + c4);
        As[c4+0][rA] = av.x; As[c4+1][rA] = av.y; As[c4+2][rA] = av.z; As[c4+3][rA] = av.w;
        if (TRANSB) {
            float4 bv = make_float4(0.f,0.f,0.f,0.f);
            if (n0 + rA < N) bv = *(const float4*)(B + (size_t)(n0 + rA) * ldb + k0 + c4);
            Bs[c4+0][rA] = bv.x; Bs[c4+1][rA] = bv.y; Bs[c4+2][rA] = bv.z; Bs[c4+3][rA] = bv.w;
        } else {
            float4 bv = make_float4(0.f,0.f,0.f,0.f);
            if (n0 + nB4 < N) bv = *(const float4*)(B + (size_t)(k0 + kB) * ldb + n0 + nB4);
            *(float4*)&Bs[kB][nB4] = bv;
        }
        __syncthreads();
        #pragma unroll
        for (int kk = 0; kk < BK; ++kk) {
            float4 a4 = *(const float4*)&As[kk][ty << 2];
            float4 b4 = *(const float4*)&Bs[kk][tx << 2];
            float a[4] = {a4.x, a4.y, a4.z, a4.w};
            float b[4] = {b4.x, b4.y, b4.z, b4.w};
            #pragma unroll
            for (int i = 0; i < 4; ++i)
                #pragma unroll
                for (int j = 0; j < 4; ++j)
                    acc[i][j] = fmaf(a[i], b[j], acc[i][j]);
        }
        __syncthreads();
    }
    #pragma unroll
    for (int i = 0; i < 4; ++i) {
        int m = m0 + (ty << 2) + i;
        if (m >= M) continue;
        #pragma unroll
        for (int j = 0; j < 4; ++j) {
            int n = n0 + (tx << 2) + j;
            if (n >= N) continue;
            float v = acc[i][j];
            if (EPI == 1) {
                float xv = v + bias[n];
                v = fmaxf(xv, 0.0f) + log1pf(expf(-fabsf(xv)));   // stable softplus
            } else if (EPI == 2) {
                v = Src[(size_t)m * ldsrc + n] + scale * v;
            }
            C[(size_t)m * ldc + n] = v;
        }
    }
}

extern "C" void kernel_launch(void* const* d_in, const int* in_sizes, int n_in,
                              void* d_out, int out_size, void* d_ws, size_t ws_size,
                              hipStream_t stream)
{
    const float* x        = (const float*)d_in[0];
    const float* norm_w   = (const float*)d_in[1];
    const float* in_proj  = (const float*)d_in[2];
    const float* conv_w   = (const float*)d_in[3];
    const float* conv_b   = (const float*)d_in[4];
    const float* x_proj   = (const float*)d_in[5];
    const float* dt_projw = (const float*)d_in[6];
    const float* dt_projb = (const float*)d_in[7];
    const float* A_log    = (const float*)d_in[8];
    const float* D_param  = (const float*)d_in[9];
    const float* out_proj = (const float*)d_in[10];
    const float* hebb_w   = (const float*)d_in[11];
    const float* Wk       = (const float*)d_in[12];
    const float* Wv       = (const float*)d_in[13];
    float* out = (float*)d_out;

    // workspace layout (floats): xn 4M | xz 16M | u 8M | xdbl 0.5M | dtb(y) 8M
    // After gate+out_proj, xz is dead -> kb/vb/scores pack into it.
    float* ws   = (float*)d_ws;
    float* xn   = ws;
    float* xz   = xn   + (size_t)4*1024*1024;
    float* u    = xz   + (size_t)16*1024*1024;
    float* xdbl = u    + (size_t)8*1024*1024;
    float* dtb  = xdbl + (size_t)512*1024;      // dt -> (in place) y -> dead -> scores? no: scores below
    float* kb   = xz;                           // 4M
    float* vb   = xz + (size_t)4*1024*1024;     // 4M
    float* scb  = xz + (size_t)8*1024*1024;     // 8M (scores, B*L*L)
    size_t need = ((size_t)(4+16+8+8)*1024*1024 + 512*1024) * sizeof(float); // ~146 MB
    if (ws_size < need) return;   // insufficient scratch: bail (will show as incorrect)

    dim3 blk(256);
    const long long LD = (long long)SEQ_L * D_MODEL;   // 2097152
    const long long LL = (long long)SEQ_L * SEQ_L;     // 4194304

    // 1. xn = rmsnorm(x, norm_w)
    rmsnorm_kernel<<<MTOK, blk, 0, stream>>>(x, norm_w, xn);
    // 2. xz = xn @ in_proj^T   [4096 x 4096, K=1024]
    gemm_kernel<1,0><<<dim3((2*DINNER)/BN, MTOK/BM, 1), blk, 0, stream>>>(
        xn, D_MODEL, 0, in_proj, D_MODEL, 0, xz, 2*DINNER, 0,
        MTOK, 2*DINNER, D_MODEL, nullptr, nullptr, 0, 0, 0.f);
    // 3. u = silu(depthwise_causal_conv(xm) + conv_b)
    conv_silu_kernel<<<(MTOK*DINNER)/256, blk, 0, stream>>>(xz, conv_w, conv_b, u);
    // 4. xdbl = u @ x_proj^T   [4096 x 96, K=2048]
    gemm_kernel<1,0><<<dim3(2, MTOK/BM, 1), blk, 0, stream>>>(
        u, DINNER, 0, x_proj, DINNER, 0, xdbl, 96, 0,
        MTOK, 96, DINNER, nullptr, nullptr, 0, 0, 0.f);
    // 5. dt = softplus(xdbl[:, :64] @ dt_proj^T + dt_proj_b)   [4096 x 2048, K=64]
    gemm_kernel<1,1><<<dim3(DINNER/BN, MTOK/BM, 1), blk, 0, stream>>>(
        xdbl, 96, 0, dt_projw, DTRANK, 0, dtb, DINNER, 0,
        MTOK, DINNER, DTRANK, dt_projb, nullptr, 0, 0, 0.f);
    // 6. selective scan: dtb (dt) -> dtb (y), in place
    scan_kernel<<<(BATCH*DINNER*NSTATE)/256, blk, 0, stream>>>(dtb, u, xdbl, A_log);
    // 7. y = (y + u*D_param) * silu(z)   (y lives in dtb)
    gate_kernel<<<(MTOK*DINNER)/256, blk, 0, stream>>>(dtb, u, D_param, xz);
    // 8. out = x + y @ out_proj^T   [4096 x 1024, K=2048]
    gemm_kernel<1,2><<<dim3(D_MODEL/BN, MTOK/BM, 1), blk, 0, stream>>>(
        dtb, DINNER, 0, out_proj, DINNER, 0, out, D_MODEL, 0,
        MTOK, D_MODEL, DINNER, nullptr, x, D_MODEL, 0, 1.0f);
    // 9. xn = rmsnorm(out, hebb_w)
    rmsnorm_kernel<<<MTOK, blk, 0, stream>>>(out, hebb_w, xn);
    // 10. k = xn @ Wk, v = xn @ Wv   (NN)  [4096 x 1024, K=1024]
    gemm_kernel<0,0><<<dim3(D_MODEL/BN, MTOK/BM, 1), blk, 0, stream>>>(
        xn, D_MODEL, 0, Wk, D_MODEL, 0, kb, D_MODEL, 0,
        MTOK, D_MODEL, D_MODEL, nullptr, nullptr, 0, 0, 0.f);
    gemm_kernel<0,0><<<dim3(D_MODEL/BN, MTOK/BM, 1), blk, 0, stream>>>(
        xn, D_MODEL, 0, Wv, D_MODEL, 0, vb, D_MODEL, 0,
        MTOK, D_MODEL, D_MODEL, nullptr, nullptr, 0, 0, 0.f);
    // 11. scores[b] = xn[b] @ k[b]^T   [2048 x 2048, K=1024], batched over b
    gemm_kernel<1,0><<<dim3(SEQ_L/BN, SEQ_L/BM, BATCH), blk, 0, stream>>>(
        xn, D_MODEL, LD, kb, D_MODEL, LD, scb, SEQ_L, LL,
        SEQ_L, SEQ_L, D_MODEL, nullptr, nullptr, 0, 0, 0.f);
    // 12. scores *= ETA * DECAY^(t-1-s) * (s<t)
    decay_weight_kernel<<<(int)((BATCH*LL)/256), blk, 0, stream>>>(scb);
    // 13. out += scores @ v   (NN) [2048 x 1024, K=2048], batched over b
    gemm_kernel<0,2><<<dim3(D_MODEL/BN, SEQ_L/BM, BATCH), blk, 0, stream>>>(
        scb, SEQ_L, LL, vb, D_MODEL, LD, out, D_MODEL, LD,
        SEQ_L, D_MODEL, SEQ_L, nullptr, out, D_MODEL, LD, 1.0f);
}

// Round 4
// 952.555 us; speedup vs baseline: 2.7558x; 2.7558x over previous
//
#include <hip/hip_runtime.h>
#include <hip/hip_bf16.h>
#include <math.h>

#define D_MODEL 1024
#define SEQ_L   2048
#define BATCH   2
#define NSTATE  16
#define DCONV   4
#define DINNER  2048
#define DTRANK  64
#define ETA_C   0.1f
#define DECAY_C 0.95f
#define EPS_C   1e-5f
#define MTOK    (BATCH*SEQ_L)   // 4096
#define LOG2_DECAY (-0.07400058144377693f)

typedef unsigned short u16;
typedef __attribute__((ext_vector_type(8))) short bf16x8;
typedef __attribute__((ext_vector_type(4))) float f32x4;

__device__ inline u16 f2b(float f) {
    __hip_bfloat16 h = __float2bfloat16(f);
    return *reinterpret_cast<u16*>(&h);
}
__device__ inline float silu_f(float z) { return z / (1.0f + expf(-z)); }

// ---------------- rmsnorm -> bf16 out: one block per row ---------------------
__global__ __launch_bounds__(256)
void rmsnorm_b_kernel(const float* __restrict__ in, const float* __restrict__ w,
                      u16* __restrict__ outb)
{
    int row = blockIdx.x;
    int t = threadIdx.x;
    const float4* ip = (const float4*)(in + (size_t)row * D_MODEL);
    float4 v = ip[t];
    float ss = v.x*v.x + v.y*v.y + v.z*v.z + v.w*v.w;
    #pragma unroll
    for (int m = 1; m < 64; m <<= 1) ss += __shfl_xor(ss, m);
    __shared__ float red[4];
    if ((t & 63) == 0) red[t >> 6] = ss;
    __syncthreads();
    float total = red[0] + red[1] + red[2] + red[3];
    float sc = rsqrtf(total * (1.0f / D_MODEL) + EPS_C);
    float4 wv = ((const float4*)w)[t];
    ushort4 o;
    o.x = f2b(v.x * sc * wv.x); o.y = f2b(v.y * sc * wv.y);
    o.z = f2b(v.z * sc * wv.z); o.w = f2b(v.w * sc * wv.w);
    ((ushort4*)(outb + (size_t)row * D_MODEL))[t] = o;
}

// ---------------- plain f32 -> bf16 convert (vector4) ------------------------
__global__ __launch_bounds__(256)
void cvt_bf16_kernel(const float* __restrict__ in, u16* __restrict__ out, int n4)
{
    int i = blockIdx.x * 256 + threadIdx.x;
    if (i >= n4) return;
    float4 v = *(const float4*)(in + (size_t)i * 4);
    ushort4 o; o.x = f2b(v.x); o.y = f2b(v.y); o.z = f2b(v.z); o.w = f2b(v.w);
    *(ushort4*)(out + (size_t)i * 4) = o;
}

// ---------------- tiled transpose -> bf16 (f32 or bf16 input) ----------------
__device__ inline u16 to_b16(float v) { return f2b(v); }
__device__ inline u16 to_b16(u16 v)   { return v; }

template<typename TIN>
__global__ __launch_bounds__(256)
void transpose_b16_kernel(const TIN* __restrict__ in, u16* __restrict__ outT,
                          int R, int C, long long sIn, long long sOut)
{
    __shared__ u16 tile[32][34];
    in   += (size_t)blockIdx.z * sIn;
    outT += (size_t)blockIdx.z * sOut;
    int c0 = blockIdx.x * 32, r0 = blockIdx.y * 32;
    int tx = threadIdx.x & 31, ty = threadIdx.x >> 5;   // ty 0..7
    #pragma unroll
    for (int i = 0; i < 4; ++i)
        tile[ty + 8*i][tx] = to_b16(in[(size_t)(r0 + ty + 8*i) * C + c0 + tx]);
    __syncthreads();
    #pragma unroll
    for (int i = 0; i < 4; ++i)
        outT[(size_t)(c0 + ty + 8*i) * R + r0 + tx] = tile[tx][ty + 8*i];
}

// ---------------- depthwise causal conv (DC=4) + silu ------------------------
__global__ __launch_bounds__(256)
void conv_silu_kernel(const float* __restrict__ xz, const float* __restrict__ cw,
                      const float* __restrict__ cb, float* __restrict__ u)
{
    int idx = blockIdx.x * 256 + threadIdx.x;       // B*L*DI
    int d = idx & (DINNER - 1);
    int l = (idx >> 11) & (SEQ_L - 1);
    int b = idx >> 22;
    const float* base = xz + ((size_t)b * SEQ_L) * (2*DINNER) + d;
    float s = cb[d];
    #pragma unroll
    for (int j = 0; j < DCONV; ++j) {
        int lj = l - (DCONV-1) + j;
        if (lj >= 0) s += cw[d*DCONV + j] * base[(size_t)lj * (2*DINNER)];
    }
    u[idx] = s / (1.0f + expf(-s));
}

// ---------------- chunked selective scan (3 passes) --------------------------
// h_t = a_t h_{t-1} + b_t with a = exp(dt*A), b = dt*u*B. NC=16 chunks of 128.
#define NCHUNK 16
#define CHLEN  128

__global__ __launch_bounds__(256)
void scanA_kernel(const float* __restrict__ dt, const float* __restrict__ u,
                  const float* __restrict__ xdbl, const float* __restrict__ A_log,
                  float* __restrict__ P, float* __restrict__ c)
{
    int flat = blockIdx.x * 256 + threadIdx.x;      // B*DI*16 = 65536
    int chunk = blockIdx.y;
    int s = flat & 15;
    int d = (flat >> 4) & (DINNER - 1);
    int b = flat >> 15;
    float A = -expf(A_log[d * NSTATE + s]);
    const float* dtp = dt + (size_t)b * SEQ_L * DINNER + d;
    const float* up  = u  + (size_t)b * SEQ_L * DINNER + d;
    const float* xdp = xdbl + (size_t)b * SEQ_L * 96;
    float Pv = 1.0f, cv = 0.0f;
    int t0 = chunk * CHLEN;
    for (int t = t0; t < t0 + CHLEN; ++t) {
        float dtv = dtp[(size_t)t * DINNER];
        float uv  = up [(size_t)t * DINNER];
        float Bv  = xdp[t * 96 + DTRANK + s];
        float a = __expf(dtv * A);
        Pv *= a;
        cv = cv * a + dtv * uv * Bv;
    }
    P[(size_t)chunk * 65536 + flat] = Pv;
    c[(size_t)chunk * 65536 + flat] = cv;
}

__global__ __launch_bounds__(256)
void scanB_kernel(const float* __restrict__ P, const float* __restrict__ c,
                  float* __restrict__ hst)
{
    int flat = blockIdx.x * 256 + threadIdx.x;      // 65536
    float h = 0.0f;
    #pragma unroll
    for (int ch = 0; ch < NCHUNK; ++ch) {
        hst[(size_t)ch * 65536 + flat] = h;
        h = P[(size_t)ch * 65536 + flat] * h + c[(size_t)ch * 65536 + flat];
    }
}

// pass C: recompute locally, write y over dt in place (16-lane group owns (d,t))
__global__ __launch_bounds__(256)
void scanC_kernel(float* dty, const float* __restrict__ u,
                  const float* __restrict__ xdbl, const float* __restrict__ A_log,
                  const float* __restrict__ hst)
{
    int flat = blockIdx.x * 256 + threadIdx.x;      // 65536
    int chunk = blockIdx.y;
    int s = flat & 15;
    int d = (flat >> 4) & (DINNER - 1);
    int b = flat >> 15;
    float A = -expf(A_log[d * NSTATE + s]);
    float* dtp = dty + (size_t)b * SEQ_L * DINNER + d;
    const float* up  = u  + (size_t)b * SEQ_L * DINNER + d;
    const float* xdp = xdbl + (size_t)b * SEQ_L * 96;
    float h = hst[(size_t)chunk * 65536 + flat];
    int t0 = chunk * CHLEN;
    for (int t = t0; t < t0 + CHLEN; ++t) {
        float dtv = dtp[(size_t)t * DINNER];
        float uv  = up [(size_t)t * DINNER];
        float Bv  = xdp[t * 96 + DTRANK + s];
        float Cv  = xdp[t * 96 + DTRANK + NSTATE + s];
        h = h * __expf(dtv * A) + dtv * uv * Bv;
        float yv = h * Cv;
        yv += __shfl_xor(yv, 1);
        yv += __shfl_xor(yv, 2);
        yv += __shfl_xor(yv, 4);
        yv += __shfl_xor(yv, 8);
        if (s == 0) dtp[(size_t)t * DINNER] = yv;
    }
}

// ---------------- y = (y + u*D) * silu(z) -> bf16 ----------------------------
__global__ __launch_bounds__(256)
void gate_b_kernel(const float* __restrict__ y, const float* __restrict__ u,
                   const float* __restrict__ Dp, const float* __restrict__ xz,
                   u16* __restrict__ yb)
{
    int i4 = blockIdx.x * 256 + threadIdx.x;        // B*L*DI/4 = 2M
    int d4 = (i4 & 511) << 2;
    int row = i4 >> 9;
    float4 yv = *(const float4*)(y + (size_t)i4 * 4);
    float4 uv = *(const float4*)(u + (size_t)i4 * 4);
    float4 zv = *(const float4*)(xz + (size_t)row * (2*DINNER) + DINNER + d4);
    float4 dv = *(const float4*)(Dp + d4);
    ushort4 o;
    o.x = f2b((yv.x + uv.x * dv.x) * silu_f(zv.x));
    o.y = f2b((yv.y + uv.y * dv.y) * silu_f(zv.y));
    o.z = f2b((yv.z + uv.z * dv.z) * silu_f(zv.z));
    o.w = f2b((yv.w + uv.w * dv.w) * silu_f(zv.w));
    *(ushort4*)(yb + (size_t)i4 * 4) = o;
}

// ---------------- f32 tiled GEMM (kept for x_proj / dt_proj) -----------------
#define BM 64
#define BN 64
#define BK 16

template<int TRANSB, int EPI>   // EPI: 0 = store, 1 = softplus(acc+bias)
__global__ __launch_bounds__(256)
void gemm_kernel(const float* __restrict__ A, int lda,
                 const float* __restrict__ B, int ldb,
                 float* __restrict__ C, int ldc,
                 int M, int N, int K, const float* __restrict__ bias)
{
    __shared__ float As[BK][BM + 4];
    __shared__ float Bs[BK][BN + 4];
    int m0 = blockIdx.y * BM, n0 = blockIdx.x * BN;
    int t = threadIdx.x;
    int tx = t & 15, ty = t >> 4;
    int rA = t >> 2, c4 = (t & 3) << 2;
    float acc[4][4] = {};
    for (int k0 = 0; k0 < K; k0 += BK) {
        float4 av = make_float4(0.f,0.f,0.f,0.f);
        if (m0 + rA < M) av = *(const float4*)(A + (size_t)(m0 + rA) * lda + k0 + c4);
        As[c4+0][rA] = av.x; As[c4+1][rA] = av.y; As[c4+2][rA] = av.z; As[c4+3][rA] = av.w;
        float4 bv = make_float4(0.f,0.f,0.f,0.f);
        if (n0 + rA < N) bv = *(const float4*)(B + (size_t)(n0 + rA) * ldb + k0 + c4);
        Bs[c4+0][rA] = bv.x; Bs[c4+1][rA] = bv.y; Bs[c4+2][rA] = bv.z; Bs[c4+3][rA] = bv.w;
        __syncthreads();
        #pragma unroll
        for (int kk = 0; kk < BK; ++kk) {
            float4 a4 = *(const float4*)&As[kk][ty << 2];
            float4 b4 = *(const float4*)&Bs[kk][tx << 2];
            float a[4] = {a4.x, a4.y, a4.z, a4.w};
            float b[4] = {b4.x, b4.y, b4.z, b4.w};
            #pragma unroll
            for (int i = 0; i < 4; ++i)
                #pragma unroll
                for (int j = 0; j < 4; ++j)
                    acc[i][j] = fmaf(a[i], b[j], acc[i][j]);
        }
        __syncthreads();
    }
    #pragma unroll
    for (int i = 0; i < 4; ++i) {
        int m = m0 + (ty << 2) + i;
        if (m >= M) continue;
        #pragma unroll
        for (int j = 0; j < 4; ++j) {
            int n = n0 + (tx << 2) + j;
            if (n >= N) continue;
            float v = acc[i][j];
            if (EPI == 1) {
                float xv = v + bias[n];
                v = fmaxf(xv, 0.0f) + log1pf(expf(-fabsf(xv)));
            }
            C[(size_t)m * ldc + n] = v;
        }
    }
}

// ---------------- bf16 MFMA NT GEMM ------------------------------------------
// C[m,n] = sum_k A[m,k]*B[n,k], A:[M,K] bf16 row-major, B:[N,K] bf16 row-major.
// 128x128 tile, 256 thr = 4 waves (2x2 of 64x64), BK=64, padded LDS (stride 72).
// EPI: 0 = f32 store, 1 = bf16 store, 2 = f32 Src+acc store,
//      3 = bf16 store of acc * decay_mask(m,n)  (for scores)
#define LDSK 72

template<int EPI>
__global__ __launch_bounds__(256)
void mfma_nt_kernel(const u16* __restrict__ A, int lda, long long sA,
                    const u16* __restrict__ B, int ldb, long long sB,
                    float* __restrict__ Cf, u16* __restrict__ Cb, int ldc, long long sC,
                    int K, const float* __restrict__ Src)
{
    __shared__ u16 As[128][LDSK];
    __shared__ u16 Bs[128][LDSK];
    int bz = blockIdx.z;
    A += (size_t)bz * sA; B += (size_t)bz * sB;
    if (EPI == 1 || EPI == 3) Cb += (size_t)bz * sC; else Cf += (size_t)bz * sC;
    if (EPI == 2) Src += (size_t)bz * sC;
    int m0 = blockIdx.y * 128, n0 = blockIdx.x * 128;
    int t = threadIdx.x;
    int lane = t & 63, w = t >> 6;
    int wm = (w >> 1) * 64, wn = (w & 1) * 64;
    int l15 = lane & 15, lhi = lane >> 4;

    f32x4 acc[4][4] = {};
    uint4 ra[4], rb[4];
    const int nk = K >> 6;

    #pragma unroll
    for (int q = 0; q < 4; ++q) {
        int cidx = q * 256 + t, row = cidx >> 3, j = cidx & 7;
        ra[q] = *(const uint4*)(A + (size_t)(m0 + row) * lda + j * 8);
        rb[q] = *(const uint4*)(B + (size_t)(n0 + row) * ldb + j * 8);
    }
    for (int kt = 0; kt < nk; ++kt) {
        __syncthreads();
        #pragma unroll
        for (int q = 0; q < 4; ++q) {
            int cidx = q * 256 + t, row = cidx >> 3, j = cidx & 7;
            *(uint4*)&As[row][j * 8] = ra[q];
            *(uint4*)&Bs[row][j * 8] = rb[q];
        }
        __syncthreads();
        if (kt + 1 < nk) {
            int k0 = (kt + 1) << 6;
            #pragma unroll
            for (int q = 0; q < 4; ++q) {
                int cidx = q * 256 + t, row = cidx >> 3, j = cidx & 7;
                ra[q] = *(const uint4*)(A + (size_t)(m0 + row) * lda + k0 + j * 8);
                rb[q] = *(const uint4*)(B + (size_t)(n0 + row) * ldb + k0 + j * 8);
            }
        }
        #pragma unroll
        for (int ks = 0; ks < 2; ++ks) {
            bf16x8 af[4], bfr[4];
            #pragma unroll
            for (int f = 0; f < 4; ++f) {
                af[f]  = *(const bf16x8*)&As[wm + f*16 + l15][ks*32 + lhi*8];
                bfr[f] = *(const bf16x8*)&Bs[wn + f*16 + l15][ks*32 + lhi*8];
            }
            #pragma unroll
            for (int i = 0; i < 4; ++i)
                #pragma unroll
                for (int j = 0; j < 4; ++j)
                    acc[i][j] = __builtin_amdgcn_mfma_f32_16x16x32_bf16(
                                    af[i], bfr[j], acc[i][j], 0, 0, 0);
        }
    }
    // epilogue: C[r][c], c = lane&15, r = 4*(lane>>4)+i  [m89-verified]
    int rb0 = m0 + wm + lhi * 4;
    int cb0 = n0 + wn + l15;
    #pragma unroll
    for (int mf = 0; mf < 4; ++mf) {
        #pragma unroll
        for (int nf = 0; nf < 4; ++nf) {
            #pragma unroll
            for (int i = 0; i < 4; ++i) {
                int r = rb0 + mf * 16 + i;
                int cc = cb0 + nf * 16;
                float v = acc[mf][nf][i];
                if (EPI == 0) {
                    Cf[(size_t)r * ldc + cc] = v;
                } else if (EPI == 1) {
                    Cb[(size_t)r * ldc + cc] = f2b(v);
                } else if (EPI == 2) {
                    Cf[(size_t)r * ldc + cc] = Src[(size_t)r * ldc + cc] + v;
                } else { // 3: decay-weighted causal mask
                    float wv = (cc < r) ? ETA_C * exp2f((float)(r - 1 - cc) * LOG2_DECAY) : 0.0f;
                    Cb[(size_t)r * ldc + cc] = f2b(v * wv);
                }
            }
        }
    }
}

extern "C" void kernel_launch(void* const* d_in, const int* in_sizes, int n_in,
                              void* d_out, int out_size, void* d_ws, size_t ws_size,
                              hipStream_t stream)
{
    const float* x        = (const float*)d_in[0];
    const float* norm_w   = (const float*)d_in[1];
    const float* in_proj  = (const float*)d_in[2];
    const float* conv_w   = (const float*)d_in[3];
    const float* conv_b   = (const float*)d_in[4];
    const float* x_proj   = (const float*)d_in[5];
    const float* dt_projw = (const float*)d_in[6];
    const float* dt_projb = (const float*)d_in[7];
    const float* A_log    = (const float*)d_in[8];
    const float* D_param  = (const float*)d_in[9];
    const float* out_proj = (const float*)d_in[10];
    const float* hebb_w   = (const float*)d_in[11];
    const float* Wk       = (const float*)d_in[12];
    const float* Wv       = (const float*)d_in[13];
    float* out = (float*)d_out;

    // ---- workspace layout (float units, M1 = 1Mi floats) ----
    // [0,2M):  xnb bf16 (steps 1-3) -> opb bf16 [0,1M) + hst [1M,2M) (later)
    // [2M,18M): xz f32 -> after gate: xnb2/kb16/vb16/vT16/scb16/wkT/wvT (bf16)
    // [18M,26M): u f32
    // [26M,26.5M): xdbl f32
    // [26.5M,34.5M): dtb f32 (ipb bf16 lives here before dt_proj writes)
    // [34.5M,35.5M): P   [35.5M,36.5M): c
    // [36.5M,40.5M): ybb bf16
    float* ws = (float*)d_ws;
    const size_t M1 = 1024 * 1024;
    u16*   xnb  = (u16*)ws;
    u16*   opb  = (u16*)ws;
    float* hst  = ws + M1;
    float* xz   = ws + 2*M1;
    u16*   xnb2 = (u16*)(ws + 2*M1);
    u16*   kb16 = (u16*)(ws + 4*M1);
    u16*   vb16 = (u16*)(ws + 6*M1);
    u16*   vT16 = (u16*)(ws + 8*M1);
    u16*   scb16= (u16*)(ws + 10*M1);
    u16*   wkT  = (u16*)(ws + 14*M1);
    u16*   wvT  = (u16*)(ws + 14*M1 + M1/2);
    float* ubuf = ws + 18*M1;
    float* xdbl = ws + 26*M1;
    float* dtb  = ws + 26*M1 + M1/2;
    u16*   ipb  = (u16*)dtb;
    float* Pbuf = ws + 34*M1 + M1/2;
    float* cbuf = ws + 35*M1 + M1/2;
    u16*   ybb  = (u16*)(ws + 36*M1 + M1/2);
    size_t need = (40*M1 + M1/2) * sizeof(float);   // 162 MiB
    if (ws_size < need) return;

    dim3 blk(256);
    const long long LD  = (long long)SEQ_L * D_MODEL;   // 2M
    const long long LDI = (long long)SEQ_L * DINNER;    // 4M
    const long long LL  = (long long)SEQ_L * SEQ_L;     // 4M

    // 1. xnb = bf16(rmsnorm(x))
    rmsnorm_b_kernel<<<MTOK, blk, 0, stream>>>(x, norm_w, xnb);
    // 2. ipb = bf16(in_proj_w)  (4M elems)
    cvt_bf16_kernel<<<(2*DINNER*D_MODEL/4 + 255)/256, blk, 0, stream>>>(in_proj, ipb, 2*DINNER*D_MODEL/4);
    // 3. xz = xnb @ ipb^T  [4096x4096, K=1024] f32
    mfma_nt_kernel<0><<<dim3(32, 32, 1), blk, 0, stream>>>(
        xnb, D_MODEL, 0, ipb, D_MODEL, 0, xz, nullptr, 2*DINNER, 0, D_MODEL, nullptr);
    // 4. u = silu(conv(xm)+b)
    conv_silu_kernel<<<(MTOK*DINNER)/256, blk, 0, stream>>>(xz, conv_w, conv_b, ubuf);
    // 5. xdbl = u @ x_proj^T  [4096x96, K=2048] f32
    gemm_kernel<1,0><<<dim3(2, MTOK/BM, 1), blk, 0, stream>>>(
        ubuf, DINNER, x_proj, DINNER, xdbl, 96, MTOK, 96, DINNER, nullptr);
    // 6. dt = softplus(xdbl[:,:64] @ dt_proj^T + b)  [4096x2048, K=64] f32
    gemm_kernel<1,1><<<dim3(DINNER/BN, MTOK/BM, 1), blk, 0, stream>>>(
        xdbl, 96, dt_projw, DTRANK, dtb, DINNER, MTOK, DINNER, DTRANK, dt_projb);
    // 7. chunked selective scan: dtb(dt) -> dtb(y)
    scanA_kernel<<<dim3(256, NCHUNK), blk, 0, stream>>>(dtb, ubuf, xdbl, A_log, Pbuf, cbuf);
    scanB_kernel<<<256, blk, 0, stream>>>(Pbuf, cbuf, hst);
    scanC_kernel<<<dim3(256, NCHUNK), blk, 0, stream>>>(dtb, ubuf, xdbl, A_log, hst);
    // 8. ybb = bf16((y + u*D) * silu(z))
    gate_b_kernel<<<(MTOK*DINNER/4)/256, blk, 0, stream>>>(dtb, ubuf, D_param, xz, ybb);
    // 8b. opb = bf16(out_proj_w); wkT/wvT = bf16(Wk^T / Wv^T)
    cvt_bf16_kernel<<<(D_MODEL*DINNER/4 + 255)/256, blk, 0, stream>>>(out_proj, opb, D_MODEL*DINNER/4);
    transpose_b16_kernel<float><<<dim3(32, 32, 1), blk, 0, stream>>>(Wk, wkT, D_MODEL, D_MODEL, 0, 0);
    transpose_b16_kernel<float><<<dim3(32, 32, 1), blk, 0, stream>>>(Wv, wvT, D_MODEL, D_MODEL, 0, 0);
    // 9. out = x + ybb @ opb^T  [4096x1024, K=2048]
    mfma_nt_kernel<2><<<dim3(8, 32, 1), blk, 0, stream>>>(
        ybb, DINNER, 0, opb, DINNER, 0, out, nullptr, D_MODEL, 0, DINNER, x);
    // 10. xnb2 = bf16(rmsnorm(out))
    rmsnorm_b_kernel<<<MTOK, blk, 0, stream>>>(out, hebb_w, xnb2);
    // 11. kb16 = xnb2 @ wkT^T  (= xn @ Wk)  [4096x1024, K=1024] bf16
    mfma_nt_kernel<1><<<dim3(8, 32, 1), blk, 0, stream>>>(
        xnb2, D_MODEL, 0, wkT, D_MODEL, 0, nullptr, kb16, D_MODEL, 0, D_MODEL, nullptr);
    // 12. vb16 = xnb2 @ wvT^T  [4096x1024, K=1024] bf16
    mfma_nt_kernel<1><<<dim3(8, 32, 1), blk, 0, stream>>>(
        xnb2, D_MODEL, 0, wvT, D_MODEL, 0, nullptr, vb16, D_MODEL, 0, D_MODEL, nullptr);
    // 13. vT16[b] = vb16[b]^T  ([2048x1024] -> [1024x2048])
    transpose_b16_kernel<u16><<<dim3(32, 64, BATCH), blk, 0, stream>>>(
        vb16, vT16, SEQ_L, D_MODEL, LD, LD);
    // 14. scb16[b] = decay_mask .* (xnb2[b] @ kb16[b]^T)  [2048x2048, K=1024] bf16
    mfma_nt_kernel<3><<<dim3(16, 16, BATCH), blk, 0, stream>>>(
        xnb2, D_MODEL, LD, kb16, D_MODEL, LD, nullptr, scb16, SEQ_L, LL, D_MODEL, nullptr);
    // 15. out[b] += scb16[b] @ vT16[b]^T  [2048x1024, K=2048]
    mfma_nt_kernel<2><<<dim3(8, 16, BATCH), blk, 0, stream>>>(
        scb16, SEQ_L, LL, vT16, SEQ_L, LD, out, nullptr, D_MODEL, LD, SEQ_L, out);
}

// Round 5
// 648.667 us; speedup vs baseline: 4.0469x; 1.4685x over previous
//
#include <hip/hip_runtime.h>
#include <hip/hip_bf16.h>
#include <math.h>

#define D_MODEL 1024
#define SEQ_L   2048
#define BATCH   2
#define NSTATE  16
#define DCONV   4
#define DINNER  2048
#define DTRANK  64
#define ETA_C   0.1f
#define DECAY_C 0.95f
#define EPS_C   1e-5f
#define MTOK    (BATCH*SEQ_L)   // 4096
#define LOG2_DECAY (-0.07400058144377693f)

typedef unsigned short u16;
typedef __attribute__((ext_vector_type(8))) short bf16x8;
typedef __attribute__((ext_vector_type(4))) float f32x4;

__device__ inline u16 f2b(float f) {
    __hip_bfloat16 h = __float2bfloat16(f);
    return *reinterpret_cast<u16*>(&h);
}
__device__ inline float silu_f(float z) { return z / (1.0f + expf(-z)); }

// global->LDS direct DMA, 16B per lane. LDS dest = wave-uniform base + lane*16.
#define GLL16(gsrc, ldst) \
    __builtin_amdgcn_global_load_lds((const __attribute__((address_space(1))) void*)(gsrc), \
                                     (__attribute__((address_space(3))) void*)(ldst), 16, 0, 0)

// ---------------- rmsnorm -> bf16 out: one block per row ---------------------
__global__ __launch_bounds__(256)
void rmsnorm_b_kernel(const float* __restrict__ in, const float* __restrict__ w,
                      u16* __restrict__ outb)
{
    int row = blockIdx.x;
    int t = threadIdx.x;
    const float4* ip = (const float4*)(in + (size_t)row * D_MODEL);
    float4 v = ip[t];
    float ss = v.x*v.x + v.y*v.y + v.z*v.z + v.w*v.w;
    #pragma unroll
    for (int m = 1; m < 64; m <<= 1) ss += __shfl_xor(ss, m);
    __shared__ float red[4];
    if ((t & 63) == 0) red[t >> 6] = ss;
    __syncthreads();
    float total = red[0] + red[1] + red[2] + red[3];
    float sc = rsqrtf(total * (1.0f / D_MODEL) + EPS_C);
    float4 wv = ((const float4*)w)[t];
    ushort4 o;
    o.x = f2b(v.x * sc * wv.x); o.y = f2b(v.y * sc * wv.y);
    o.z = f2b(v.z * sc * wv.z); o.w = f2b(v.w * sc * wv.w);
    ((ushort4*)(outb + (size_t)row * D_MODEL))[t] = o;
}

// ---------------- plain f32 -> bf16 convert (vector4) ------------------------
__global__ __launch_bounds__(256)
void cvt_bf16_kernel(const float* __restrict__ in, u16* __restrict__ out, int n4)
{
    int i = blockIdx.x * 256 + threadIdx.x;
    if (i >= n4) return;
    float4 v = *(const float4*)(in + (size_t)i * 4);
    ushort4 o; o.x = f2b(v.x); o.y = f2b(v.y); o.z = f2b(v.z); o.w = f2b(v.w);
    *(ushort4*)(out + (size_t)i * 4) = o;
}

// ---------------- tiled transpose -> bf16 (f32 or bf16 input) ----------------
__device__ inline u16 to_b16(float v) { return f2b(v); }
__device__ inline u16 to_b16(u16 v)   { return v; }

template<typename TIN>
__global__ __launch_bounds__(256)
void transpose_b16_kernel(const TIN* __restrict__ in, u16* __restrict__ outT,
                          int R, int C, long long sIn, long long sOut)
{
    __shared__ u16 tile[32][34];
    in   += (size_t)blockIdx.z * sIn;
    outT += (size_t)blockIdx.z * sOut;
    int c0 = blockIdx.x * 32, r0 = blockIdx.y * 32;
    int tx = threadIdx.x & 31, ty = threadIdx.x >> 5;   // ty 0..7
    #pragma unroll
    for (int i = 0; i < 4; ++i)
        tile[ty + 8*i][tx] = to_b16(in[(size_t)(r0 + ty + 8*i) * C + c0 + tx]);
    __syncthreads();
    #pragma unroll
    for (int i = 0; i < 4; ++i)
        outT[(size_t)(c0 + ty + 8*i) * R + r0 + tx] = tile[tx][ty + 8*i];
}

// ---------------- depthwise causal conv (DC=4) + silu ------------------------
__global__ __launch_bounds__(256)
void conv_silu_kernel(const float* __restrict__ xz, const float* __restrict__ cw,
                      const float* __restrict__ cb, float* __restrict__ u)
{
    int idx = blockIdx.x * 256 + threadIdx.x;       // B*L*DI
    int d = idx & (DINNER - 1);
    int l = (idx >> 11) & (SEQ_L - 1);
    int b = idx >> 22;
    const float* base = xz + ((size_t)b * SEQ_L) * (2*DINNER) + d;
    float s = cb[d];
    #pragma unroll
    for (int j = 0; j < DCONV; ++j) {
        int lj = l - (DCONV-1) + j;
        if (lj >= 0) s += cw[d*DCONV + j] * base[(size_t)lj * (2*DINNER)];
    }
    u[idx] = s / (1.0f + expf(-s));
}

// ---------------- chunked selective scan (3 passes) --------------------------
#define NCHUNK 16
#define CHLEN  128

__global__ __launch_bounds__(256)
void scanA_kernel(const float* __restrict__ dt, const float* __restrict__ u,
                  const float* __restrict__ xdbl, const float* __restrict__ A_log,
                  float* __restrict__ P, float* __restrict__ c)
{
    int flat = blockIdx.x * 256 + threadIdx.x;      // B*DI*16 = 65536
    int chunk = blockIdx.y;
    int s = flat & 15;
    int d = (flat >> 4) & (DINNER - 1);
    int b = flat >> 15;
    float A = -expf(A_log[d * NSTATE + s]);
    const float* dtp = dt + (size_t)b * SEQ_L * DINNER + d;
    const float* up  = u  + (size_t)b * SEQ_L * DINNER + d;
    const float* xdp = xdbl + (size_t)b * SEQ_L * 96;
    float Pv = 1.0f, cv = 0.0f;
    int t0 = chunk * CHLEN;
    for (int t = t0; t < t0 + CHLEN; ++t) {
        float dtv = dtp[(size_t)t * DINNER];
        float uv  = up [(size_t)t * DINNER];
        float Bv  = xdp[t * 96 + DTRANK + s];
        float a = __expf(dtv * A);
        Pv *= a;
        cv = cv * a + dtv * uv * Bv;
    }
    P[(size_t)chunk * 65536 + flat] = Pv;
    c[(size_t)chunk * 65536 + flat] = cv;
}

__global__ __launch_bounds__(256)
void scanB_kernel(const float* __restrict__ P, const float* __restrict__ c,
                  float* __restrict__ hst)
{
    int flat = blockIdx.x * 256 + threadIdx.x;      // 65536
    float h = 0.0f;
    #pragma unroll
    for (int ch = 0; ch < NCHUNK; ++ch) {
        hst[(size_t)ch * 65536 + flat] = h;
        h = P[(size_t)ch * 65536 + flat] * h + c[(size_t)ch * 65536 + flat];
    }
}

__global__ __launch_bounds__(256)
void scanC_kernel(float* dty, const float* __restrict__ u,
                  const float* __restrict__ xdbl, const float* __restrict__ A_log,
                  const float* __restrict__ hst)
{
    int flat = blockIdx.x * 256 + threadIdx.x;      // 65536
    int chunk = blockIdx.y;
    int s = flat & 15;
    int d = (flat >> 4) & (DINNER - 1);
    int b = flat >> 15;
    float A = -expf(A_log[d * NSTATE + s]);
    float* dtp = dty + (size_t)b * SEQ_L * DINNER + d;
    const float* up  = u  + (size_t)b * SEQ_L * DINNER + d;
    const float* xdp = xdbl + (size_t)b * SEQ_L * 96;
    float h = hst[(size_t)chunk * 65536 + flat];
    int t0 = chunk * CHLEN;
    for (int t = t0; t < t0 + CHLEN; ++t) {
        float dtv = dtp[(size_t)t * DINNER];
        float uv  = up [(size_t)t * DINNER];
        float Bv  = xdp[t * 96 + DTRANK + s];
        float Cv  = xdp[t * 96 + DTRANK + NSTATE + s];
        h = h * __expf(dtv * A) + dtv * uv * Bv;
        float yv = h * Cv;
        yv += __shfl_xor(yv, 1);
        yv += __shfl_xor(yv, 2);
        yv += __shfl_xor(yv, 4);
        yv += __shfl_xor(yv, 8);
        if (s == 0) dtp[(size_t)t * DINNER] = yv;
    }
}

// ---------------- y = (y + u*D) * silu(z) -> bf16 ----------------------------
__global__ __launch_bounds__(256)
void gate_b_kernel(const float* __restrict__ y, const float* __restrict__ u,
                   const float* __restrict__ Dp, const float* __restrict__ xz,
                   u16* __restrict__ yb)
{
    int i4 = blockIdx.x * 256 + threadIdx.x;        // B*L*DI/4 = 2M
    int d4 = (i4 & 511) << 2;
    int row = i4 >> 9;
    float4 yv = *(const float4*)(y + (size_t)i4 * 4);
    float4 uv = *(const float4*)(u + (size_t)i4 * 4);
    float4 zv = *(const float4*)(xz + (size_t)row * (2*DINNER) + DINNER + d4);
    float4 dv = *(const float4*)(Dp + d4);
    ushort4 o;
    o.x = f2b((yv.x + uv.x * dv.x) * silu_f(zv.x));
    o.y = f2b((yv.y + uv.y * dv.y) * silu_f(zv.y));
    o.z = f2b((yv.z + uv.z * dv.z) * silu_f(zv.z));
    o.w = f2b((yv.w + uv.w * dv.w) * silu_f(zv.w));
    *(ushort4*)(yb + (size_t)i4 * 4) = o;
}

// ---------------- f32 tiled GEMM (kept for x_proj / dt_proj) -----------------
#define BM 64
#define BN 64
#define BK 16

template<int TRANSB, int EPI>   // EPI: 0 = store, 1 = softplus(acc+bias)
__global__ __launch_bounds__(256)
void gemm_kernel(const float* __restrict__ A, int lda,
                 const float* __restrict__ B, int ldb,
                 float* __restrict__ C, int ldc,
                 int M, int N, int K, const float* __restrict__ bias)
{
    __shared__ float As[BK][BM + 4];
    __shared__ float Bs[BK][BN + 4];
    int m0 = blockIdx.y * BM, n0 = blockIdx.x * BN;
    int t = threadIdx.x;
    int tx = t & 15, ty = t >> 4;
    int rA = t >> 2, c4 = (t & 3) << 2;
    float acc[4][4] = {};
    for (int k0 = 0; k0 < K; k0 += BK) {
        float4 av = make_float4(0.f,0.f,0.f,0.f);
        if (m0 + rA < M) av = *(const float4*)(A + (size_t)(m0 + rA) * lda + k0 + c4);
        As[c4+0][rA] = av.x; As[c4+1][rA] = av.y; As[c4+2][rA] = av.z; As[c4+3][rA] = av.w;
        float4 bv = make_float4(0.f,0.f,0.f,0.f);
        if (n0 + rA < N) bv = *(const float4*)(B + (size_t)(n0 + rA) * ldb + k0 + c4);
        Bs[c4+0][rA] = bv.x; Bs[c4+1][rA] = bv.y; Bs[c4+2][rA] = bv.z; Bs[c4+3][rA] = bv.w;
        __syncthreads();
        #pragma unroll
        for (int kk = 0; kk < BK; ++kk) {
            float4 a4 = *(const float4*)&As[kk][ty << 2];
            float4 b4 = *(const float4*)&Bs[kk][tx << 2];
            float a[4] = {a4.x, a4.y, a4.z, a4.w};
            float b[4] = {b4.x, b4.y, b4.z, b4.w};
            #pragma unroll
            for (int i = 0; i < 4; ++i)
                #pragma unroll
                for (int j = 0; j < 4; ++j)
                    acc[i][j] = fmaf(a[i], b[j], acc[i][j]);
        }
        __syncthreads();
    }
    #pragma unroll
    for (int i = 0; i < 4; ++i) {
        int m = m0 + (ty << 2) + i;
        if (m >= M) continue;
        #pragma unroll
        for (int j = 0; j < 4; ++j) {
            int n = n0 + (tx << 2) + j;
            if (n >= N) continue;
            float v = acc[i][j];
            if (EPI == 1) {
                float xv = v + bias[n];
                v = fmaxf(xv, 0.0f) + log1pf(expf(-fabsf(xv)));
            }
            C[(size_t)m * ldc + n] = v;
        }
    }
}

// ---------------- bf16 MFMA NT GEMM (m97 structure) --------------------------
// C[m,n] = sum_k A[m,k]*B[n,k], A:[M,K] bf16 row-major, B:[N,K] bf16 row-major.
// 128x128 tile, 256 thr = 4 waves (2x2 of 64x64), BK=64.
// Staging: global_load_lds dwordx4, linear LDS [128][64] u16, source column
// pre-swizzled by ((row&7)<<3) u16; ds_read applies the same XOR (m173/m201).
// M, N must be multiples of 128; K multiple of 64 (true for all call sites).
// EPI: 0 = f32 store, 1 = bf16 store, 2 = f32 Src+acc store,
//      3 = bf16 store of acc * decay_mask(m,n)  (for scores)
template<int EPI>
__global__ __launch_bounds__(256)
void mfma_nt_kernel(const u16* __restrict__ A, int lda, long long sA,
                    const u16* __restrict__ B, int ldb, long long sB,
                    float* __restrict__ Cf, u16* __restrict__ Cb, int ldc, long long sC,
                    int K, const float* __restrict__ Src)
{
    __shared__ u16 As[128 * 64];
    __shared__ u16 Bs[128 * 64];
    int bz = blockIdx.z;
    A += (size_t)bz * sA; B += (size_t)bz * sB;
    if (EPI == 1 || EPI == 3) Cb += (size_t)bz * sC; else Cf += (size_t)bz * sC;
    if (EPI == 2) Src += (size_t)bz * sC;
    int m0 = blockIdx.y * 128, n0 = blockIdx.x * 128;
    int t = threadIdx.x;
    int lane = t & 63, w = t >> 6;
    int wm = (w >> 1) * 64, wn = (w & 1) * 64;
    int l15 = lane & 15, lhi = lane >> 4;

    // staging geometry: chunk c (0..15) = rows 8c..8c+7; lane l -> row 8c+(l>>3),
    // LDS u16 col (l&7)*8; global col pre-swizzled so swizzled reads see identity.
    int lrow = lane >> 3;                                   // 0..7
    int scol = ((lane & 7) ^ lrow) << 3;                    // pre-swizzled source col (u16)

    f32x4 acc[4][4] = {};
    const int nk = K >> 6;

    for (int kt = 0; kt < nk; ++kt) {
        int kb = kt << 6;
        #pragma unroll
        for (int q = 0; q < 4; ++q) {
            int c = (q << 2) + w;                           // chunk 0..15
            int row = (c << 3) + lrow;
            GLL16(A + (size_t)(m0 + row) * lda + kb + scol, &As[c << 9]);
            GLL16(B + (size_t)(n0 + row) * ldb + kb + scol, &Bs[c << 9]);
        }
        __syncthreads();   // compiler drains vmcnt before barrier
        #pragma unroll
        for (int ks = 0; ks < 2; ++ks) {
            int csw = (ks * 32 + lhi * 8) ^ ((l15 & 7) << 3);  // swizzled u16 col
            bf16x8 af[4], bfr[4];
            #pragma unroll
            for (int f = 0; f < 4; ++f) {
                af[f]  = *(const bf16x8*)&As[(wm + f*16 + l15) * 64 + csw];
                bfr[f] = *(const bf16x8*)&Bs[(wn + f*16 + l15) * 64 + csw];
            }
            #pragma unroll
            for (int i = 0; i < 4; ++i)
                #pragma unroll
                for (int j = 0; j < 4; ++j)
                    acc[i][j] = __builtin_amdgcn_mfma_f32_16x16x32_bf16(
                                    af[i], bfr[j], acc[i][j], 0, 0, 0);
        }
        __syncthreads();
    }
    // epilogue: C[r][c], c = lane&15, r = 4*(lane>>4)+i  [m89-verified]
    int rb0 = m0 + wm + lhi * 4;
    int cb0 = n0 + wn + l15;
    #pragma unroll
    for (int mf = 0; mf < 4; ++mf) {
        #pragma unroll
        for (int nf = 0; nf < 4; ++nf) {
            #pragma unroll
            for (int i = 0; i < 4; ++i) {
                int r = rb0 + mf * 16 + i;
                int cc = cb0 + nf * 16;
                float v = acc[mf][nf][i];
                if (EPI == 0) {
                    Cf[(size_t)r * ldc + cc] = v;
                } else if (EPI == 1) {
                    Cb[(size_t)r * ldc + cc] = f2b(v);
                } else if (EPI == 2) {
                    Cf[(size_t)r * ldc + cc] = Src[(size_t)r * ldc + cc] + v;
                } else { // 3: decay-weighted causal mask
                    float wv = (cc < r) ? ETA_C * exp2f((float)(r - 1 - cc) * LOG2_DECAY) : 0.0f;
                    Cb[(size_t)r * ldc + cc] = f2b(v * wv);
                }
            }
        }
    }
}

extern "C" void kernel_launch(void* const* d_in, const int* in_sizes, int n_in,
                              void* d_out, int out_size, void* d_ws, size_t ws_size,
                              hipStream_t stream)
{
    const float* x        = (const float*)d_in[0];
    const float* norm_w   = (const float*)d_in[1];
    const float* in_proj  = (const float*)d_in[2];
    const float* conv_w   = (const float*)d_in[3];
    const float* conv_b   = (const float*)d_in[4];
    const float* x_proj   = (const float*)d_in[5];
    const float* dt_projw = (const float*)d_in[6];
    const float* dt_projb = (const float*)d_in[7];
    const float* A_log    = (const float*)d_in[8];
    const float* D_param  = (const float*)d_in[9];
    const float* out_proj = (const float*)d_in[10];
    const float* hebb_w   = (const float*)d_in[11];
    const float* Wk       = (const float*)d_in[12];
    const float* Wv       = (const float*)d_in[13];
    float* out = (float*)d_out;

    // ---- workspace layout (float units, M1 = 1Mi floats) ----
    float* ws = (float*)d_ws;
    const size_t M1 = 1024 * 1024;
    u16*   xnb  = (u16*)ws;
    u16*   opb  = (u16*)ws;
    float* hst  = ws + M1;
    float* xz   = ws + 2*M1;
    u16*   xnb2 = (u16*)(ws + 2*M1);
    u16*   kb16 = (u16*)(ws + 4*M1);
    u16*   vb16 = (u16*)(ws + 6*M1);
    u16*   vT16 = (u16*)(ws + 8*M1);
    u16*   scb16= (u16*)(ws + 10*M1);
    u16*   wkT  = (u16*)(ws + 14*M1);
    u16*   wvT  = (u16*)(ws + 14*M1 + M1/2);
    float* ubuf = ws + 18*M1;
    float* xdbl = ws + 26*M1;
    float* dtb  = ws + 26*M1 + M1/2;
    u16*   ipb  = (u16*)dtb;
    float* Pbuf = ws + 34*M1 + M1/2;
    float* cbuf = ws + 35*M1 + M1/2;
    u16*   ybb  = (u16*)(ws + 36*M1 + M1/2);
    size_t need = (40*M1 + M1/2) * sizeof(float);   // 162 MiB
    if (ws_size < need) return;

    dim3 blk(256);
    const long long LD  = (long long)SEQ_L * D_MODEL;   // 2M
    const long long LL  = (long long)SEQ_L * SEQ_L;     // 4M

    // 1. xnb = bf16(rmsnorm(x))
    rmsnorm_b_kernel<<<MTOK, blk, 0, stream>>>(x, norm_w, xnb);
    // 2. ipb = bf16(in_proj_w)  (4M elems)
    cvt_bf16_kernel<<<(2*DINNER*D_MODEL/4 + 255)/256, blk, 0, stream>>>(in_proj, ipb, 2*DINNER*D_MODEL/4);
    // 3. xz = xnb @ ipb^T  [4096x4096, K=1024] f32
    mfma_nt_kernel<0><<<dim3(32, 32, 1), blk, 0, stream>>>(
        xnb, D_MODEL, 0, ipb, D_MODEL, 0, xz, nullptr, 2*DINNER, 0, D_MODEL, nullptr);
    // 4. u = silu(conv(xm)+b)
    conv_silu_kernel<<<(MTOK*DINNER)/256, blk, 0, stream>>>(xz, conv_w, conv_b, ubuf);
    // 5. xdbl = u @ x_proj^T  [4096x96, K=2048] f32
    gemm_kernel<1,0><<<dim3(2, MTOK/BM, 1), blk, 0, stream>>>(
        ubuf, DINNER, x_proj, DINNER, xdbl, 96, MTOK, 96, DINNER, nullptr);
    // 6. dt = softplus(xdbl[:,:64] @ dt_proj^T + b)  [4096x2048, K=64] f32
    gemm_kernel<1,1><<<dim3(DINNER/BN, MTOK/BM, 1), blk, 0, stream>>>(
        xdbl, 96, dt_projw, DTRANK, dtb, DINNER, MTOK, DINNER, DTRANK, dt_projb);
    // 7. chunked selective scan: dtb(dt) -> dtb(y)
    scanA_kernel<<<dim3(256, NCHUNK), blk, 0, stream>>>(dtb, ubuf, xdbl, A_log, Pbuf, cbuf);
    scanB_kernel<<<256, blk, 0, stream>>>(Pbuf, cbuf, hst);
    scanC_kernel<<<dim3(256, NCHUNK), blk, 0, stream>>>(dtb, ubuf, xdbl, A_log, hst);
    // 8. ybb = bf16((y + u*D) * silu(z))
    gate_b_kernel<<<(MTOK*DINNER/4)/256, blk, 0, stream>>>(dtb, ubuf, D_param, xz, ybb);
    // 8b. opb = bf16(out_proj_w); wkT/wvT = bf16(Wk^T / Wv^T)
    cvt_bf16_kernel<<<(D_MODEL*DINNER/4 + 255)/256, blk, 0, stream>>>(out_proj, opb, D_MODEL*DINNER/4);
    transpose_b16_kernel<float><<<dim3(32, 32, 1), blk, 0, stream>>>(Wk, wkT, D_MODEL, D_MODEL, 0, 0);
    transpose_b16_kernel<float><<<dim3(32, 32, 1), blk, 0, stream>>>(Wv, wvT, D_MODEL, D_MODEL, 0, 0);
    // 9. out = x + ybb @ opb^T  [4096x1024, K=2048]
    mfma_nt_kernel<2><<<dim3(8, 32, 1), blk, 0, stream>>>(
        ybb, DINNER, 0, opb, DINNER, 0, out, nullptr, D_MODEL, 0, DINNER, x);
    // 10. xnb2 = bf16(rmsnorm(out))
    rmsnorm_b_kernel<<<MTOK, blk, 0, stream>>>(out, hebb_w, xnb2);
    // 11. kb16 = xnb2 @ wkT^T  (= xn @ Wk)  [4096x1024, K=1024] bf16
    mfma_nt_kernel<1><<<dim3(8, 32, 1), blk, 0, stream>>>(
        xnb2, D_MODEL, 0, wkT, D_MODEL, 0, nullptr, kb16, D_MODEL, 0, D_MODEL, nullptr);
    // 12. vb16 = xnb2 @ wvT^T  [4096x1024, K=1024] bf16
    mfma_nt_kernel<1><<<dim3(8, 32, 1), blk, 0, stream>>>(
        xnb2, D_MODEL, 0, wvT, D_MODEL, 0, nullptr, vb16, D_MODEL, 0, D_MODEL, nullptr);
    // 13. vT16[b] = vb16[b]^T  ([2048x1024] -> [1024x2048])
    transpose_b16_kernel<u16><<<dim3(32, 64, BATCH), blk, 0, stream>>>(
        vb16, vT16, SEQ_L, D_MODEL, LD, LD);
    // 14. scb16[b] = decay_mask .* (xnb2[b] @ kb16[b]^T)  [2048x2048, K=1024] bf16
    mfma_nt_kernel<3><<<dim3(16, 16, BATCH), blk, 0, stream>>>(
        xnb2, D_MODEL, LD, kb16, D_MODEL, LD, nullptr, scb16, SEQ_L, LL, D_MODEL, nullptr);
    // 15. out[b] += scb16[b] @ vT16[b]^T  [2048x1024, K=2048]
    mfma_nt_kernel<2><<<dim3(8, 16, BATCH), blk, 0, stream>>>(
        scb16, SEQ_L, LL, vT16, SEQ_L, LD, out, nullptr, D_MODEL, LD, SEQ_L, out);
}

// Round 7
// 536.477 us; speedup vs baseline: 4.8932x; 1.2091x over previous
//
#include <hip/hip_runtime.h>
#include <hip/hip_bf16.h>
#include <math.h>

#define D_MODEL 1024
#define SEQ_L   2048
#define BATCH   2
#define NSTATE  16
#define DCONV   4
#define DINNER  2048
#define DTRANK  64
#define ETA_C   0.1f
#define DECAY_C 0.95f
#define EPS_C   1e-5f
#define MTOK    (BATCH*SEQ_L)   // 4096
#define LOG2_DECAY (-0.07400058144377693f)

typedef unsigned short u16;
typedef __attribute__((ext_vector_type(8))) short bf16x8;
typedef __attribute__((ext_vector_type(4))) float f32x4;

__device__ inline u16 f2b(float f) {
    __hip_bfloat16 h = __float2bfloat16(f);
    return *reinterpret_cast<u16*>(&h);
}
__device__ inline float silu_f(float z) { return z / (1.0f + expf(-z)); }

// global->LDS direct DMA, 16B per lane. LDS dest = wave-uniform base + lane*16.
#define GLL16(gsrc, ldst) \
    __builtin_amdgcn_global_load_lds((const __attribute__((address_space(1))) void*)(gsrc), \
                                     (__attribute__((address_space(3))) void*)(ldst), 16, 0, 0)

// ---------------- rmsnorm -> bf16 out: one block per row ---------------------
__global__ __launch_bounds__(256)
void rmsnorm_b_kernel(const float* __restrict__ in, const float* __restrict__ w,
                      u16* __restrict__ outb)
{
    int row = blockIdx.x;
    int t = threadIdx.x;
    const float4* ip = (const float4*)(in + (size_t)row * D_MODEL);
    float4 v = ip[t];
    float ss = v.x*v.x + v.y*v.y + v.z*v.z + v.w*v.w;
    #pragma unroll
    for (int m = 1; m < 64; m <<= 1) ss += __shfl_xor(ss, m);
    __shared__ float red[4];
    if ((t & 63) == 0) red[t >> 6] = ss;
    __syncthreads();
    float total = red[0] + red[1] + red[2] + red[3];
    float sc = rsqrtf(total * (1.0f / D_MODEL) + EPS_C);
    float4 wv = ((const float4*)w)[t];
    ushort4 o;
    o.x = f2b(v.x * sc * wv.x); o.y = f2b(v.y * sc * wv.y);
    o.z = f2b(v.z * sc * wv.z); o.w = f2b(v.w * sc * wv.w);
    ((ushort4*)(outb + (size_t)row * D_MODEL))[t] = o;
}

// ---------------- plain f32 -> bf16 convert (vector4) ------------------------
__global__ __launch_bounds__(256)
void cvt_bf16_kernel(const float* __restrict__ in, u16* __restrict__ out, int n4)
{
    int i = blockIdx.x * 256 + threadIdx.x;
    if (i >= n4) return;
    float4 v = *(const float4*)(in + (size_t)i * 4);
    ushort4 o; o.x = f2b(v.x); o.y = f2b(v.y); o.z = f2b(v.z); o.w = f2b(v.w);
    *(ushort4*)(out + (size_t)i * 4) = o;
}

// ---------------- tiled transpose -> bf16 (f32 or bf16 input) ----------------
__device__ inline u16 to_b16(float v) { return f2b(v); }
__device__ inline u16 to_b16(u16 v)   { return v; }

template<typename TIN>
__global__ __launch_bounds__(256)
void transpose_b16_kernel(const TIN* __restrict__ in, u16* __restrict__ outT,
                          int R, int C, long long sIn, long long sOut)
{
    __shared__ u16 tile[32][34];
    in   += (size_t)blockIdx.z * sIn;
    outT += (size_t)blockIdx.z * sOut;
    int c0 = blockIdx.x * 32, r0 = blockIdx.y * 32;
    int tx = threadIdx.x & 31, ty = threadIdx.x >> 5;   // ty 0..7
    #pragma unroll
    for (int i = 0; i < 4; ++i)
        tile[ty + 8*i][tx] = to_b16(in[(size_t)(r0 + ty + 8*i) * C + c0 + tx]);
    __syncthreads();
    #pragma unroll
    for (int i = 0; i < 4; ++i)
        outT[(size_t)(c0 + ty + 8*i) * R + r0 + tx] = tile[tx][ty + 8*i];
}

// ---------------- depthwise causal conv (DC=4) + silu ------------------------
__global__ __launch_bounds__(256)
void conv_silu_kernel(const float* __restrict__ xz, const float* __restrict__ cw,
                      const float* __restrict__ cb, float* __restrict__ u)
{
    int idx = blockIdx.x * 256 + threadIdx.x;       // B*L*DI
    int d = idx & (DINNER - 1);
    int l = (idx >> 11) & (SEQ_L - 1);
    int b = idx >> 22;
    const float* base = xz + ((size_t)b * SEQ_L) * (2*DINNER) + d;
    float s = cb[d];
    #pragma unroll
    for (int j = 0; j < DCONV; ++j) {
        int lj = l - (DCONV-1) + j;
        if (lj >= 0) s += cw[d*DCONV + j] * base[(size_t)lj * (2*DINNER)];
    }
    u[idx] = s / (1.0f + expf(-s));
}

// ---------------- chunked selective scan (3 passes), lane-owns-channel -------
// h_t[s] = exp(dt_t*A[s]) h_{t-1}[s] + dt_t u_t B_t[s];  y_t = sum_s h_t[s] C_t[s]
// One lane per (b,d): 16 states in registers. dt/u loads coalesced (64 lanes =
// 64 consecutive d); B/C loads wave-uniform (broadcast). P/c/hst: [ch][b][s][d].
#define NCHUNK 16
#define CHLEN  128

__global__ __launch_bounds__(256)
void scanA_kernel(const float* __restrict__ dt, const float* __restrict__ u,
                  const float* __restrict__ xdbl, const float* __restrict__ A_log,
                  float* __restrict__ P, float* __restrict__ c)
{
    int flat = blockIdx.x * 256 + threadIdx.x;      // B*DI = 4096
    int chunk = blockIdx.y;
    int d = flat & (DINNER - 1);
    int b = flat >> 11;
    float Aa[NSTATE], Pv[NSTATE], cv[NSTATE];
    #pragma unroll
    for (int s = 0; s < NSTATE; ++s) {
        Aa[s] = -expf(A_log[d * NSTATE + s]);
        Pv[s] = 1.0f; cv[s] = 0.0f;
    }
    const float* dtp = dt + ((size_t)b * SEQ_L) * DINNER + d;
    const float* up  = u  + ((size_t)b * SEQ_L) * DINNER + d;
    const float* xdp = xdbl + (size_t)b * SEQ_L * 96 + DTRANK;
    int t0 = chunk * CHLEN;
    for (int t = t0; t < t0 + CHLEN; ++t) {
        float dtv = dtp[(size_t)t * DINNER];
        float uv  = up [(size_t)t * DINNER];
        float du = dtv * uv;
        float Bv[NSTATE];
        *(float4*)&Bv[0]  = *(const float4*)(xdp + t * 96);
        *(float4*)&Bv[4]  = *(const float4*)(xdp + t * 96 + 4);
        *(float4*)&Bv[8]  = *(const float4*)(xdp + t * 96 + 8);
        *(float4*)&Bv[12] = *(const float4*)(xdp + t * 96 + 12);
        #pragma unroll
        for (int s = 0; s < NSTATE; ++s) {
            float e = __expf(dtv * Aa[s]);
            Pv[s] *= e;
            cv[s] = fmaf(cv[s], e, du * Bv[s]);
        }
    }
    #pragma unroll
    for (int s = 0; s < NSTATE; ++s) {
        size_t o = (((size_t)chunk * BATCH + b) * NSTATE + s) * DINNER + d;
        P[o] = Pv[s]; c[o] = cv[s];
    }
}

__global__ __launch_bounds__(256)
void scanB_kernel(const float* __restrict__ P, const float* __restrict__ c,
                  float* __restrict__ hst)
{
    int flat = blockIdx.x * 256 + threadIdx.x;      // B*NSTATE*DINNER = 65536
    int d = flat & (DINNER - 1);
    int s = (flat >> 11) & (NSTATE - 1);
    int b = flat >> 15;
    float h = 0.0f;
    #pragma unroll
    for (int ch = 0; ch < NCHUNK; ++ch) {
        size_t o = (((size_t)ch * BATCH + b) * NSTATE + s) * DINNER + d;
        hst[o] = h;
        h = P[o] * h + c[o];
    }
}

// pass C: recompute locally from h0, write y over dt in place (same lane, safe)
__global__ __launch_bounds__(256)
void scanC_kernel(float* dty, const float* __restrict__ u,
                  const float* __restrict__ xdbl, const float* __restrict__ A_log,
                  const float* __restrict__ hst)
{
    int flat = blockIdx.x * 256 + threadIdx.x;      // B*DI = 4096
    int chunk = blockIdx.y;
    int d = flat & (DINNER - 1);
    int b = flat >> 11;
    float Aa[NSTATE], h[NSTATE];
    #pragma unroll
    for (int s = 0; s < NSTATE; ++s) {
        Aa[s] = -expf(A_log[d * NSTATE + s]);
        h[s] = hst[(((size_t)chunk * BATCH + b) * NSTATE + s) * DINNER + d];
    }
    float* dtp = dty + ((size_t)b * SEQ_L) * DINNER + d;
    const float* up  = u  + ((size_t)b * SEQ_L) * DINNER + d;
    const float* xdp = xdbl + (size_t)b * SEQ_L * 96 + DTRANK;
    int t0 = chunk * CHLEN;
    for (int t = t0; t < t0 + CHLEN; ++t) {
        float dtv = dtp[(size_t)t * DINNER];
        float uv  = up [(size_t)t * DINNER];
        float du = dtv * uv;
        float Bv[NSTATE], Cv[NSTATE];
        *(float4*)&Bv[0]  = *(const float4*)(xdp + t * 96);
        *(float4*)&Bv[4]  = *(const float4*)(xdp + t * 96 + 4);
        *(float4*)&Bv[8]  = *(const float4*)(xdp + t * 96 + 8);
        *(float4*)&Bv[12] = *(const float4*)(xdp + t * 96 + 12);
        *(float4*)&Cv[0]  = *(const float4*)(xdp + t * 96 + 16);
        *(float4*)&Cv[4]  = *(const float4*)(xdp + t * 96 + 20);
        *(float4*)&Cv[8]  = *(const float4*)(xdp + t * 96 + 24);
        *(float4*)&Cv[12] = *(const float4*)(xdp + t * 96 + 28);
        float y = 0.0f;
        #pragma unroll
        for (int s = 0; s < NSTATE; ++s) {
            float e = __expf(dtv * Aa[s]);
            h[s] = fmaf(h[s], e, du * Bv[s]);
            y = fmaf(h[s], Cv[s], y);
        }
        dtp[(size_t)t * DINNER] = y;
    }
}

// ---------------- y = (y + u*D) * silu(z) -> bf16 ----------------------------
__global__ __launch_bounds__(256)
void gate_b_kernel(const float* __restrict__ y, const float* __restrict__ u,
                   const float* __restrict__ Dp, const float* __restrict__ xz,
                   u16* __restrict__ yb)
{
    int i4 = blockIdx.x * 256 + threadIdx.x;        // B*L*DI/4 = 2M
    int d4 = (i4 & 511) << 2;
    int row = i4 >> 9;
    float4 yv = *(const float4*)(y + (size_t)i4 * 4);
    float4 uv = *(const float4*)(u + (size_t)i4 * 4);
    float4 zv = *(const float4*)(xz + (size_t)row * (2*DINNER) + DINNER + d4);
    float4 dv = *(const float4*)(Dp + d4);
    ushort4 o;
    o.x = f2b((yv.x + uv.x * dv.x) * silu_f(zv.x));
    o.y = f2b((yv.y + uv.y * dv.y) * silu_f(zv.y));
    o.z = f2b((yv.z + uv.z * dv.z) * silu_f(zv.z));
    o.w = f2b((yv.w + uv.w * dv.w) * silu_f(zv.w));
    *(ushort4*)(yb + (size_t)i4 * 4) = o;
}

// ---------------- f32 tiled GEMM with optional split-K -----------------------
// Computes C[m,n] += over k in [z*Kc, (z+1)*Kc); C offset by z*sCz (partials).
// EPI: 0 = store, 1 = softplus(acc+bias)
#define BM 64
#define BN 64
#define BK 16

template<int TRANSB, int EPI>
__global__ __launch_bounds__(256)
void gemm_kernel(const float* __restrict__ A, int lda,
                 const float* __restrict__ B, int ldb,
                 float* __restrict__ C, int ldc,
                 int M, int N, int Kc, const float* __restrict__ bias,
                 long long sCz)
{
    __shared__ float As[BK][BM + 4];
    __shared__ float Bs[BK][BN + 4];
    C += (size_t)blockIdx.z * sCz;
    int kOff = blockIdx.z * Kc;
    int m0 = blockIdx.y * BM, n0 = blockIdx.x * BN;
    int t = threadIdx.x;
    int tx = t & 15, ty = t >> 4;
    int rA = t >> 2, c4 = (t & 3) << 2;
    float acc[4][4] = {};
    for (int k0 = kOff; k0 < kOff + Kc; k0 += BK) {
        float4 av = make_float4(0.f,0.f,0.f,0.f);
        if (m0 + rA < M) av = *(const float4*)(A + (size_t)(m0 + rA) * lda + k0 + c4);
        As[c4+0][rA] = av.x; As[c4+1][rA] = av.y; As[c4+2][rA] = av.z; As[c4+3][rA] = av.w;
        float4 bv = make_float4(0.f,0.f,0.f,0.f);
        if (n0 + rA < N) bv = *(const float4*)(B + (size_t)(n0 + rA) * ldb + k0 + c4);
        Bs[c4+0][rA] = bv.x; Bs[c4+1][rA] = bv.y; Bs[c4+2][rA] = bv.z; Bs[c4+3][rA] = bv.w;
        __syncthreads();
        #pragma unroll
        for (int kk = 0; kk < BK; ++kk) {
            float4 a4 = *(const float4*)&As[kk][ty << 2];
            float4 b4 = *(const float4*)&Bs[kk][tx << 2];
            float a[4] = {a4.x, a4.y, a4.z, a4.w};
            float b[4] = {b4.x, b4.y, b4.z, b4.w};
            #pragma unroll
            for (int i = 0; i < 4; ++i)
                #pragma unroll
                for (int j = 0; j < 4; ++j)
                    acc[i][j] = fmaf(a[i], b[j], acc[i][j]);
        }
        __syncthreads();
    }
    #pragma unroll
    for (int i = 0; i < 4; ++i) {
        int m = m0 + (ty << 2) + i;
        if (m >= M) continue;
        #pragma unroll
        for (int j = 0; j < 4; ++j) {
            int n = n0 + (tx << 2) + j;
            if (n >= N) continue;
            float v = acc[i][j];
            if (EPI == 1) {
                float xv = v + bias[n];
                v = fmaxf(xv, 0.0f) + log1pf(expf(-fabsf(xv)));
            }
            C[(size_t)m * ldc + n] = v;
        }
    }
}

// ---------------- deterministic 8-way split-K reduce -------------------------
__global__ __launch_bounds__(256)
void reduce8_kernel(const float* __restrict__ p, float* __restrict__ o, int n)
{
    int i = blockIdx.x * 256 + threadIdx.x;
    if (i >= n) return;
    float s = 0.0f;
    #pragma unroll
    for (int z = 0; z < 8; ++z) s += p[(size_t)z * n + i];
    o[i] = s;
}

// ---------------- bf16 MFMA NT GEMM (m97 structure) --------------------------
// C[m,n] = sum_k A[m,k]*B[n,k], A:[M,K] bf16 row-major, B:[N,K] bf16 row-major.
// 128x128 tile, 256 thr = 4 waves (2x2 of 64x64), BK=64. global_load_lds
// staging, linear LDS [128][64], pre-swizzled source col + swizzled ds_read.
// EPI: 0 = f32 store, 1 = bf16 store, 2 = f32 Src+acc store,
//      3 = bf16 store of acc * decay_mask(m,n)  (for scores)
template<int EPI>
__global__ __launch_bounds__(256)
void mfma_nt_kernel(const u16* __restrict__ A, int lda, long long sA,
                    const u16* __restrict__ B, int ldb, long long sB,
                    float* __restrict__ Cf, u16* __restrict__ Cb, int ldc, long long sC,
                    int K, const float* __restrict__ Src)
{
    __shared__ u16 As[128 * 64];
    __shared__ u16 Bs[128 * 64];
    int bz = blockIdx.z;
    A += (size_t)bz * sA; B += (size_t)bz * sB;
    if (EPI == 1 || EPI == 3) Cb += (size_t)bz * sC; else Cf += (size_t)bz * sC;
    if (EPI == 2) Src += (size_t)bz * sC;
    int m0 = blockIdx.y * 128, n0 = blockIdx.x * 128;
    int t = threadIdx.x;
    int lane = t & 63, w = t >> 6;
    int wm = (w >> 1) * 64, wn = (w & 1) * 64;
    int l15 = lane & 15, lhi = lane >> 4;

    int lrow = lane >> 3;                                   // 0..7
    int scol = ((lane & 7) ^ lrow) << 3;                    // pre-swizzled source col (u16)

    f32x4 acc[4][4] = {};
    const int nk = K >> 6;

    for (int kt = 0; kt < nk; ++kt) {
        int kb = kt << 6;
        #pragma unroll
        for (int q = 0; q < 4; ++q) {
            int c = (q << 2) + w;                           // chunk 0..15
            int row = (c << 3) + lrow;
            GLL16(A + (size_t)(m0 + row) * lda + kb + scol, &As[c << 9]);
            GLL16(B + (size_t)(n0 + row) * ldb + kb + scol, &Bs[c << 9]);
        }
        __syncthreads();
        #pragma unroll
        for (int ks = 0; ks < 2; ++ks) {
            int csw = (ks * 32 + lhi * 8) ^ ((l15 & 7) << 3);  // swizzled u16 col
            bf16x8 af[4], bfr[4];
            #pragma unroll
            for (int f = 0; f < 4; ++f) {
                af[f]  = *(const bf16x8*)&As[(wm + f*16 + l15) * 64 + csw];
                bfr[f] = *(const bf16x8*)&Bs[(wn + f*16 + l15) * 64 + csw];
            }
            #pragma unroll
            for (int i = 0; i < 4; ++i)
                #pragma unroll
                for (int j = 0; j < 4; ++j)
                    acc[i][j] = __builtin_amdgcn_mfma_f32_16x16x32_bf16(
                                    af[i], bfr[j], acc[i][j], 0, 0, 0);
        }
        __syncthreads();
    }
    int rb0 = m0 + wm + lhi * 4;
    int cb0 = n0 + wn + l15;
    #pragma unroll
    for (int mf = 0; mf < 4; ++mf) {
        #pragma unroll
        for (int nf = 0; nf < 4; ++nf) {
            #pragma unroll
            for (int i = 0; i < 4; ++i) {
                int r = rb0 + mf * 16 + i;
                int cc = cb0 + nf * 16;
                float v = acc[mf][nf][i];
                if (EPI == 0) {
                    Cf[(size_t)r * ldc + cc] = v;
                } else if (EPI == 1) {
                    Cb[(size_t)r * ldc + cc] = f2b(v);
                } else if (EPI == 2) {
                    Cf[(size_t)r * ldc + cc] = Src[(size_t)r * ldc + cc] + v;
                } else {
                    float wv = (cc < r) ? ETA_C * exp2f((float)(r - 1 - cc) * LOG2_DECAY) : 0.0f;
                    Cb[(size_t)r * ldc + cc] = f2b(v * wv);
                }
            }
        }
    }
}

extern "C" void kernel_launch(void* const* d_in, const int* in_sizes, int n_in,
                              void* d_out, int out_size, void* d_ws, size_t ws_size,
                              hipStream_t stream)
{
    const float* x        = (const float*)d_in[0];
    const float* norm_w   = (const float*)d_in[1];
    const float* in_proj  = (const float*)d_in[2];
    const float* conv_w   = (const float*)d_in[3];
    const float* conv_b   = (const float*)d_in[4];
    const float* x_proj   = (const float*)d_in[5];
    const float* dt_projw = (const float*)d_in[6];
    const float* dt_projb = (const float*)d_in[7];
    const float* A_log    = (const float*)d_in[8];
    const float* D_param  = (const float*)d_in[9];
    const float* out_proj = (const float*)d_in[10];
    const float* hebb_w   = (const float*)d_in[11];
    const float* Wk       = (const float*)d_in[12];
    const float* Wv       = (const float*)d_in[13];
    float* out = (float*)d_out;

    // ---- workspace layout (float units, M1 = 1Mi floats) ----
    // [0,1M): xnb bf16 head -> later opb bf16; [1M,2M): xnb tail -> later hst
    // [2M,18M): xz f32 -> after gate: xnb2/kb16/vb16/vT16/scb16/wkT/wvT (bf16)
    // [18M,26M): u f32
    // [26M,26.5M): xdbl f32
    // [26.5M,34.5M): dtb f32 (ipb bf16 before dt written)
    // [34.5M,35.5M): Pbuf  [35.5M,36.5M): cbuf   (scan only)
    // [34.5M,37.5M): pbuf (x_proj split-K partials; dead before scans)
    // [36.5M,40.5M): ybb bf16
    float* ws = (float*)d_ws;
    const size_t M1 = 1024 * 1024;
    u16*   xnb  = (u16*)ws;
    u16*   opb  = (u16*)ws;
    float* hst  = ws + M1;
    float* xz   = ws + 2*M1;
    u16*   xnb2 = (u16*)(ws + 2*M1);
    u16*   kb16 = (u16*)(ws + 4*M1);
    u16*   vb16 = (u16*)(ws + 6*M1);
    u16*   vT16 = (u16*)(ws + 8*M1);
    u16*   scb16= (u16*)(ws + 10*M1);
    u16*   wkT  = (u16*)(ws + 14*M1);
    u16*   wvT  = (u16*)(ws + 14*M1 + M1/2);
    float* ubuf = ws + 18*M1;
    float* xdbl = ws + 26*M1;
    float* dtb  = ws + 26*M1 + M1/2;
    u16*   ipb  = (u16*)dtb;
    float* Pbuf = ws + 34*M1 + M1/2;
    float* cbuf = ws + 35*M1 + M1/2;
    float* pbuf = ws + 34*M1 + M1/2;     // 3M floats, overlaps Pbuf/cbuf/ybb-head (dead then)
    u16*   ybb  = (u16*)(ws + 36*M1 + M1/2);
    size_t need = (40*M1 + M1/2) * sizeof(float);   // 162 MiB
    if (ws_size < need) return;

    dim3 blk(256);
    const long long LD  = (long long)SEQ_L * D_MODEL;   // 2M
    const long long LL  = (long long)SEQ_L * SEQ_L;     // 4M
    const int NXP = MTOK * 96;                          // 393216

    // 1. xnb = bf16(rmsnorm(x))
    rmsnorm_b_kernel<<<MTOK, blk, 0, stream>>>(x, norm_w, xnb);
    // 2. ipb = bf16(in_proj_w)
    cvt_bf16_kernel<<<(2*DINNER*D_MODEL/4 + 255)/256, blk, 0, stream>>>(in_proj, ipb, 2*DINNER*D_MODEL/4);
    // 3. xz = xnb @ ipb^T  [4096x4096, K=1024] f32
    mfma_nt_kernel<0><<<dim3(32, 32, 1), blk, 0, stream>>>(
        xnb, D_MODEL, 0, ipb, D_MODEL, 0, xz, nullptr, 2*DINNER, 0, D_MODEL, nullptr);
    // 4. u = silu(conv(xm)+b)
    conv_silu_kernel<<<(MTOK*DINNER)/256, blk, 0, stream>>>(xz, conv_w, conv_b, ubuf);
    // 5. xdbl = u @ x_proj^T  [4096x96, K=2048] f32, split-K 8 -> reduce
    gemm_kernel<1,0><<<dim3(2, MTOK/BM, 8), blk, 0, stream>>>(
        ubuf, DINNER, x_proj, DINNER, pbuf, 96, MTOK, 96, DINNER/8, nullptr, (long long)NXP);
    reduce8_kernel<<<(NXP + 255)/256, blk, 0, stream>>>(pbuf, xdbl, NXP);
    // 6. dt = softplus(xdbl[:,:64] @ dt_proj^T + b)  [4096x2048, K=64] f32
    gemm_kernel<1,1><<<dim3(DINNER/BN, MTOK/BM, 1), blk, 0, stream>>>(
        xdbl, 96, dt_projw, DTRANK, dtb, DINNER, MTOK, DINNER, DTRANK, dt_projb, 0);
    // 7. chunked selective scan (lane-owns-channel): dtb(dt) -> dtb(y)
    scanA_kernel<<<dim3(16, NCHUNK), blk, 0, stream>>>(dtb, ubuf, xdbl, A_log, Pbuf, cbuf);
    scanB_kernel<<<256, blk, 0, stream>>>(Pbuf, cbuf, hst);
    scanC_kernel<<<dim3(16, NCHUNK), blk, 0, stream>>>(dtb, ubuf, xdbl, A_log, hst);
    // 8. ybb = bf16((y + u*D) * silu(z))
    gate_b_kernel<<<(MTOK*DINNER/4)/256, blk, 0, stream>>>(dtb, ubuf, D_param, xz, ybb);
    // 8b. opb = bf16(out_proj_w); wkT/wvT = bf16(Wk^T / Wv^T)
    cvt_bf16_kernel<<<(D_MODEL*DINNER/4 + 255)/256, blk, 0, stream>>>(out_proj, opb, D_MODEL*DINNER/4);
    transpose_b16_kernel<float><<<dim3(32, 32, 1), blk, 0, stream>>>(Wk, wkT, D_MODEL, D_MODEL, 0, 0);
    transpose_b16_kernel<float><<<dim3(32, 32, 1), blk, 0, stream>>>(Wv, wvT, D_MODEL, D_MODEL, 0, 0);
    // 9. out = x + ybb @ opb^T  [4096x1024, K=2048]
    mfma_nt_kernel<2><<<dim3(8, 32, 1), blk, 0, stream>>>(
        ybb, DINNER, 0, opb, DINNER, 0, out, nullptr, D_MODEL, 0, DINNER, x);
    // 10. xnb2 = bf16(rmsnorm(out))
    rmsnorm_b_kernel<<<MTOK, blk, 0, stream>>>(out, hebb_w, xnb2);
    // 11. kb16 = xnb2 @ wkT^T  (= xn @ Wk)  [4096x1024, K=1024] bf16
    mfma_nt_kernel<1><<<dim3(8, 32, 1), blk, 0, stream>>>(
        xnb2, D_MODEL, 0, wkT, D_MODEL, 0, nullptr, kb16, D_MODEL, 0, D_MODEL, nullptr);
    // 12. vb16 = xnb2 @ wvT^T  [4096x1024, K=1024] bf16
    mfma_nt_kernel<1><<<dim3(8, 32, 1), blk, 0, stream>>>(
        xnb2, D_MODEL, 0, wvT, D_MODEL, 0, nullptr, vb16, D_MODEL, 0, D_MODEL, nullptr);
    // 13. vT16[b] = vb16[b]^T  ([2048x1024] -> [1024x2048])
    transpose_b16_kernel<u16><<<dim3(32, 64, BATCH), blk, 0, stream>>>(
        vb16, vT16, SEQ_L, D_MODEL, LD, LD);
    // 14. scb16[b] = decay_mask .* (xnb2[b] @ kb16[b]^T)  [2048x2048, K=1024] bf16
    mfma_nt_kernel<3><<<dim3(16, 16, BATCH), blk, 0, stream>>>(
        xnb2, D_MODEL, LD, kb16, D_MODEL, LD, nullptr, scb16, SEQ_L, LL, D_MODEL, nullptr);
    // 15. out[b] += scb16[b] @ vT16[b]^T  [2048x1024, K=2048]
    mfma_nt_kernel<2><<<dim3(8, 16, BATCH), blk, 0, stream>>>(
        scb16, SEQ_L, LL, vT16, SEQ_L, LD, out, nullptr, D_MODEL, LD, SEQ_L, out);
}

// Round 8
// 466.293 us; speedup vs baseline: 5.6297x; 1.1505x over previous
//
#include <hip/hip_runtime.h>
#include <hip/hip_bf16.h>
#include <math.h>

#define D_MODEL 1024
#define SEQ_L   2048
#define BATCH   2
#define NSTATE  16
#define DCONV   4
#define DINNER  2048
#define DTRANK  64
#define ETA_C   0.1f
#define DECAY_C 0.95f
#define EPS_C   1e-5f
#define MTOK    (BATCH*SEQ_L)   // 4096
#define LOG2_DECAY (-0.07400058144377693f)

typedef unsigned short u16;
typedef __attribute__((ext_vector_type(8))) short bf16x8;
typedef __attribute__((ext_vector_type(4))) float f32x4;

__device__ inline u16 f2b(float f) {
    __hip_bfloat16 h = __float2bfloat16(f);
    return *reinterpret_cast<u16*>(&h);
}
__device__ inline float silu_f(float z) { return z / (1.0f + expf(-z)); }

// global->LDS direct DMA, 16B per lane. LDS dest = wave-uniform base + lane*16.
#define GLL16(gsrc, ldst) \
    __builtin_amdgcn_global_load_lds((const __attribute__((address_space(1))) void*)(gsrc), \
                                     (__attribute__((address_space(3))) void*)(ldst), 16, 0, 0)

// ---------------- rmsnorm -> bf16 out: one block per row ---------------------
__global__ __launch_bounds__(256)
void rmsnorm_b_kernel(const float* __restrict__ in, const float* __restrict__ w,
                      u16* __restrict__ outb)
{
    int row = blockIdx.x;
    int t = threadIdx.x;
    const float4* ip = (const float4*)(in + (size_t)row * D_MODEL);
    float4 v = ip[t];
    float ss = v.x*v.x + v.y*v.y + v.z*v.z + v.w*v.w;
    #pragma unroll
    for (int m = 1; m < 64; m <<= 1) ss += __shfl_xor(ss, m);
    __shared__ float red[4];
    if ((t & 63) == 0) red[t >> 6] = ss;
    __syncthreads();
    float total = red[0] + red[1] + red[2] + red[3];
    float sc = rsqrtf(total * (1.0f / D_MODEL) + EPS_C);
    float4 wv = ((const float4*)w)[t];
    ushort4 o;
    o.x = f2b(v.x * sc * wv.x); o.y = f2b(v.y * sc * wv.y);
    o.z = f2b(v.z * sc * wv.z); o.w = f2b(v.w * sc * wv.w);
    ((ushort4*)(outb + (size_t)row * D_MODEL))[t] = o;
}

// ---------------- plain f32 -> bf16 convert (vector4) ------------------------
__global__ __launch_bounds__(256)
void cvt_bf16_kernel(const float* __restrict__ in, u16* __restrict__ out, int n4)
{
    int i = blockIdx.x * 256 + threadIdx.x;
    if (i >= n4) return;
    float4 v = *(const float4*)(in + (size_t)i * 4);
    ushort4 o; o.x = f2b(v.x); o.y = f2b(v.y); o.z = f2b(v.z); o.w = f2b(v.w);
    *(ushort4*)(out + (size_t)i * 4) = o;
}

// ---------------- tiled transpose -> bf16 (f32 or bf16 input) ----------------
__device__ inline u16 to_b16(float v) { return f2b(v); }
__device__ inline u16 to_b16(u16 v)   { return v; }

template<typename TIN>
__global__ __launch_bounds__(256)
void transpose_b16_kernel(const TIN* __restrict__ in, u16* __restrict__ outT,
                          int R, int C, long long sIn, long long sOut)
{
    __shared__ u16 tile[32][34];
    in   += (size_t)blockIdx.z * sIn;
    outT += (size_t)blockIdx.z * sOut;
    int c0 = blockIdx.x * 32, r0 = blockIdx.y * 32;
    int tx = threadIdx.x & 31, ty = threadIdx.x >> 5;   // ty 0..7
    #pragma unroll
    for (int i = 0; i < 4; ++i)
        tile[ty + 8*i][tx] = to_b16(in[(size_t)(r0 + ty + 8*i) * C + c0 + tx]);
    __syncthreads();
    #pragma unroll
    for (int i = 0; i < 4; ++i)
        outT[(size_t)(c0 + ty + 8*i) * R + r0 + tx] = tile[tx][ty + 8*i];
}

// ---------------- depthwise causal conv (DC=4) + silu ------------------------
__global__ __launch_bounds__(256)
void conv_silu_kernel(const float* __restrict__ xz, const float* __restrict__ cw,
                      const float* __restrict__ cb, float* __restrict__ u)
{
    int idx = blockIdx.x * 256 + threadIdx.x;       // B*L*DI
    int d = idx & (DINNER - 1);
    int l = (idx >> 11) & (SEQ_L - 1);
    int b = idx >> 22;
    const float* base = xz + ((size_t)b * SEQ_L) * (2*DINNER) + d;
    float s = cb[d];
    #pragma unroll
    for (int j = 0; j < DCONV; ++j) {
        int lj = l - (DCONV-1) + j;
        if (lj >= 0) s += cw[d*DCONV + j] * base[(size_t)lj * (2*DINNER)];
    }
    u[idx] = s / (1.0f + expf(-s));
}

// ---------------- chunked selective scan (3 passes), lane-owns-channel -------
// h_t[s] = exp(dt_t*A[s]) h_{t-1}[s] + dt_t u_t B_t[s];  y_t = sum_s h_t[s] C_t[s]
// One lane per (b,d): 16 states in registers. dt/u loads coalesced; B/C loads
// wave-uniform (broadcast). PC: float2{P,c} at [ch][b][s][d]; hst f32 same idx.
#define NCHUNK 32
#define CHLEN  64

__global__ __launch_bounds__(256)
void scanA_kernel(const float* __restrict__ dt, const float* __restrict__ u,
                  const float* __restrict__ xdbl, const float* __restrict__ A_log,
                  float2* __restrict__ PC)
{
    int flat = blockIdx.x * 256 + threadIdx.x;      // B*DI = 4096
    int chunk = blockIdx.y;
    int d = flat & (DINNER - 1);
    int b = flat >> 11;
    float Aa[NSTATE], Pv[NSTATE], cv[NSTATE];
    #pragma unroll
    for (int s = 0; s < NSTATE; ++s) {
        Aa[s] = -expf(A_log[d * NSTATE + s]);
        Pv[s] = 1.0f; cv[s] = 0.0f;
    }
    const float* dtp = dt + ((size_t)b * SEQ_L) * DINNER + d;
    const float* up  = u  + ((size_t)b * SEQ_L) * DINNER + d;
    const float* xdp = xdbl + (size_t)b * SEQ_L * 96 + DTRANK;
    int t0 = chunk * CHLEN;
    #pragma unroll 2
    for (int t = t0; t < t0 + CHLEN; ++t) {
        float dtv = dtp[(size_t)t * DINNER];
        float uv  = up [(size_t)t * DINNER];
        float du = dtv * uv;
        float Bv[NSTATE];
        *(float4*)&Bv[0]  = *(const float4*)(xdp + t * 96);
        *(float4*)&Bv[4]  = *(const float4*)(xdp + t * 96 + 4);
        *(float4*)&Bv[8]  = *(const float4*)(xdp + t * 96 + 8);
        *(float4*)&Bv[12] = *(const float4*)(xdp + t * 96 + 12);
        #pragma unroll
        for (int s = 0; s < NSTATE; ++s) {
            float e = __expf(dtv * Aa[s]);
            Pv[s] *= e;
            cv[s] = fmaf(cv[s], e, du * Bv[s]);
        }
    }
    #pragma unroll
    for (int s = 0; s < NSTATE; ++s) {
        size_t o = (((size_t)chunk * BATCH + b) * NSTATE + s) * DINNER + d;
        PC[o] = make_float2(Pv[s], cv[s]);
    }
}

__global__ __launch_bounds__(256)
void scanB_kernel(const float2* __restrict__ PC, float* __restrict__ hst)
{
    int flat = blockIdx.x * 256 + threadIdx.x;      // B*NSTATE*DINNER = 65536
    int d = flat & (DINNER - 1);
    int s = (flat >> 11) & (NSTATE - 1);
    int b = flat >> 15;
    float h = 0.0f;
    #pragma unroll
    for (int ch = 0; ch < NCHUNK; ++ch) {
        size_t o = (((size_t)ch * BATCH + b) * NSTATE + s) * DINNER + d;
        hst[o] = h;
        float2 pc = PC[o];
        h = pc.x * h + pc.y;
    }
}

// pass C: recompute locally from h0, write y over dt in place (same lane, safe)
__global__ __launch_bounds__(256)
void scanC_kernel(float* dty, const float* __restrict__ u,
                  const float* __restrict__ xdbl, const float* __restrict__ A_log,
                  const float* __restrict__ hst)
{
    int flat = blockIdx.x * 256 + threadIdx.x;      // B*DI = 4096
    int chunk = blockIdx.y;
    int d = flat & (DINNER - 1);
    int b = flat >> 11;
    float Aa[NSTATE], h[NSTATE];
    #pragma unroll
    for (int s = 0; s < NSTATE; ++s) {
        Aa[s] = -expf(A_log[d * NSTATE + s]);
        h[s] = hst[(((size_t)chunk * BATCH + b) * NSTATE + s) * DINNER + d];
    }
    float* dtp = dty + ((size_t)b * SEQ_L) * DINNER + d;
    const float* up  = u  + ((size_t)b * SEQ_L) * DINNER + d;
    const float* xdp = xdbl + (size_t)b * SEQ_L * 96 + DTRANK;
    int t0 = chunk * CHLEN;
    #pragma unroll 2
    for (int t = t0; t < t0 + CHLEN; ++t) {
        float dtv = dtp[(size_t)t * DINNER];
        float uv  = up [(size_t)t * DINNER];
        float du = dtv * uv;
        float Bv[NSTATE], Cv[NSTATE];
        *(float4*)&Bv[0]  = *(const float4*)(xdp + t * 96);
        *(float4*)&Bv[4]  = *(const float4*)(xdp + t * 96 + 4);
        *(float4*)&Bv[8]  = *(const float4*)(xdp + t * 96 + 8);
        *(float4*)&Bv[12] = *(const float4*)(xdp + t * 96 + 12);
        *(float4*)&Cv[0]  = *(const float4*)(xdp + t * 96 + 16);
        *(float4*)&Cv[4]  = *(const float4*)(xdp + t * 96 + 20);
        *(float4*)&Cv[8]  = *(const float4*)(xdp + t * 96 + 24);
        *(float4*)&Cv[12] = *(const float4*)(xdp + t * 96 + 28);
        float y = 0.0f;
        #pragma unroll
        for (int s = 0; s < NSTATE; ++s) {
            float e = __expf(dtv * Aa[s]);
            h[s] = fmaf(h[s], e, du * Bv[s]);
            y = fmaf(h[s], Cv[s], y);
        }
        dtp[(size_t)t * DINNER] = y;
    }
}

// ---------------- y = (y + u*D) * silu(z) -> bf16 ----------------------------
__global__ __launch_bounds__(256)
void gate_b_kernel(const float* __restrict__ y, const float* __restrict__ u,
                   const float* __restrict__ Dp, const float* __restrict__ xz,
                   u16* __restrict__ yb)
{
    int i4 = blockIdx.x * 256 + threadIdx.x;        // B*L*DI/4 = 2M
    int d4 = (i4 & 511) << 2;
    int row = i4 >> 9;
    float4 yv = *(const float4*)(y + (size_t)i4 * 4);
    float4 uv = *(const float4*)(u + (size_t)i4 * 4);
    float4 zv = *(const float4*)(xz + (size_t)row * (2*DINNER) + DINNER + d4);
    float4 dv = *(const float4*)(Dp + d4);
    ushort4 o;
    o.x = f2b((yv.x + uv.x * dv.x) * silu_f(zv.x));
    o.y = f2b((yv.y + uv.y * dv.y) * silu_f(zv.y));
    o.z = f2b((yv.z + uv.z * dv.z) * silu_f(zv.z));
    o.w = f2b((yv.w + uv.w * dv.w) * silu_f(zv.w));
    *(ushort4*)(yb + (size_t)i4 * 4) = o;
}

// ---------------- f32 tiled GEMM with optional split-K -----------------------
// EPI: 0 = store, 1 = softplus(acc+bias)
#define BM 64
#define BN 64
#define BK 16

template<int TRANSB, int EPI>
__global__ __launch_bounds__(256)
void gemm_kernel(const float* __restrict__ A, int lda,
                 const float* __restrict__ B, int ldb,
                 float* __restrict__ C, int ldc,
                 int M, int N, int Kc, const float* __restrict__ bias,
                 long long sCz)
{
    __shared__ float As[BK][BM + 4];
    __shared__ float Bs[BK][BN + 4];
    C += (size_t)blockIdx.z * sCz;
    int kOff = blockIdx.z * Kc;
    int m0 = blockIdx.y * BM, n0 = blockIdx.x * BN;
    int t = threadIdx.x;
    int tx = t & 15, ty = t >> 4;
    int rA = t >> 2, c4 = (t & 3) << 2;
    float acc[4][4] = {};
    for (int k0 = kOff; k0 < kOff + Kc; k0 += BK) {
        float4 av = make_float4(0.f,0.f,0.f,0.f);
        if (m0 + rA < M) av = *(const float4*)(A + (size_t)(m0 + rA) * lda + k0 + c4);
        As[c4+0][rA] = av.x; As[c4+1][rA] = av.y; As[c4+2][rA] = av.z; As[c4+3][rA] = av.w;
        float4 bv = make_float4(0.f,0.f,0.f,0.f);
        if (n0 + rA < N) bv = *(const float4*)(B + (size_t)(n0 + rA) * ldb + k0 + c4);
        Bs[c4+0][rA] = bv.x; Bs[c4+1][rA] = bv.y; Bs[c4+2][rA] = bv.z; Bs[c4+3][rA] = bv.w;
        __syncthreads();
        #pragma unroll
        for (int kk = 0; kk < BK; ++kk) {
            float4 a4 = *(const float4*)&As[kk][ty << 2];
            float4 b4 = *(const float4*)&Bs[kk][tx << 2];
            float a[4] = {a4.x, a4.y, a4.z, a4.w};
            float b[4] = {b4.x, b4.y, b4.z, b4.w};
            #pragma unroll
            for (int i = 0; i < 4; ++i)
                #pragma unroll
                for (int j = 0; j < 4; ++j)
                    acc[i][j] = fmaf(a[i], b[j], acc[i][j]);
        }
        __syncthreads();
    }
    #pragma unroll
    for (int i = 0; i < 4; ++i) {
        int m = m0 + (ty << 2) + i;
        if (m >= M) continue;
        #pragma unroll
        for (int j = 0; j < 4; ++j) {
            int n = n0 + (tx << 2) + j;
            if (n >= N) continue;
            float v = acc[i][j];
            if (EPI == 1) {
                float xv = v + bias[n];
                v = fmaxf(xv, 0.0f) + log1pf(expf(-fabsf(xv)));
            }
            C[(size_t)m * ldc + n] = v;
        }
    }
}

// ---------------- deterministic 8-way split-K reduce -------------------------
__global__ __launch_bounds__(256)
void reduce8_kernel(const float* __restrict__ p, float* __restrict__ o, int n)
{
    int i = blockIdx.x * 256 + threadIdx.x;
    if (i >= n) return;
    float s = 0.0f;
    #pragma unroll
    for (int z = 0; z < 8; ++z) s += p[(size_t)z * n + i];
    o[i] = s;
}

// ---------------- bf16 MFMA NT GEMM (m97 structure) --------------------------
// C[m,n] = sum_k A[m,k]*B[n,k], A:[M,K] bf16 row-major, B:[N,K] bf16 row-major.
// 128x128 tile, 256 thr = 4 waves (2x2 of 64x64), BK=64. global_load_lds
// staging, linear LDS [128][64], pre-swizzled source col + swizzled ds_read.
// EPI: 0 = f32 store, 1 = bf16 store, 2 = f32 Src+acc store,
//      3 = bf16 store of acc * decay_mask(m,n)  (for scores)
template<int EPI>
__global__ __launch_bounds__(256)
void mfma_nt_kernel(const u16* __restrict__ A, int lda, long long sA,
                    const u16* __restrict__ B, int ldb, long long sB,
                    float* __restrict__ Cf, u16* __restrict__ Cb, int ldc, long long sC,
                    int K, const float* __restrict__ Src)
{
    __shared__ u16 As[128 * 64];
    __shared__ u16 Bs[128 * 64];
    int bz = blockIdx.z;
    A += (size_t)bz * sA; B += (size_t)bz * sB;
    if (EPI == 1 || EPI == 3) Cb += (size_t)bz * sC; else Cf += (size_t)bz * sC;
    if (EPI == 2) Src += (size_t)bz * sC;
    int m0 = blockIdx.y * 128, n0 = blockIdx.x * 128;
    int t = threadIdx.x;
    int lane = t & 63, w = t >> 6;
    int wm = (w >> 1) * 64, wn = (w & 1) * 64;
    int l15 = lane & 15, lhi = lane >> 4;

    int lrow = lane >> 3;                                   // 0..7
    int scol = ((lane & 7) ^ lrow) << 3;                    // pre-swizzled source col (u16)

    f32x4 acc[4][4] = {};
    const int nk = K >> 6;

    for (int kt = 0; kt < nk; ++kt) {
        int kb = kt << 6;
        #pragma unroll
        for (int q = 0; q < 4; ++q) {
            int c = (q << 2) + w;                           // chunk 0..15
            int row = (c << 3) + lrow;
            GLL16(A + (size_t)(m0 + row) * lda + kb + scol, &As[c << 9]);
            GLL16(B + (size_t)(n0 + row) * ldb + kb + scol, &Bs[c << 9]);
        }
        __syncthreads();
        #pragma unroll
        for (int ks = 0; ks < 2; ++ks) {
            int csw = (ks * 32 + lhi * 8) ^ ((l15 & 7) << 3);  // swizzled u16 col
            bf16x8 af[4], bfr[4];
            #pragma unroll
            for (int f = 0; f < 4; ++f) {
                af[f]  = *(const bf16x8*)&As[(wm + f*16 + l15) * 64 + csw];
                bfr[f] = *(const bf16x8*)&Bs[(wn + f*16 + l15) * 64 + csw];
            }
            #pragma unroll
            for (int i = 0; i < 4; ++i)
                #pragma unroll
                for (int j = 0; j < 4; ++j)
                    acc[i][j] = __builtin_amdgcn_mfma_f32_16x16x32_bf16(
                                    af[i], bfr[j], acc[i][j], 0, 0, 0);
        }
        __syncthreads();
    }
    int rb0 = m0 + wm + lhi * 4;
    int cb0 = n0 + wn + l15;
    #pragma unroll
    for (int mf = 0; mf < 4; ++mf) {
        #pragma unroll
        for (int nf = 0; nf < 4; ++nf) {
            #pragma unroll
            for (int i = 0; i < 4; ++i) {
                int r = rb0 + mf * 16 + i;
                int cc = cb0 + nf * 16;
                float v = acc[mf][nf][i];
                if (EPI == 0) {
                    Cf[(size_t)r * ldc + cc] = v;
                } else if (EPI == 1) {
                    Cb[(size_t)r * ldc + cc] = f2b(v);
                } else if (EPI == 2) {
                    Cf[(size_t)r * ldc + cc] = Src[(size_t)r * ldc + cc] + v;
                } else {
                    float wv = (cc < r) ? ETA_C * exp2f((float)(r - 1 - cc) * LOG2_DECAY) : 0.0f;
                    Cb[(size_t)r * ldc + cc] = f2b(v * wv);
                }
            }
        }
    }
}

extern "C" void kernel_launch(void* const* d_in, const int* in_sizes, int n_in,
                              void* d_out, int out_size, void* d_ws, size_t ws_size,
                              hipStream_t stream)
{
    const float* x        = (const float*)d_in[0];
    const float* norm_w   = (const float*)d_in[1];
    const float* in_proj  = (const float*)d_in[2];
    const float* conv_w   = (const float*)d_in[3];
    const float* conv_b   = (const float*)d_in[4];
    const float* x_proj   = (const float*)d_in[5];
    const float* dt_projw = (const float*)d_in[6];
    const float* dt_projb = (const float*)d_in[7];
    const float* A_log    = (const float*)d_in[8];
    const float* D_param  = (const float*)d_in[9];
    const float* out_proj = (const float*)d_in[10];
    const float* hebb_w   = (const float*)d_in[11];
    const float* Wk       = (const float*)d_in[12];
    const float* Wv       = (const float*)d_in[13];
    float* out = (float*)d_out;

    // ---- workspace layout (float units, M1 = 1Mi floats) ----
    // [0,1M): xnb bf16 head -> later opb bf16; [1M,2M): xnb tail (dead after 3)
    // [2M,18M): xz f32 -> after gate: xnb2/kb16/vb16/vT16/scb16/wkT/wvT (bf16)
    // [18M,26M): u f32
    // [26M,26.5M): xdbl f32
    // [26.5M,34.5M): dtb f32 (ipb bf16 before dt written)
    // [34.5M,37.5M): pbuf (x_proj split-K partials; dead before scanA)
    // [34.5M,38.5M): PCbuf float2 (scanA->scanB, dead after scanB)
    // [38.5M,40.5M): hst f32 (scanB->scanC, dead after scanC)
    // [36.5M,40.5M): ybb bf16 (written at gate, after PC/hst dead)
    float* ws = (float*)d_ws;
    const size_t M1 = 1024 * 1024;
    u16*   xnb  = (u16*)ws;
    u16*   opb  = (u16*)ws;
    float* xz   = ws + 2*M1;
    u16*   xnb2 = (u16*)(ws + 2*M1);
    u16*   kb16 = (u16*)(ws + 4*M1);
    u16*   vb16 = (u16*)(ws + 6*M1);
    u16*   vT16 = (u16*)(ws + 8*M1);
    u16*   scb16= (u16*)(ws + 10*M1);
    u16*   wkT  = (u16*)(ws + 14*M1);
    u16*   wvT  = (u16*)(ws + 14*M1 + M1/2);
    float* ubuf = ws + 18*M1;
    float* xdbl = ws + 26*M1;
    float* dtb  = ws + 26*M1 + M1/2;
    u16*   ipb  = (u16*)dtb;
    float* pbuf = ws + 34*M1 + M1/2;              // 3M floats
    float2* PCbuf = (float2*)(ws + 34*M1 + M1/2); // 2M float2 = 4M floats
    float* hst  = ws + 38*M1 + M1/2;              // 2M floats
    u16*   ybb  = (u16*)(ws + 36*M1 + M1/2);
    size_t need = (40*M1 + M1/2) * sizeof(float);   // 162 MiB
    if (ws_size < need) return;

    dim3 blk(256);
    const long long LD  = (long long)SEQ_L * D_MODEL;   // 2M
    const long long LL  = (long long)SEQ_L * SEQ_L;     // 4M
    const int NXP = MTOK * 96;                          // 393216

    // 1. xnb = bf16(rmsnorm(x))
    rmsnorm_b_kernel<<<MTOK, blk, 0, stream>>>(x, norm_w, xnb);
    // 2. ipb = bf16(in_proj_w)
    cvt_bf16_kernel<<<(2*DINNER*D_MODEL/4 + 255)/256, blk, 0, stream>>>(in_proj, ipb, 2*DINNER*D_MODEL/4);
    // 3. xz = xnb @ ipb^T  [4096x4096, K=1024] f32
    mfma_nt_kernel<0><<<dim3(32, 32, 1), blk, 0, stream>>>(
        xnb, D_MODEL, 0, ipb, D_MODEL, 0, xz, nullptr, 2*DINNER, 0, D_MODEL, nullptr);
    // 4. u = silu(conv(xm)+b)
    conv_silu_kernel<<<(MTOK*DINNER)/256, blk, 0, stream>>>(xz, conv_w, conv_b, ubuf);
    // 5. xdbl = u @ x_proj^T  [4096x96, K=2048] f32, split-K 8 -> reduce
    gemm_kernel<1,0><<<dim3(2, MTOK/BM, 8), blk, 0, stream>>>(
        ubuf, DINNER, x_proj, DINNER, pbuf, 96, MTOK, 96, DINNER/8, nullptr, (long long)NXP);
    reduce8_kernel<<<(NXP + 255)/256, blk, 0, stream>>>(pbuf, xdbl, NXP);
    // 6. dt = softplus(xdbl[:,:64] @ dt_proj^T + b)  [4096x2048, K=64] f32
    gemm_kernel<1,1><<<dim3(DINNER/BN, MTOK/BM, 1), blk, 0, stream>>>(
        xdbl, 96, dt_projw, DTRANK, dtb, DINNER, MTOK, DINNER, DTRANK, dt_projb, 0);
    // 7. chunked selective scan (lane-owns-channel): dtb(dt) -> dtb(y)
    scanA_kernel<<<dim3(16, NCHUNK), blk, 0, stream>>>(dtb, ubuf, xdbl, A_log, PCbuf);
    scanB_kernel<<<256, blk, 0, stream>>>(PCbuf, hst);
    scanC_kernel<<<dim3(16, NCHUNK), blk, 0, stream>>>(dtb, ubuf, xdbl, A_log, hst);
    // 8. ybb = bf16((y + u*D) * silu(z))
    gate_b_kernel<<<(MTOK*DINNER/4)/256, blk, 0, stream>>>(dtb, ubuf, D_param, xz, ybb);
    // 8b. opb = bf16(out_proj_w); wkT/wvT = bf16(Wk^T / Wv^T)
    cvt_bf16_kernel<<<(D_MODEL*DINNER/4 + 255)/256, blk, 0, stream>>>(out_proj, opb, D_MODEL*DINNER/4);
    transpose_b16_kernel<float><<<dim3(32, 32, 1), blk, 0, stream>>>(Wk, wkT, D_MODEL, D_MODEL, 0, 0);
    transpose_b16_kernel<float><<<dim3(32, 32, 1), blk, 0, stream>>>(Wv, wvT, D_MODEL, D_MODEL, 0, 0);
    // 9. out = x + ybb @ opb^T  [4096x1024, K=2048]
    mfma_nt_kernel<2><<<dim3(8, 32, 1), blk, 0, stream>>>(
        ybb, DINNER, 0, opb, DINNER, 0, out, nullptr, D_MODEL, 0, DINNER, x);
    // 10. xnb2 = bf16(rmsnorm(out))
    rmsnorm_b_kernel<<<MTOK, blk, 0, stream>>>(out, hebb_w, xnb2);
    // 11. kb16 = xnb2 @ wkT^T  (= xn @ Wk)  [4096x1024, K=1024] bf16
    mfma_nt_kernel<1><<<dim3(8, 32, 1), blk, 0, stream>>>(
        xnb2, D_MODEL, 0, wkT, D_MODEL, 0, nullptr, kb16, D_MODEL, 0, D_MODEL, nullptr);
    // 12. vb16 = xnb2 @ wvT^T  [4096x1024, K=1024] bf16
    mfma_nt_kernel<1><<<dim3(8, 32, 1), blk, 0, stream>>>(
        xnb2, D_MODEL, 0, wvT, D_MODEL, 0, nullptr, vb16, D_MODEL, 0, D_MODEL, nullptr);
    // 13. vT16[b] = vb16[b]^T  ([2048x1024] -> [1024x2048])
    transpose_b16_kernel<u16><<<dim3(32, 64, BATCH), blk, 0, stream>>>(
        vb16, vT16, SEQ_L, D_MODEL, LD, LD);
    // 14. scb16[b] = decay_mask .* (xnb2[b] @ kb16[b]^T)  [2048x2048, K=1024] bf16
    mfma_nt_kernel<3><<<dim3(16, 16, BATCH), blk, 0, stream>>>(
        xnb2, D_MODEL, LD, kb16, D_MODEL, LD, nullptr, scb16, SEQ_L, LL, D_MODEL, nullptr);
    // 15. out[b] += scb16[b] @ vT16[b]^T  [2048x1024, K=2048]
    mfma_nt_kernel<2><<<dim3(8, 16, BATCH), blk, 0, stream>>>(
        scb16, SEQ_L, LL, vT16, SEQ_L, LD, out, nullptr, D_MODEL, LD, SEQ_L, out);
}

// Round 9
// 454.477 us; speedup vs baseline: 5.7761x; 1.0260x over previous
//
#include <hip/hip_runtime.h>
#include <hip/hip_bf16.h>
#include <math.h>

#define D_MODEL 1024
#define SEQ_L   2048
#define BATCH   2
#define NSTATE  16
#define DCONV   4
#define DINNER  2048
#define DTRANK  64
#define ETA_C   0.1f
#define DECAY_C 0.95f
#define EPS_C   1e-5f
#define MTOK    (BATCH*SEQ_L)   // 4096
#define LOG2_DECAY (-0.07400058144377693f)

typedef unsigned short u16;
typedef __attribute__((ext_vector_type(8))) short bf16x8;
typedef __attribute__((ext_vector_type(4))) float f32x4;

__device__ inline u16 f2b(float f) {
    __hip_bfloat16 h = __float2bfloat16(f);
    return *reinterpret_cast<u16*>(&h);
}
__device__ inline float silu_f(float z) { return z / (1.0f + expf(-z)); }

// global->LDS direct DMA, 16B per lane. LDS dest = wave-uniform base + lane*16.
#define GLL16(gsrc, ldst) \
    __builtin_amdgcn_global_load_lds((const __attribute__((address_space(1))) void*)(gsrc), \
                                     (__attribute__((address_space(3))) void*)(ldst), 16, 0, 0)

// ---------------- rmsnorm -> bf16 out: one block per row ---------------------
__global__ __launch_bounds__(256)
void rmsnorm_b_kernel(const float* __restrict__ in, const float* __restrict__ w,
                      u16* __restrict__ outb)
{
    int row = blockIdx.x;
    int t = threadIdx.x;
    const float4* ip = (const float4*)(in + (size_t)row * D_MODEL);
    float4 v = ip[t];
    float ss = v.x*v.x + v.y*v.y + v.z*v.z + v.w*v.w;
    #pragma unroll
    for (int m = 1; m < 64; m <<= 1) ss += __shfl_xor(ss, m);
    __shared__ float red[4];
    if ((t & 63) == 0) red[t >> 6] = ss;
    __syncthreads();
    float total = red[0] + red[1] + red[2] + red[3];
    float sc = rsqrtf(total * (1.0f / D_MODEL) + EPS_C);
    float4 wv = ((const float4*)w)[t];
    ushort4 o;
    o.x = f2b(v.x * sc * wv.x); o.y = f2b(v.y * sc * wv.y);
    o.z = f2b(v.z * sc * wv.z); o.w = f2b(v.w * sc * wv.w);
    ((ushort4*)(outb + (size_t)row * D_MODEL))[t] = o;
}

// ---------------- plain f32 -> bf16 convert (vector4) ------------------------
__global__ __launch_bounds__(256)
void cvt_bf16_kernel(const float* __restrict__ in, u16* __restrict__ out, int n4)
{
    int i = blockIdx.x * 256 + threadIdx.x;
    if (i >= n4) return;
    float4 v = *(const float4*)(in + (size_t)i * 4);
    ushort4 o; o.x = f2b(v.x); o.y = f2b(v.y); o.z = f2b(v.z); o.w = f2b(v.w);
    *(ushort4*)(out + (size_t)i * 4) = o;
}

// ---------------- cvt slice: [R][96] f32 cols 0..63 -> [R][64] bf16 ----------
__global__ __launch_bounds__(256)
void cvt_slice64_kernel(const float* __restrict__ in, u16* __restrict__ out)
{
    int i = blockIdx.x * 256 + threadIdx.x;     // R*16
    int row = i >> 4, c4 = (i & 15) << 2;
    float4 v = *(const float4*)(in + (size_t)row * 96 + c4);
    ushort4 o; o.x = f2b(v.x); o.y = f2b(v.y); o.z = f2b(v.z); o.w = f2b(v.w);
    *(ushort4*)(out + (size_t)row * 64 + c4) = o;
}

// ---------------- tiled transpose -> bf16 (f32 or bf16 input) ----------------
__device__ inline u16 to_b16(float v) { return f2b(v); }
__device__ inline u16 to_b16(u16 v)   { return v; }

template<typename TIN>
__global__ __launch_bounds__(256)
void transpose_b16_kernel(const TIN* __restrict__ in, u16* __restrict__ outT,
                          int R, int C, long long sIn, long long sOut)
{
    __shared__ u16 tile[32][34];
    in   += (size_t)blockIdx.z * sIn;
    outT += (size_t)blockIdx.z * sOut;
    int c0 = blockIdx.x * 32, r0 = blockIdx.y * 32;
    int tx = threadIdx.x & 31, ty = threadIdx.x >> 5;   // ty 0..7
    #pragma unroll
    for (int i = 0; i < 4; ++i)
        tile[ty + 8*i][tx] = to_b16(in[(size_t)(r0 + ty + 8*i) * C + c0 + tx]);
    __syncthreads();
    #pragma unroll
    for (int i = 0; i < 4; ++i)
        outT[(size_t)(c0 + ty + 8*i) * R + r0 + tx] = tile[tx][ty + 8*i];
}

// ---------------- depthwise causal conv (DC=4) + silu ------------------------
__global__ __launch_bounds__(256)
void conv_silu_kernel(const float* __restrict__ xz, const float* __restrict__ cw,
                      const float* __restrict__ cb, float* __restrict__ u)
{
    int idx = blockIdx.x * 256 + threadIdx.x;       // B*L*DI
    int d = idx & (DINNER - 1);
    int l = (idx >> 11) & (SEQ_L - 1);
    int b = idx >> 22;
    const float* base = xz + ((size_t)b * SEQ_L) * (2*DINNER) + d;
    float s = cb[d];
    #pragma unroll
    for (int j = 0; j < DCONV; ++j) {
        int lj = l - (DCONV-1) + j;
        if (lj >= 0) s += cw[d*DCONV + j] * base[(size_t)lj * (2*DINNER)];
    }
    u[idx] = s / (1.0f + expf(-s));
}

// ---------------- chunked selective scan (3 passes), lane-owns-channel -------
#define NCHUNK 32
#define CHLEN  64

__global__ __launch_bounds__(256)
void scanA_kernel(const float* __restrict__ dt, const float* __restrict__ u,
                  const float* __restrict__ xdbl, const float* __restrict__ A_log,
                  float2* __restrict__ PC)
{
    int flat = blockIdx.x * 256 + threadIdx.x;      // B*DI = 4096
    int chunk = blockIdx.y;
    int d = flat & (DINNER - 1);
    int b = flat >> 11;
    float Aa[NSTATE], Pv[NSTATE], cv[NSTATE];
    #pragma unroll
    for (int s = 0; s < NSTATE; ++s) {
        Aa[s] = -expf(A_log[d * NSTATE + s]);
        Pv[s] = 1.0f; cv[s] = 0.0f;
    }
    const float* dtp = dt + ((size_t)b * SEQ_L) * DINNER + d;
    const float* up  = u  + ((size_t)b * SEQ_L) * DINNER + d;
    const float* xdp = xdbl + (size_t)b * SEQ_L * 96 + DTRANK;
    int t0 = chunk * CHLEN;
    #pragma unroll 2
    for (int t = t0; t < t0 + CHLEN; ++t) {
        float dtv = dtp[(size_t)t * DINNER];
        float uv  = up [(size_t)t * DINNER];
        float du = dtv * uv;
        float Bv[NSTATE];
        *(float4*)&Bv[0]  = *(const float4*)(xdp + t * 96);
        *(float4*)&Bv[4]  = *(const float4*)(xdp + t * 96 + 4);
        *(float4*)&Bv[8]  = *(const float4*)(xdp + t * 96 + 8);
        *(float4*)&Bv[12] = *(const float4*)(xdp + t * 96 + 12);
        #pragma unroll
        for (int s = 0; s < NSTATE; ++s) {
            float e = __expf(dtv * Aa[s]);
            Pv[s] *= e;
            cv[s] = fmaf(cv[s], e, du * Bv[s]);
        }
    }
    #pragma unroll
    for (int s = 0; s < NSTATE; ++s) {
        size_t o = (((size_t)chunk * BATCH + b) * NSTATE + s) * DINNER + d;
        PC[o] = make_float2(Pv[s], cv[s]);
    }
}

__global__ __launch_bounds__(256)
void scanB_kernel(const float2* __restrict__ PC, float* __restrict__ hst)
{
    int flat = blockIdx.x * 256 + threadIdx.x;      // B*NSTATE*DINNER = 65536
    int d = flat & (DINNER - 1);
    int s = (flat >> 11) & (NSTATE - 1);
    int b = flat >> 15;
    float h = 0.0f;
    #pragma unroll
    for (int ch = 0; ch < NCHUNK; ++ch) {
        size_t o = (((size_t)ch * BATCH + b) * NSTATE + s) * DINNER + d;
        hst[o] = h;
        float2 pc = PC[o];
        h = pc.x * h + pc.y;
    }
}

__global__ __launch_bounds__(256)
void scanC_kernel(float* dty, const float* __restrict__ u,
                  const float* __restrict__ xdbl, const float* __restrict__ A_log,
                  const float* __restrict__ hst)
{
    int flat = blockIdx.x * 256 + threadIdx.x;      // B*DI = 4096
    int chunk = blockIdx.y;
    int d = flat & (DINNER - 1);
    int b = flat >> 11;
    float Aa[NSTATE], h[NSTATE];
    #pragma unroll
    for (int s = 0; s < NSTATE; ++s) {
        Aa[s] = -expf(A_log[d * NSTATE + s]);
        h[s] = hst[(((size_t)chunk * BATCH + b) * NSTATE + s) * DINNER + d];
    }
    float* dtp = dty + ((size_t)b * SEQ_L) * DINNER + d;
    const float* up  = u  + ((size_t)b * SEQ_L) * DINNER + d;
    const float* xdp = xdbl + (size_t)b * SEQ_L * 96 + DTRANK;
    int t0 = chunk * CHLEN;
    #pragma unroll 2
    for (int t = t0; t < t0 + CHLEN; ++t) {
        float dtv = dtp[(size_t)t * DINNER];
        float uv  = up [(size_t)t * DINNER];
        float du = dtv * uv;
        float Bv[NSTATE], Cv[NSTATE];
        *(float4*)&Bv[0]  = *(const float4*)(xdp + t * 96);
        *(float4*)&Bv[4]  = *(const float4*)(xdp + t * 96 + 4);
        *(float4*)&Bv[8]  = *(const float4*)(xdp + t * 96 + 8);
        *(float4*)&Bv[12] = *(const float4*)(xdp + t * 96 + 12);
        *(float4*)&Cv[0]  = *(const float4*)(xdp + t * 96 + 16);
        *(float4*)&Cv[4]  = *(const float4*)(xdp + t * 96 + 20);
        *(float4*)&Cv[8]  = *(const float4*)(xdp + t * 96 + 24);
        *(float4*)&Cv[12] = *(const float4*)(xdp + t * 96 + 28);
        float y = 0.0f;
        #pragma unroll
        for (int s = 0; s < NSTATE; ++s) {
            float e = __expf(dtv * Aa[s]);
            h[s] = fmaf(h[s], e, du * Bv[s]);
            y = fmaf(h[s], Cv[s], y);
        }
        dtp[(size_t)t * DINNER] = y;
    }
}

// ---------------- y = (y + u*D) * silu(z) -> bf16 ----------------------------
__global__ __launch_bounds__(256)
void gate_b_kernel(const float* __restrict__ y, const float* __restrict__ u,
                   const float* __restrict__ Dp, const float* __restrict__ xz,
                   u16* __restrict__ yb)
{
    int i4 = blockIdx.x * 256 + threadIdx.x;        // B*L*DI/4 = 2M
    int d4 = (i4 & 511) << 2;
    int row = i4 >> 9;
    float4 yv = *(const float4*)(y + (size_t)i4 * 4);
    float4 uv = *(const float4*)(u + (size_t)i4 * 4);
    float4 zv = *(const float4*)(xz + (size_t)row * (2*DINNER) + DINNER + d4);
    float4 dv = *(const float4*)(Dp + d4);
    ushort4 o;
    o.x = f2b((yv.x + uv.x * dv.x) * silu_f(zv.x));
    o.y = f2b((yv.y + uv.y * dv.y) * silu_f(zv.y));
    o.z = f2b((yv.z + uv.z * dv.z) * silu_f(zv.z));
    o.w = f2b((yv.w + uv.w * dv.w) * silu_f(zv.w));
    *(ushort4*)(yb + (size_t)i4 * 4) = o;
}

// ---------------- f32 tiled GEMM with optional split-K -----------------------
#define BM 64
#define BN 64
#define BK 16

template<int TRANSB, int EPI>
__global__ __launch_bounds__(256)
void gemm_kernel(const float* __restrict__ A, int lda,
                 const float* __restrict__ B, int ldb,
                 float* __restrict__ C, int ldc,
                 int M, int N, int Kc, const float* __restrict__ bias,
                 long long sCz)
{
    __shared__ float As[BK][BM + 4];
    __shared__ float Bs[BK][BN + 4];
    C += (size_t)blockIdx.z * sCz;
    int kOff = blockIdx.z * Kc;
    int m0 = blockIdx.y * BM, n0 = blockIdx.x * BN;
    int t = threadIdx.x;
    int tx = t & 15, ty = t >> 4;
    int rA = t >> 2, c4 = (t & 3) << 2;
    float acc[4][4] = {};
    for (int k0 = kOff; k0 < kOff + Kc; k0 += BK) {
        float4 av = make_float4(0.f,0.f,0.f,0.f);
        if (m0 + rA < M) av = *(const float4*)(A + (size_t)(m0 + rA) * lda + k0 + c4);
        As[c4+0][rA] = av.x; As[c4+1][rA] = av.y; As[c4+2][rA] = av.z; As[c4+3][rA] = av.w;
        float4 bv = make_float4(0.f,0.f,0.f,0.f);
        if (n0 + rA < N) bv = *(const float4*)(B + (size_t)(n0 + rA) * ldb + k0 + c4);
        Bs[c4+0][rA] = bv.x; Bs[c4+1][rA] = bv.y; Bs[c4+2][rA] = bv.z; Bs[c4+3][rA] = bv.w;
        __syncthreads();
        #pragma unroll
        for (int kk = 0; kk < BK; ++kk) {
            float4 a4 = *(const float4*)&As[kk][ty << 2];
            float4 b4 = *(const float4*)&Bs[kk][tx << 2];
            float a[4] = {a4.x, a4.y, a4.z, a4.w};
            float b[4] = {b4.x, b4.y, b4.z, b4.w};
            #pragma unroll
            for (int i = 0; i < 4; ++i)
                #pragma unroll
                for (int j = 0; j < 4; ++j)
                    acc[i][j] = fmaf(a[i], b[j], acc[i][j]);
        }
        __syncthreads();
    }
    #pragma unroll
    for (int i = 0; i < 4; ++i) {
        int m = m0 + (ty << 2) + i;
        if (m >= M) continue;
        #pragma unroll
        for (int j = 0; j < 4; ++j) {
            int n = n0 + (tx << 2) + j;
            if (n >= N) continue;
            float v = acc[i][j];
            if (EPI == 1) {
                float xv = v + bias[n];
                v = fmaxf(xv, 0.0f) + log1pf(expf(-fabsf(xv)));
            }
            C[(size_t)m * ldc + n] = v;
        }
    }
}

// ---------------- deterministic 8-way split-K reduce -------------------------
__global__ __launch_bounds__(256)
void reduce8_kernel(const float* __restrict__ p, float* __restrict__ o, int n)
{
    int i = blockIdx.x * 256 + threadIdx.x;
    if (i >= n) return;
    float s = 0.0f;
    #pragma unroll
    for (int z = 0; z < 8; ++z) s += p[(size_t)z * n + i];
    o[i] = s;
}

// ---------------- bf16 MFMA NT GEMM (m97 structure) --------------------------
// C[m,n] = sum_k A[m,k]*B[n,k], A:[M,K] bf16 row-major, B:[N,K] bf16 row-major.
// 128x128 tile, 4 waves, BK=64, global_load_lds staging, swizzled LDS.
// EPI: 0 = f32 store, 1 = bf16 store, 2 = f32 Src+acc store,
//      3 = bf16 store of acc * decay_mask(m,n),
//      4 = f32 store of softplus(acc + Src[n])   (Src = bias)
// SWZ: 1 = bijective XCD-chunked remap of (bx,by); requires gx*gy % 8 == 0.
template<int EPI, int SWZ = 0>
__global__ __launch_bounds__(256)
void mfma_nt_kernel(const u16* __restrict__ A, int lda, long long sA,
                    const u16* __restrict__ B, int ldb, long long sB,
                    float* __restrict__ Cf, u16* __restrict__ Cb, int ldc, long long sC,
                    int K, const float* __restrict__ Src)
{
    __shared__ u16 As[128 * 64];
    __shared__ u16 Bs[128 * 64];
    int bz = blockIdx.z;
    A += (size_t)bz * sA; B += (size_t)bz * sB;
    if (EPI == 1 || EPI == 3) Cb += (size_t)bz * sC; else Cf += (size_t)bz * sC;
    if (EPI == 2) Src += (size_t)bz * sC;
    int bx = blockIdx.x, by = blockIdx.y;
    if (SWZ) {
        int gx = gridDim.x;
        int nwg = gx * gridDim.y;
        int flat = by * gx + bx;
        int swz = (flat & 7) * (nwg >> 3) + (flat >> 3);   // nwg % 8 == 0
        bx = swz % gx; by = swz / gx;
    }
    int m0 = by * 128, n0 = bx * 128;
    int t = threadIdx.x;
    int lane = t & 63, w = t >> 6;
    int wm = (w >> 1) * 64, wn = (w & 1) * 64;
    int l15 = lane & 15, lhi = lane >> 4;

    int lrow = lane >> 3;                                   // 0..7
    int scol = ((lane & 7) ^ lrow) << 3;                    // pre-swizzled source col (u16)

    f32x4 acc[4][4] = {};
    const int nk = K >> 6;

    for (int kt = 0; kt < nk; ++kt) {
        int kb = kt << 6;
        #pragma unroll
        for (int q = 0; q < 4; ++q) {
            int c = (q << 2) + w;                           // chunk 0..15
            int row = (c << 3) + lrow;
            GLL16(A + (size_t)(m0 + row) * lda + kb + scol, &As[c << 9]);
            GLL16(B + (size_t)(n0 + row) * ldb + kb + scol, &Bs[c << 9]);
        }
        __syncthreads();
        #pragma unroll
        for (int ks = 0; ks < 2; ++ks) {
            int csw = (ks * 32 + lhi * 8) ^ ((l15 & 7) << 3);  // swizzled u16 col
            bf16x8 af[4], bfr[4];
            #pragma unroll
            for (int f = 0; f < 4; ++f) {
                af[f]  = *(const bf16x8*)&As[(wm + f*16 + l15) * 64 + csw];
                bfr[f] = *(const bf16x8*)&Bs[(wn + f*16 + l15) * 64 + csw];
            }
            #pragma unroll
            for (int i = 0; i < 4; ++i)
                #pragma unroll
                for (int j = 0; j < 4; ++j)
                    acc[i][j] = __builtin_amdgcn_mfma_f32_16x16x32_bf16(
                                    af[i], bfr[j], acc[i][j], 0, 0, 0);
        }
        __syncthreads();
    }
    int rb0 = m0 + wm + lhi * 4;
    int cb0 = n0 + wn + l15;
    #pragma unroll
    for (int mf = 0; mf < 4; ++mf) {
        #pragma unroll
        for (int nf = 0; nf < 4; ++nf) {
            #pragma unroll
            for (int i = 0; i < 4; ++i) {
                int r = rb0 + mf * 16 + i;
                int cc = cb0 + nf * 16;
                float v = acc[mf][nf][i];
                if (EPI == 0) {
                    Cf[(size_t)r * ldc + cc] = v;
                } else if (EPI == 1) {
                    Cb[(size_t)r * ldc + cc] = f2b(v);
                } else if (EPI == 2) {
                    Cf[(size_t)r * ldc + cc] = Src[(size_t)r * ldc + cc] + v;
                } else if (EPI == 4) {
                    float xv = v + Src[cc];
                    Cf[(size_t)r * ldc + cc] = fmaxf(xv, 0.0f) + log1pf(expf(-fabsf(xv)));
                } else {
                    float wv = (cc < r) ? ETA_C * exp2f((float)(r - 1 - cc) * LOG2_DECAY) : 0.0f;
                    Cb[(size_t)r * ldc + cc] = f2b(v * wv);
                }
            }
        }
    }
}

extern "C" void kernel_launch(void* const* d_in, const int* in_sizes, int n_in,
                              void* d_out, int out_size, void* d_ws, size_t ws_size,
                              hipStream_t stream)
{
    const float* x        = (const float*)d_in[0];
    const float* norm_w   = (const float*)d_in[1];
    const float* in_proj  = (const float*)d_in[2];
    const float* conv_w   = (const float*)d_in[3];
    const float* conv_b   = (const float*)d_in[4];
    const float* x_proj   = (const float*)d_in[5];
    const float* dt_projw = (const float*)d_in[6];
    const float* dt_projb = (const float*)d_in[7];
    const float* A_log    = (const float*)d_in[8];
    const float* D_param  = (const float*)d_in[9];
    const float* out_proj = (const float*)d_in[10];
    const float* hebb_w   = (const float*)d_in[11];
    const float* Wk       = (const float*)d_in[12];
    const float* Wv       = (const float*)d_in[13];
    float* out = (float*)d_out;

    // ---- workspace layout (float units, M1 = 1Mi floats) ----
    // [0,1M): xnb bf16 head -> later opb bf16; [1M,2M): xnb tail (dead after 3)
    // [2M,18M): xz f32 -> after gate: xnb2/kb16/vb16/vT16/scb16/wkT/wvT (bf16)
    // [18M,26M): u f32
    // [26M,26.5M): xdbl f32
    // [26.5M,34.5M): dtb f32 (ipb bf16 before dt written)
    // [34.5M,37.5M): pbuf (x_proj split-K partials; dead after reduce8)
    // [34.5M,+128K): xdb16 bf16; [+128K,+192K): dtw16 bf16  (dead after dt MFMA)
    // [34.5M,38.5M): PCbuf float2 (scanA->scanB)
    // [38.5M,40.5M): hst f32 (scanB->scanC)
    // [36.5M,40.5M): ybb bf16 (written at gate, after PC/hst dead)
    float* ws = (float*)d_ws;
    const size_t M1 = 1024 * 1024;
    u16*   xnb  = (u16*)ws;
    u16*   opb  = (u16*)ws;
    float* xz   = ws + 2*M1;
    u16*   xnb2 = (u16*)(ws + 2*M1);
    u16*   kb16 = (u16*)(ws + 4*M1);
    u16*   vb16 = (u16*)(ws + 6*M1);
    u16*   vT16 = (u16*)(ws + 8*M1);
    u16*   scb16= (u16*)(ws + 10*M1);
    u16*   wkT  = (u16*)(ws + 14*M1);
    u16*   wvT  = (u16*)(ws + 14*M1 + M1/2);
    float* ubuf = ws + 18*M1;
    float* xdbl = ws + 26*M1;
    float* dtb  = ws + 26*M1 + M1/2;
    u16*   ipb  = (u16*)dtb;
    float* pbuf = ws + 34*M1 + M1/2;                 // 3M floats
    u16*   xdb16 = (u16*)(ws + 34*M1 + M1/2);        // 256K u16
    u16*   dtw16 = (u16*)(ws + 34*M1 + M1/2 + 128*1024);  // 128K u16
    float2* PCbuf = (float2*)(ws + 34*M1 + M1/2);    // 2M float2
    float* hst  = ws + 38*M1 + M1/2;                 // 2M floats
    u16*   ybb  = (u16*)(ws + 36*M1 + M1/2);
    size_t need = (40*M1 + M1/2) * sizeof(float);    // 162 MiB
    if (ws_size < need) return;

    dim3 blk(256);
    const long long LD  = (long long)SEQ_L * D_MODEL;   // 2M
    const long long LL  = (long long)SEQ_L * SEQ_L;     // 4M
    const int NXP = MTOK * 96;                          // 393216

    // 1. xnb = bf16(rmsnorm(x))
    rmsnorm_b_kernel<<<MTOK, blk, 0, stream>>>(x, norm_w, xnb);
    // 2. ipb = bf16(in_proj_w)
    cvt_bf16_kernel<<<(2*DINNER*D_MODEL/4 + 255)/256, blk, 0, stream>>>(in_proj, ipb, 2*DINNER*D_MODEL/4);
    // 3. xz = xnb @ ipb^T  [4096x4096, K=1024] f32, XCD-swizzled (HBM-bound)
    mfma_nt_kernel<0,1><<<dim3(32, 32, 1), blk, 0, stream>>>(
        xnb, D_MODEL, 0, ipb, D_MODEL, 0, xz, nullptr, 2*DINNER, 0, D_MODEL, nullptr);
    // 4. u = silu(conv(xm)+b)
    conv_silu_kernel<<<(MTOK*DINNER)/256, blk, 0, stream>>>(xz, conv_w, conv_b, ubuf);
    // 5. xdbl = u @ x_proj^T  [4096x96, K=2048] f32, split-K 8 -> reduce
    gemm_kernel<1,0><<<dim3(2, MTOK/BM, 8), blk, 0, stream>>>(
        ubuf, DINNER, x_proj, DINNER, pbuf, 96, MTOK, 96, DINNER/8, nullptr, (long long)NXP);
    reduce8_kernel<<<(NXP + 255)/256, blk, 0, stream>>>(pbuf, xdbl, NXP);
    // 6. dt = softplus(xdbl[:,:64] @ dt_proj^T + b) via bf16 MFMA  [4096x2048, K=64]
    cvt_bf16_kernel<<<(DINNER*DTRANK/4 + 255)/256, blk, 0, stream>>>(dt_projw, dtw16, DINNER*DTRANK/4);
    cvt_slice64_kernel<<<(MTOK*16)/256, blk, 0, stream>>>(xdbl, xdb16);
    mfma_nt_kernel<4><<<dim3(DINNER/128, MTOK/128, 1), blk, 0, stream>>>(
        xdb16, DTRANK, 0, dtw16, DTRANK, 0, dtb, nullptr, DINNER, 0, DTRANK, dt_projb);
    // 7. chunked selective scan (lane-owns-channel): dtb(dt) -> dtb(y)
    scanA_kernel<<<dim3(16, NCHUNK), blk, 0, stream>>>(dtb, ubuf, xdbl, A_log, PCbuf);
    scanB_kernel<<<256, blk, 0, stream>>>(PCbuf, hst);
    scanC_kernel<<<dim3(16, NCHUNK), blk, 0, stream>>>(dtb, ubuf, xdbl, A_log, hst);
    // 8. ybb = bf16((y + u*D) * silu(z))
    gate_b_kernel<<<(MTOK*DINNER/4)/256, blk, 0, stream>>>(dtb, ubuf, D_param, xz, ybb);
    // 8b. opb = bf16(out_proj_w); wkT/wvT = bf16(Wk^T / Wv^T)
    cvt_bf16_kernel<<<(D_MODEL*DINNER/4 + 255)/256, blk, 0, stream>>>(out_proj, opb, D_MODEL*DINNER/4);
    transpose_b16_kernel<float><<<dim3(32, 32, 1), blk, 0, stream>>>(Wk, wkT, D_MODEL, D_MODEL, 0, 0);
    transpose_b16_kernel<float><<<dim3(32, 32, 1), blk, 0, stream>>>(Wv, wvT, D_MODEL, D_MODEL, 0, 0);
    // 9. out = x + ybb @ opb^T  [4096x1024, K=2048]
    mfma_nt_kernel<2><<<dim3(8, 32, 1), blk, 0, stream>>>(
        ybb, DINNER, 0, opb, DINNER, 0, out, nullptr, D_MODEL, 0, DINNER, x);
    // 10. xnb2 = bf16(rmsnorm(out))
    rmsnorm_b_kernel<<<MTOK, blk, 0, stream>>>(out, hebb_w, xnb2);
    // 11. kb16 = xnb2 @ wkT^T  (= xn @ Wk)  [4096x1024, K=1024] bf16
    mfma_nt_kernel<1><<<dim3(8, 32, 1), blk, 0, stream>>>(
        xnb2, D_MODEL, 0, wkT, D_MODEL, 0, nullptr, kb16, D_MODEL, 0, D_MODEL, nullptr);
    // 12. vb16 = xnb2 @ wvT^T  [4096x1024, K=1024] bf16
    mfma_nt_kernel<1><<<dim3(8, 32, 1), blk, 0, stream>>>(
        xnb2, D_MODEL, 0, wvT, D_MODEL, 0, nullptr, vb16, D_MODEL, 0, D_MODEL, nullptr);
    // 13. vT16[b] = vb16[b]^T  ([2048x1024] -> [1024x2048])
    transpose_b16_kernel<u16><<<dim3(32, 64, BATCH), blk, 0, stream>>>(
        vb16, vT16, SEQ_L, D_MODEL, LD, LD);
    // 14. scb16[b] = decay_mask .* (xnb2[b] @ kb16[b]^T)  [2048x2048, K=1024] bf16
    mfma_nt_kernel<3><<<dim3(16, 16, BATCH), blk, 0, stream>>>(
        xnb2, D_MODEL, LD, kb16, D_MODEL, LD, nullptr, scb16, SEQ_L, LL, D_MODEL, nullptr);
    // 15. out[b] += scb16[b] @ vT16[b]^T  [2048x1024, K=2048]
    mfma_nt_kernel<2><<<dim3(8, 16, BATCH), blk, 0, stream>>>(
        scb16, SEQ_L, LL, vT16, SEQ_L, LD, out, nullptr, D_MODEL, LD, SEQ_L, out);
}

// Round 10
// 438.478 us; speedup vs baseline: 5.9868x; 1.0365x over previous
//
#include <hip/hip_runtime.h>
#include <hip/hip_bf16.h>
#include <math.h>

#define D_MODEL 1024
#define SEQ_L   2048
#define BATCH   2
#define NSTATE  16
#define DCONV   4
#define DINNER  2048
#define DTRANK  64
#define ETA_C   0.1f
#define DECAY_C 0.95f
#define EPS_C   1e-5f
#define MTOK    (BATCH*SEQ_L)   // 4096
#define LOG2_DECAY (-0.07400058144377693f)

typedef unsigned short u16;
typedef __attribute__((ext_vector_type(8))) short bf16x8;
typedef __attribute__((ext_vector_type(4))) float f32x4;

__device__ inline u16 f2b(float f) {
    __hip_bfloat16 h = __float2bfloat16(f);
    return *reinterpret_cast<u16*>(&h);
}
__device__ inline float b2f(u16 u) {
    unsigned int x = ((unsigned int)u) << 16;
    return __uint_as_float(x);
}
__device__ inline float silu_f(float z) { return z / (1.0f + expf(-z)); }

// global->LDS direct DMA, 16B per lane. LDS dest = wave-uniform base + lane*16.
#define GLL16(gsrc, ldst) \
    __builtin_amdgcn_global_load_lds((const __attribute__((address_space(1))) void*)(gsrc), \
                                     (__attribute__((address_space(3))) void*)(ldst), 16, 0, 0)

// ---------------- rmsnorm -> bf16 out: one block per row ---------------------
__global__ __launch_bounds__(256)
void rmsnorm_b_kernel(const float* __restrict__ in, const float* __restrict__ w,
                      u16* __restrict__ outb)
{
    int row = blockIdx.x;
    int t = threadIdx.x;
    const float4* ip = (const float4*)(in + (size_t)row * D_MODEL);
    float4 v = ip[t];
    float ss = v.x*v.x + v.y*v.y + v.z*v.z + v.w*v.w;
    #pragma unroll
    for (int m = 1; m < 64; m <<= 1) ss += __shfl_xor(ss, m);
    __shared__ float red[4];
    if ((t & 63) == 0) red[t >> 6] = ss;
    __syncthreads();
    float total = red[0] + red[1] + red[2] + red[3];
    float sc = rsqrtf(total * (1.0f / D_MODEL) + EPS_C);
    float4 wv = ((const float4*)w)[t];
    ushort4 o;
    o.x = f2b(v.x * sc * wv.x); o.y = f2b(v.y * sc * wv.y);
    o.z = f2b(v.z * sc * wv.z); o.w = f2b(v.w * sc * wv.w);
    ((ushort4*)(outb + (size_t)row * D_MODEL))[t] = o;
}

// ---------------- plain f32 -> bf16 convert (vector4) ------------------------
__global__ __launch_bounds__(256)
void cvt_bf16_kernel(const float* __restrict__ in, u16* __restrict__ out, int n4)
{
    int i = blockIdx.x * 256 + threadIdx.x;
    if (i >= n4) return;
    float4 v = *(const float4*)(in + (size_t)i * 4);
    ushort4 o; o.x = f2b(v.x); o.y = f2b(v.y); o.z = f2b(v.z); o.w = f2b(v.w);
    *(ushort4*)(out + (size_t)i * 4) = o;
}

// ---------------- cvt slice: [R][96] f32 cols 0..63 -> [R][64] bf16 ----------
__global__ __launch_bounds__(256)
void cvt_slice64_kernel(const float* __restrict__ in, u16* __restrict__ out)
{
    int i = blockIdx.x * 256 + threadIdx.x;     // R*16
    int row = i >> 4, c4 = (i & 15) << 2;
    float4 v = *(const float4*)(in + (size_t)row * 96 + c4);
    ushort4 o; o.x = f2b(v.x); o.y = f2b(v.y); o.z = f2b(v.z); o.w = f2b(v.w);
    *(ushort4*)(out + (size_t)row * 64 + c4) = o;
}

// ---------------- tiled transpose -> bf16 (f32 or bf16 input) ----------------
__device__ inline u16 to_b16(float v) { return f2b(v); }
__device__ inline u16 to_b16(u16 v)   { return v; }

template<typename TIN>
__global__ __launch_bounds__(256)
void transpose_b16_kernel(const TIN* __restrict__ in, u16* __restrict__ outT,
                          int R, int C, long long sIn, long long sOut)
{
    __shared__ u16 tile[32][34];
    in   += (size_t)blockIdx.z * sIn;
    outT += (size_t)blockIdx.z * sOut;
    int c0 = blockIdx.x * 32, r0 = blockIdx.y * 32;
    int tx = threadIdx.x & 31, ty = threadIdx.x >> 5;   // ty 0..7
    #pragma unroll
    for (int i = 0; i < 4; ++i)
        tile[ty + 8*i][tx] = to_b16(in[(size_t)(r0 + ty + 8*i) * C + c0 + tx]);
    __syncthreads();
    #pragma unroll
    for (int i = 0; i < 4; ++i)
        outT[(size_t)(c0 + ty + 8*i) * R + r0 + tx] = tile[tx][ty + 8*i];
}

// ---------------- depthwise causal conv (DC=4) + silu, bf16 in, f32 out ------
// xm = xzb[:, 0:DINNER] bf16, row stride 2*DINNER. 4 channels per thread.
__global__ __launch_bounds__(256)
void conv_silu_kernel(const u16* __restrict__ xzb, const float* __restrict__ cw,
                      const float* __restrict__ cb, float* __restrict__ u)
{
    int i4 = blockIdx.x * 256 + threadIdx.x;        // B*L*DI/4 = 2M
    int d4 = (i4 & 511) << 2;                       // d in [0,2048) step 4
    int row = i4 >> 9;                              // b*L + l
    int l = row & (SEQ_L - 1);
    const u16* base = xzb + (size_t)row * (2*DINNER) + d4;
    float4 cbv = *(const float4*)(cb + d4);
    float s[4] = {cbv.x, cbv.y, cbv.z, cbv.w};
    float4 w0 = *(const float4*)(cw + (d4+0)*DCONV);
    float4 w1 = *(const float4*)(cw + (d4+1)*DCONV);
    float4 w2 = *(const float4*)(cw + (d4+2)*DCONV);
    float4 w3 = *(const float4*)(cw + (d4+3)*DCONV);
    const float* wj[4] = {(const float*)&w0, (const float*)&w1,
                          (const float*)&w2, (const float*)&w3};
    #pragma unroll
    for (int j = 0; j < DCONV; ++j) {
        int lj = l - (DCONV-1) + j;
        if (lj >= 0) {
            ushort4 xv = *(const ushort4*)(base + (size_t)(lj - l) * (2*DINNER));
            s[0] = fmaf(wj[0][j], b2f(xv.x), s[0]);
            s[1] = fmaf(wj[1][j], b2f(xv.y), s[1]);
            s[2] = fmaf(wj[2][j], b2f(xv.z), s[2]);
            s[3] = fmaf(wj[3][j], b2f(xv.w), s[3]);
        }
    }
    float4 o;
    o.x = s[0] / (1.0f + expf(-s[0]));
    o.y = s[1] / (1.0f + expf(-s[1]));
    o.z = s[2] / (1.0f + expf(-s[2]));
    o.w = s[3] / (1.0f + expf(-s[3]));
    *(float4*)(u + (size_t)i4 * 4) = o;
}

// ---------------- chunked selective scan (3 passes), lane-owns-channel -------
#define NCHUNK 32
#define CHLEN  64

__global__ __launch_bounds__(256)
void scanA_kernel(const float* __restrict__ dt, const float* __restrict__ u,
                  const float* __restrict__ xdbl, const float* __restrict__ A_log,
                  float2* __restrict__ PC)
{
    int flat = blockIdx.x * 256 + threadIdx.x;      // B*DI = 4096
    int chunk = blockIdx.y;
    int d = flat & (DINNER - 1);
    int b = flat >> 11;
    float Aa[NSTATE], Pv[NSTATE], cv[NSTATE];
    #pragma unroll
    for (int s = 0; s < NSTATE; ++s) {
        Aa[s] = -expf(A_log[d * NSTATE + s]);
        Pv[s] = 1.0f; cv[s] = 0.0f;
    }
    const float* dtp = dt + ((size_t)b * SEQ_L) * DINNER + d;
    const float* up  = u  + ((size_t)b * SEQ_L) * DINNER + d;
    const float* xdp = xdbl + (size_t)b * SEQ_L * 96 + DTRANK;
    int t0 = chunk * CHLEN;
    #pragma unroll 2
    for (int t = t0; t < t0 + CHLEN; ++t) {
        float dtv = dtp[(size_t)t * DINNER];
        float uv  = up [(size_t)t * DINNER];
        float du = dtv * uv;
        float Bv[NSTATE];
        *(float4*)&Bv[0]  = *(const float4*)(xdp + t * 96);
        *(float4*)&Bv[4]  = *(const float4*)(xdp + t * 96 + 4);
        *(float4*)&Bv[8]  = *(const float4*)(xdp + t * 96 + 8);
        *(float4*)&Bv[12] = *(const float4*)(xdp + t * 96 + 12);
        #pragma unroll
        for (int s = 0; s < NSTATE; ++s) {
            float e = __expf(dtv * Aa[s]);
            Pv[s] *= e;
            cv[s] = fmaf(cv[s], e, du * Bv[s]);
        }
    }
    #pragma unroll
    for (int s = 0; s < NSTATE; ++s) {
        size_t o = (((size_t)chunk * BATCH + b) * NSTATE + s) * DINNER + d;
        PC[o] = make_float2(Pv[s], cv[s]);
    }
}

__global__ __launch_bounds__(256)
void scanB_kernel(const float2* __restrict__ PC, float* __restrict__ hst)
{
    int flat = blockIdx.x * 256 + threadIdx.x;      // B*NSTATE*DINNER = 65536
    int d = flat & (DINNER - 1);
    int s = (flat >> 11) & (NSTATE - 1);
    int b = flat >> 15;
    float h = 0.0f;
    #pragma unroll
    for (int ch = 0; ch < NCHUNK; ++ch) {
        size_t o = (((size_t)ch * BATCH + b) * NSTATE + s) * DINNER + d;
        hst[o] = h;
        float2 pc = PC[o];
        h = pc.x * h + pc.y;
    }
}

__global__ __launch_bounds__(256)
void scanC_kernel(float* dty, const float* __restrict__ u,
                  const float* __restrict__ xdbl, const float* __restrict__ A_log,
                  const float* __restrict__ hst)
{
    int flat = blockIdx.x * 256 + threadIdx.x;      // B*DI = 4096
    int chunk = blockIdx.y;
    int d = flat & (DINNER - 1);
    int b = flat >> 11;
    float Aa[NSTATE], h[NSTATE];
    #pragma unroll
    for (int s = 0; s < NSTATE; ++s) {
        Aa[s] = -expf(A_log[d * NSTATE + s]);
        h[s] = hst[(((size_t)chunk * BATCH + b) * NSTATE + s) * DINNER + d];
    }
    float* dtp = dty + ((size_t)b * SEQ_L) * DINNER + d;
    const float* up  = u  + ((size_t)b * SEQ_L) * DINNER + d;
    const float* xdp = xdbl + (size_t)b * SEQ_L * 96 + DTRANK;
    int t0 = chunk * CHLEN;
    #pragma unroll 2
    for (int t = t0; t < t0 + CHLEN; ++t) {
        float dtv = dtp[(size_t)t * DINNER];
        float uv  = up [(size_t)t * DINNER];
        float du = dtv * uv;
        float Bv[NSTATE], Cv[NSTATE];
        *(float4*)&Bv[0]  = *(const float4*)(xdp + t * 96);
        *(float4*)&Bv[4]  = *(const float4*)(xdp + t * 96 + 4);
        *(float4*)&Bv[8]  = *(const float4*)(xdp + t * 96 + 8);
        *(float4*)&Bv[12] = *(const float4*)(xdp + t * 96 + 12);
        *(float4*)&Cv[0]  = *(const float4*)(xdp + t * 96 + 16);
        *(float4*)&Cv[4]  = *(const float4*)(xdp + t * 96 + 20);
        *(float4*)&Cv[8]  = *(const float4*)(xdp + t * 96 + 24);
        *(float4*)&Cv[12] = *(const float4*)(xdp + t * 96 + 28);
        float y = 0.0f;
        #pragma unroll
        for (int s = 0; s < NSTATE; ++s) {
            float e = __expf(dtv * Aa[s]);
            h[s] = fmaf(h[s], e, du * Bv[s]);
            y = fmaf(h[s], Cv[s], y);
        }
        dtp[(size_t)t * DINNER] = y;
    }
}

// ---------------- y = (y + u*D) * silu(z) -> bf16  (z bf16) ------------------
__global__ __launch_bounds__(256)
void gate_b_kernel(const float* __restrict__ y, const float* __restrict__ u,
                   const float* __restrict__ Dp, const u16* __restrict__ xzb,
                   u16* __restrict__ yb)
{
    int i4 = blockIdx.x * 256 + threadIdx.x;        // B*L*DI/4 = 2M
    int d4 = (i4 & 511) << 2;
    int row = i4 >> 9;
    float4 yv = *(const float4*)(y + (size_t)i4 * 4);
    float4 uv = *(const float4*)(u + (size_t)i4 * 4);
    ushort4 zb = *(const ushort4*)(xzb + (size_t)row * (2*DINNER) + DINNER + d4);
    float4 dv = *(const float4*)(Dp + d4);
    ushort4 o;
    o.x = f2b((yv.x + uv.x * dv.x) * silu_f(b2f(zb.x)));
    o.y = f2b((yv.y + uv.y * dv.y) * silu_f(b2f(zb.y)));
    o.z = f2b((yv.z + uv.z * dv.z) * silu_f(b2f(zb.z)));
    o.w = f2b((yv.w + uv.w * dv.w) * silu_f(b2f(zb.w)));
    *(ushort4*)(yb + (size_t)i4 * 4) = o;
}

// ---------------- f32 tiled GEMM with optional split-K -----------------------
#define BM 64
#define BN 64
#define BK 16

template<int TRANSB, int EPI>
__global__ __launch_bounds__(256)
void gemm_kernel(const float* __restrict__ A, int lda,
                 const float* __restrict__ B, int ldb,
                 float* __restrict__ C, int ldc,
                 int M, int N, int Kc, const float* __restrict__ bias,
                 long long sCz)
{
    __shared__ float As[BK][BM + 4];
    __shared__ float Bs[BK][BN + 4];
    C += (size_t)blockIdx.z * sCz;
    int kOff = blockIdx.z * Kc;
    int m0 = blockIdx.y * BM, n0 = blockIdx.x * BN;
    int t = threadIdx.x;
    int tx = t & 15, ty = t >> 4;
    int rA = t >> 2, c4 = (t & 3) << 2;
    float acc[4][4] = {};
    for (int k0 = kOff; k0 < kOff + Kc; k0 += BK) {
        float4 av = make_float4(0.f,0.f,0.f,0.f);
        if (m0 + rA < M) av = *(const float4*)(A + (size_t)(m0 + rA) * lda + k0 + c4);
        As[c4+0][rA] = av.x; As[c4+1][rA] = av.y; As[c4+2][rA] = av.z; As[c4+3][rA] = av.w;
        float4 bv = make_float4(0.f,0.f,0.f,0.f);
        if (n0 + rA < N) bv = *(const float4*)(B + (size_t)(n0 + rA) * ldb + k0 + c4);
        Bs[c4+0][rA] = bv.x; Bs[c4+1][rA] = bv.y; Bs[c4+2][rA] = bv.z; Bs[c4+3][rA] = bv.w;
        __syncthreads();
        #pragma unroll
        for (int kk = 0; kk < BK; ++kk) {
            float4 a4 = *(const float4*)&As[kk][ty << 2];
            float4 b4 = *(const float4*)&Bs[kk][tx << 2];
            float a[4] = {a4.x, a4.y, a4.z, a4.w};
            float b[4] = {b4.x, b4.y, b4.z, b4.w};
            #pragma unroll
            for (int i = 0; i < 4; ++i)
                #pragma unroll
                for (int j = 0; j < 4; ++j)
                    acc[i][j] = fmaf(a[i], b[j], acc[i][j]);
        }
        __syncthreads();
    }
    #pragma unroll
    for (int i = 0; i < 4; ++i) {
        int m = m0 + (ty << 2) + i;
        if (m >= M) continue;
        #pragma unroll
        for (int j = 0; j < 4; ++j) {
            int n = n0 + (tx << 2) + j;
            if (n >= N) continue;
            float v = acc[i][j];
            if (EPI == 1) {
                float xv = v + bias[n];
                v = fmaxf(xv, 0.0f) + log1pf(expf(-fabsf(xv)));
            }
            C[(size_t)m * ldc + n] = v;
        }
    }
}

// ---------------- deterministic 8-way split-K reduce -------------------------
__global__ __launch_bounds__(256)
void reduce8_kernel(const float* __restrict__ p, float* __restrict__ o, int n)
{
    int i = blockIdx.x * 256 + threadIdx.x;
    if (i >= n) return;
    float s = 0.0f;
    #pragma unroll
    for (int z = 0; z < 8; ++z) s += p[(size_t)z * n + i];
    o[i] = s;
}

// ---------------- bf16 MFMA NT GEMM (m97 structure) --------------------------
// C[m,n] = sum_k A[m,k]*B[n,k], A:[M,K] bf16 row-major, B:[N,K] bf16 row-major.
// 128x128 tile, 4 waves, BK=64, global_load_lds staging, swizzled LDS.
// EPI: 0 = f32 store, 1 = bf16 store, 2 = f32 Src+acc store,
//      3 = bf16 store of acc * decay_mask(m,n),
//      4 = f32 store of softplus(acc + Src[n])   (Src = bias)
template<int EPI, int SWZ = 0>
__global__ __launch_bounds__(256)
void mfma_nt_kernel(const u16* __restrict__ A, int lda, long long sA,
                    const u16* __restrict__ B, int ldb, long long sB,
                    float* __restrict__ Cf, u16* __restrict__ Cb, int ldc, long long sC,
                    int K, const float* __restrict__ Src)
{
    __shared__ u16 As[128 * 64];
    __shared__ u16 Bs[128 * 64];
    int bz = blockIdx.z;
    A += (size_t)bz * sA; B += (size_t)bz * sB;
    if (EPI == 1 || EPI == 3) Cb += (size_t)bz * sC; else Cf += (size_t)bz * sC;
    if (EPI == 2) Src += (size_t)bz * sC;
    int bx = blockIdx.x, by = blockIdx.y;
    if (SWZ) {
        int gx = gridDim.x;
        int nwg = gx * gridDim.y;
        int flat = by * gx + bx;
        int swz = (flat & 7) * (nwg >> 3) + (flat >> 3);   // nwg % 8 == 0
        bx = swz % gx; by = swz / gx;
    }
    int m0 = by * 128, n0 = bx * 128;
    int t = threadIdx.x;
    int lane = t & 63, w = t >> 6;
    int wm = (w >> 1) * 64, wn = (w & 1) * 64;
    int l15 = lane & 15, lhi = lane >> 4;

    int lrow = lane >> 3;                                   // 0..7
    int scol = ((lane & 7) ^ lrow) << 3;                    // pre-swizzled source col (u16)

    f32x4 acc[4][4] = {};
    const int nk = K >> 6;

    for (int kt = 0; kt < nk; ++kt) {
        int kb = kt << 6;
        #pragma unroll
        for (int q = 0; q < 4; ++q) {
            int c = (q << 2) + w;                           // chunk 0..15
            int row = (c << 3) + lrow;
            GLL16(A + (size_t)(m0 + row) * lda + kb + scol, &As[c << 9]);
            GLL16(B + (size_t)(n0 + row) * ldb + kb + scol, &Bs[c << 9]);
        }
        __syncthreads();
        #pragma unroll
        for (int ks = 0; ks < 2; ++ks) {
            int csw = (ks * 32 + lhi * 8) ^ ((l15 & 7) << 3);  // swizzled u16 col
            bf16x8 af[4], bfr[4];
            #pragma unroll
            for (int f = 0; f < 4; ++f) {
                af[f]  = *(const bf16x8*)&As[(wm + f*16 + l15) * 64 + csw];
                bfr[f] = *(const bf16x8*)&Bs[(wn + f*16 + l15) * 64 + csw];
            }
            #pragma unroll
            for (int i = 0; i < 4; ++i)
                #pragma unroll
                for (int j = 0; j < 4; ++j)
                    acc[i][j] = __builtin_amdgcn_mfma_f32_16x16x32_bf16(
                                    af[i], bfr[j], acc[i][j], 0, 0, 0);
        }
        __syncthreads();
    }
    int rb0 = m0 + wm + lhi * 4;
    int cb0 = n0 + wn + l15;
    #pragma unroll
    for (int mf = 0; mf < 4; ++mf) {
        #pragma unroll
        for (int nf = 0; nf < 4; ++nf) {
            #pragma unroll
            for (int i = 0; i < 4; ++i) {
                int r = rb0 + mf * 16 + i;
                int cc = cb0 + nf * 16;
                float v = acc[mf][nf][i];
                if (EPI == 0) {
                    Cf[(size_t)r * ldc + cc] = v;
                } else if (EPI == 1) {
                    Cb[(size_t)r * ldc + cc] = f2b(v);
                } else if (EPI == 2) {
                    Cf[(size_t)r * ldc + cc] = Src[(size_t)r * ldc + cc] + v;
                } else if (EPI == 4) {
                    float xv = v + Src[cc];
                    Cf[(size_t)r * ldc + cc] = fmaxf(xv, 0.0f) + log1pf(expf(-fabsf(xv)));
                } else {
                    float wv = (cc < r) ? ETA_C * exp2f((float)(r - 1 - cc) * LOG2_DECAY) : 0.0f;
                    Cb[(size_t)r * ldc + cc] = f2b(v * wv);
                }
            }
        }
    }
}

extern "C" void kernel_launch(void* const* d_in, const int* in_sizes, int n_in,
                              void* d_out, int out_size, void* d_ws, size_t ws_size,
                              hipStream_t stream)
{
    const float* x        = (const float*)d_in[0];
    const float* norm_w   = (const float*)d_in[1];
    const float* in_proj  = (const float*)d_in[2];
    const float* conv_w   = (const float*)d_in[3];
    const float* conv_b   = (const float*)d_in[4];
    const float* x_proj   = (const float*)d_in[5];
    const float* dt_projw = (const float*)d_in[6];
    const float* dt_projb = (const float*)d_in[7];
    const float* A_log    = (const float*)d_in[8];
    const float* D_param  = (const float*)d_in[9];
    const float* out_proj = (const float*)d_in[10];
    const float* hebb_w   = (const float*)d_in[11];
    const float* Wk       = (const float*)d_in[12];
    const float* Wv       = (const float*)d_in[13];
    float* out = (float*)d_out;

    // ---- workspace layout (float units, M1 = 1Mi floats) ----
    // [0,1M): xnb bf16 head -> later opb bf16; [1M,2M): xnb tail (dead after 3)
    // [2M,10M): xzb bf16 [4096][4096] -> after gate: xnb2/kb16/vb16/vT16 etc.
    //   (post-mamba bf16 buffers live in [2M,18M) region as before)
    // [18M,26M): u f32
    // [26M,26.5M): xdbl f32
    // [26.5M,34.5M): dtb f32 (ipb bf16 before dt written)
    // [34.5M,37.5M): pbuf (x_proj split-K partials; dead after reduce8)
    // [34.5M,+128K): xdb16 bf16; [+128K,+192K): dtw16 bf16  (dead after dt MFMA)
    // [34.5M,38.5M): PCbuf float2 (scanA->scanB)
    // [38.5M,40.5M): hst f32 (scanB->scanC)
    // [36.5M,40.5M): ybb bf16 (written at gate, after PC/hst dead)
    float* ws = (float*)d_ws;
    const size_t M1 = 1024 * 1024;
    u16*   xnb  = (u16*)ws;
    u16*   opb  = (u16*)ws;
    u16*   xzb  = (u16*)(ws + 2*M1);
    u16*   xnb2 = (u16*)(ws + 2*M1);
    u16*   kb16 = (u16*)(ws + 4*M1);
    u16*   vb16 = (u16*)(ws + 6*M1);
    u16*   vT16 = (u16*)(ws + 8*M1);
    u16*   scb16= (u16*)(ws + 10*M1);
    u16*   wkT  = (u16*)(ws + 14*M1);
    u16*   wvT  = (u16*)(ws + 14*M1 + M1/2);
    float* ubuf = ws + 18*M1;
    float* xdbl = ws + 26*M1;
    float* dtb  = ws + 26*M1 + M1/2;
    u16*   ipb  = (u16*)dtb;
    float* pbuf = ws + 34*M1 + M1/2;                 // 3M floats
    u16*   xdb16 = (u16*)(ws + 34*M1 + M1/2);        // 256K u16
    u16*   dtw16 = (u16*)(ws + 34*M1 + M1/2 + 128*1024);  // 128K u16
    float2* PCbuf = (float2*)(ws + 34*M1 + M1/2);    // 2M float2
    float* hst  = ws + 38*M1 + M1/2;                 // 2M floats
    u16*   ybb  = (u16*)(ws + 36*M1 + M1/2);
    size_t need = (40*M1 + M1/2) * sizeof(float);    // 162 MiB
    if (ws_size < need) return;

    dim3 blk(256);
    const long long LD  = (long long)SEQ_L * D_MODEL;   // 2M
    const long long LL  = (long long)SEQ_L * SEQ_L;     // 4M
    const int NXP = MTOK * 96;                          // 393216

    // 1. xnb = bf16(rmsnorm(x))
    rmsnorm_b_kernel<<<MTOK, blk, 0, stream>>>(x, norm_w, xnb);
    // 2. ipb = bf16(in_proj_w)
    cvt_bf16_kernel<<<(2*DINNER*D_MODEL/4 + 255)/256, blk, 0, stream>>>(in_proj, ipb, 2*DINNER*D_MODEL/4);
    // 3. xzb = bf16(xnb @ ipb^T)  [4096x4096, K=1024]
    mfma_nt_kernel<1><<<dim3(32, 32, 1), blk, 0, stream>>>(
        xnb, D_MODEL, 0, ipb, D_MODEL, 0, nullptr, xzb, 2*DINNER, 0, D_MODEL, nullptr);
    // 4. u = silu(conv(xm)+b)  (bf16 in, f32 out)
    conv_silu_kernel<<<(MTOK*DINNER/4)/256, blk, 0, stream>>>(xzb, conv_w, conv_b, ubuf);
    // 5. xdbl = u @ x_proj^T  [4096x96, K=2048] f32, split-K 8 -> reduce
    gemm_kernel<1,0><<<dim3(2, MTOK/BM, 8), blk, 0, stream>>>(
        ubuf, DINNER, x_proj, DINNER, pbuf, 96, MTOK, 96, DINNER/8, nullptr, (long long)NXP);
    reduce8_kernel<<<(NXP + 255)/256, blk, 0, stream>>>(pbuf, xdbl, NXP);
    // 6. dt = softplus(xdbl[:,:64] @ dt_proj^T + b) via bf16 MFMA  [4096x2048, K=64]
    cvt_bf16_kernel<<<(DINNER*DTRANK/4 + 255)/256, blk, 0, stream>>>(dt_projw, dtw16, DINNER*DTRANK/4);
    cvt_slice64_kernel<<<(MTOK*16)/256, blk, 0, stream>>>(xdbl, xdb16);
    mfma_nt_kernel<4><<<dim3(DINNER/128, MTOK/128, 1), blk, 0, stream>>>(
        xdb16, DTRANK, 0, dtw16, DTRANK, 0, dtb, nullptr, DINNER, 0, DTRANK, dt_projb);
    // 7. chunked selective scan (lane-owns-channel): dtb(dt) -> dtb(y)
    scanA_kernel<<<dim3(16, NCHUNK), blk, 0, stream>>>(dtb, ubuf, xdbl, A_log, PCbuf);
    scanB_kernel<<<256, blk, 0, stream>>>(PCbuf, hst);
    scanC_kernel<<<dim3(16, NCHUNK), blk, 0, stream>>>(dtb, ubuf, xdbl, A_log, hst);
    // 8. ybb = bf16((y + u*D) * silu(z))  (z bf16)
    gate_b_kernel<<<(MTOK*DINNER/4)/256, blk, 0, stream>>>(dtb, ubuf, D_param, xzb, ybb);
    // 8b. opb = bf16(out_proj_w); wkT/wvT = bf16(Wk^T / Wv^T)
    cvt_bf16_kernel<<<(D_MODEL*DINNER/4 + 255)/256, blk, 0, stream>>>(out_proj, opb, D_MODEL*DINNER/4);
    transpose_b16_kernel<float><<<dim3(32, 32, 1), blk, 0, stream>>>(Wk, wkT, D_MODEL, D_MODEL, 0, 0);
    transpose_b16_kernel<float><<<dim3(32, 32, 1), blk, 0, stream>>>(Wv, wvT, D_MODEL, D_MODEL, 0, 0);
    // 9. out = x + ybb @ opb^T  [4096x1024, K=2048]
    mfma_nt_kernel<2><<<dim3(8, 32, 1), blk, 0, stream>>>(
        ybb, DINNER, 0, opb, DINNER, 0, out, nullptr, D_MODEL, 0, DINNER, x);
    // 10. xnb2 = bf16(rmsnorm(out))
    rmsnorm_b_kernel<<<MTOK, blk, 0, stream>>>(out, hebb_w, xnb2);
    // 11. kb16 = xnb2 @ wkT^T  (= xn @ Wk)  [4096x1024, K=1024] bf16
    mfma_nt_kernel<1><<<dim3(8, 32, 1), blk, 0, stream>>>(
        xnb2, D_MODEL, 0, wkT, D_MODEL, 0, nullptr, kb16, D_MODEL, 0, D_MODEL, nullptr);
    // 12. vb16 = xnb2 @ wvT^T  [4096x1024, K=1024] bf16
    mfma_nt_kernel<1><<<dim3(8, 32, 1), blk, 0, stream>>>(
        xnb2, D_MODEL, 0, wvT, D_MODEL, 0, nullptr, vb16, D_MODEL, 0, D_MODEL, nullptr);
    // 13. vT16[b] = vb16[b]^T  ([2048x1024] -> [1024x2048])
    transpose_b16_kernel<u16><<<dim3(32, 64, BATCH), blk, 0, stream>>>(
        vb16, vT16, SEQ_L, D_MODEL, LD, LD);
    // 14. scb16[b] = decay_mask .* (xnb2[b] @ kb16[b]^T)  [2048x2048, K=1024] bf16
    mfma_nt_kernel<3><<<dim3(16, 16, BATCH), blk, 0, stream>>>(
        xnb2, D_MODEL, LD, kb16, D_MODEL, LD, nullptr, scb16, SEQ_L, LL, D_MODEL, nullptr);
    // 15. out[b] += scb16[b] @ vT16[b]^T  [2048x1024, K=2048]
    mfma_nt_kernel<2><<<dim3(8, 16, BATCH), blk, 0, stream>>>(
        scb16, SEQ_L, LL, vT16, SEQ_L, LD, out, nullptr, D_MODEL, LD, SEQ_L, out);
}

// Round 11
// 433.299 us; speedup vs baseline: 6.0584x; 1.0120x over previous
//
#include <hip/hip_runtime.h>
#include <hip/hip_bf16.h>
#include <math.h>

#define D_MODEL 1024
#define SEQ_L   2048
#define BATCH   2
#define NSTATE  16
#define DCONV   4
#define DINNER  2048
#define DTRANK  64
#define ETA_C   0.1f
#define DECAY_C 0.95f
#define EPS_C   1e-5f
#define MTOK    (BATCH*SEQ_L)   // 4096
#define LOG2_DECAY (-0.07400058144377693f)

typedef unsigned short u16;
typedef __attribute__((ext_vector_type(8))) short bf16x8;
typedef __attribute__((ext_vector_type(4))) float f32x4;

__device__ inline u16 f2b(float f) {
    __hip_bfloat16 h = __float2bfloat16(f);
    return *reinterpret_cast<u16*>(&h);
}
__device__ inline float b2f(u16 u) {
    unsigned int x = ((unsigned int)u) << 16;
    return __uint_as_float(x);
}
__device__ inline float silu_f(float z) { return z / (1.0f + expf(-z)); }

// global->LDS direct DMA, 16B per lane. LDS dest = wave-uniform base + lane*16.
#define GLL16(gsrc, ldst) \
    __builtin_amdgcn_global_load_lds((const __attribute__((address_space(1))) void*)(gsrc), \
                                     (__attribute__((address_space(3))) void*)(ldst), 16, 0, 0)

// ---------------- rmsnorm -> bf16 out: one block per row ---------------------
__global__ __launch_bounds__(256)
void rmsnorm_b_kernel(const float* __restrict__ in, const float* __restrict__ w,
                      u16* __restrict__ outb)
{
    int row = blockIdx.x;
    int t = threadIdx.x;
    const float4* ip = (const float4*)(in + (size_t)row * D_MODEL);
    float4 v = ip[t];
    float ss = v.x*v.x + v.y*v.y + v.z*v.z + v.w*v.w;
    #pragma unroll
    for (int m = 1; m < 64; m <<= 1) ss += __shfl_xor(ss, m);
    __shared__ float red[4];
    if ((t & 63) == 0) red[t >> 6] = ss;
    __syncthreads();
    float total = red[0] + red[1] + red[2] + red[3];
    float sc = rsqrtf(total * (1.0f / D_MODEL) + EPS_C);
    float4 wv = ((const float4*)w)[t];
    ushort4 o;
    o.x = f2b(v.x * sc * wv.x); o.y = f2b(v.y * sc * wv.y);
    o.z = f2b(v.z * sc * wv.z); o.w = f2b(v.w * sc * wv.w);
    ((ushort4*)(outb + (size_t)row * D_MODEL))[t] = o;
}

// ---------------- plain f32 -> bf16 convert (vector4) ------------------------
__global__ __launch_bounds__(256)
void cvt_bf16_kernel(const float* __restrict__ in, u16* __restrict__ out, int n4)
{
    int i = blockIdx.x * 256 + threadIdx.x;
    if (i >= n4) return;
    float4 v = *(const float4*)(in + (size_t)i * 4);
    ushort4 o; o.x = f2b(v.x); o.y = f2b(v.y); o.z = f2b(v.z); o.w = f2b(v.w);
    *(ushort4*)(out + (size_t)i * 4) = o;
}

// ---------------- cvt slice: [R][96] f32 cols 0..63 -> [R][64] bf16 ----------
__global__ __launch_bounds__(256)
void cvt_slice64_kernel(const float* __restrict__ in, u16* __restrict__ out)
{
    int i = blockIdx.x * 256 + threadIdx.x;     // R*16
    int row = i >> 4, c4 = (i & 15) << 2;
    float4 v = *(const float4*)(in + (size_t)row * 96 + c4);
    ushort4 o; o.x = f2b(v.x); o.y = f2b(v.y); o.z = f2b(v.z); o.w = f2b(v.w);
    *(ushort4*)(out + (size_t)row * 64 + c4) = o;
}

// ---------------- tiled transpose -> bf16 (f32 or bf16 input) ----------------
__device__ inline u16 to_b16(float v) { return f2b(v); }
__device__ inline u16 to_b16(u16 v)   { return v; }

template<typename TIN>
__global__ __launch_bounds__(256)
void transpose_b16_kernel(const TIN* __restrict__ in, u16* __restrict__ outT,
                          int R, int C, long long sIn, long long sOut)
{
    __shared__ u16 tile[32][34];
    in   += (size_t)blockIdx.z * sIn;
    outT += (size_t)blockIdx.z * sOut;
    int c0 = blockIdx.x * 32, r0 = blockIdx.y * 32;
    int tx = threadIdx.x & 31, ty = threadIdx.x >> 5;   // ty 0..7
    #pragma unroll
    for (int i = 0; i < 4; ++i)
        tile[ty + 8*i][tx] = to_b16(in[(size_t)(r0 + ty + 8*i) * C + c0 + tx]);
    __syncthreads();
    #pragma unroll
    for (int i = 0; i < 4; ++i)
        outT[(size_t)(c0 + ty + 8*i) * R + r0 + tx] = tile[tx][ty + 8*i];
}

// ---------------- depthwise causal conv (DC=4) + silu, bf16 in, f32 out ------
__global__ __launch_bounds__(256)
void conv_silu_kernel(const u16* __restrict__ xzb, const float* __restrict__ cw,
                      const float* __restrict__ cb, float* __restrict__ u)
{
    int i4 = blockIdx.x * 256 + threadIdx.x;        // B*L*DI/4 = 2M
    int d4 = (i4 & 511) << 2;                       // d in [0,2048) step 4
    int row = i4 >> 9;                              // b*L + l
    int l = row & (SEQ_L - 1);
    const u16* base = xzb + (size_t)row * (2*DINNER) + d4;
    float4 cbv = *(const float4*)(cb + d4);
    float s[4] = {cbv.x, cbv.y, cbv.z, cbv.w};
    float4 w0 = *(const float4*)(cw + (d4+0)*DCONV);
    float4 w1 = *(const float4*)(cw + (d4+1)*DCONV);
    float4 w2 = *(const float4*)(cw + (d4+2)*DCONV);
    float4 w3 = *(const float4*)(cw + (d4+3)*DCONV);
    const float* wj[4] = {(const float*)&w0, (const float*)&w1,
                          (const float*)&w2, (const float*)&w3};
    #pragma unroll
    for (int j = 0; j < DCONV; ++j) {
        int lj = l - (DCONV-1) + j;
        if (lj >= 0) {
            ushort4 xv = *(const ushort4*)(base + (size_t)(lj - l) * (2*DINNER));
            s[0] = fmaf(wj[0][j], b2f(xv.x), s[0]);
            s[1] = fmaf(wj[1][j], b2f(xv.y), s[1]);
            s[2] = fmaf(wj[2][j], b2f(xv.z), s[2]);
            s[3] = fmaf(wj[3][j], b2f(xv.w), s[3]);
        }
    }
    float4 o;
    o.x = s[0] / (1.0f + expf(-s[0]));
    o.y = s[1] / (1.0f + expf(-s[1]));
    o.z = s[2] / (1.0f + expf(-s[2]));
    o.w = s[3] / (1.0f + expf(-s[3]));
    *(float4*)(u + (size_t)i4 * 4) = o;
}

// ---------------- chunked selective scan (3 passes), lane-owns-channel -------
#define NCHUNK 32
#define CHLEN  64

__global__ __launch_bounds__(256)
void scanA_kernel(const float* __restrict__ dt, const float* __restrict__ u,
                  const float* __restrict__ xdbl, const float* __restrict__ A_log,
                  float2* __restrict__ PC)
{
    int flat = blockIdx.x * 256 + threadIdx.x;      // B*DI = 4096
    int chunk = blockIdx.y;
    int d = flat & (DINNER - 1);
    int b = flat >> 11;
    float Aa[NSTATE], Pv[NSTATE], cv[NSTATE];
    #pragma unroll
    for (int s = 0; s < NSTATE; ++s) {
        Aa[s] = -expf(A_log[d * NSTATE + s]);
        Pv[s] = 1.0f; cv[s] = 0.0f;
    }
    const float* dtp = dt + ((size_t)b * SEQ_L) * DINNER + d;
    const float* up  = u  + ((size_t)b * SEQ_L) * DINNER + d;
    const float* xdp = xdbl + (size_t)b * SEQ_L * 96 + DTRANK;
    int t0 = chunk * CHLEN;
    #pragma unroll 2
    for (int t = t0; t < t0 + CHLEN; ++t) {
        float dtv = dtp[(size_t)t * DINNER];
        float uv  = up [(size_t)t * DINNER];
        float du = dtv * uv;
        float Bv[NSTATE];
        *(float4*)&Bv[0]  = *(const float4*)(xdp + t * 96);
        *(float4*)&Bv[4]  = *(const float4*)(xdp + t * 96 + 4);
        *(float4*)&Bv[8]  = *(const float4*)(xdp + t * 96 + 8);
        *(float4*)&Bv[12] = *(const float4*)(xdp + t * 96 + 12);
        #pragma unroll
        for (int s = 0; s < NSTATE; ++s) {
            float e = __expf(dtv * Aa[s]);
            Pv[s] *= e;
            cv[s] = fmaf(cv[s], e, du * Bv[s]);
        }
    }
    #pragma unroll
    for (int s = 0; s < NSTATE; ++s) {
        size_t o = (((size_t)chunk * BATCH + b) * NSTATE + s) * DINNER + d;
        PC[o] = make_float2(Pv[s], cv[s]);
    }
}

__global__ __launch_bounds__(256)
void scanB_kernel(const float2* __restrict__ PC, float* __restrict__ hst)
{
    int flat = blockIdx.x * 256 + threadIdx.x;      // B*NSTATE*DINNER = 65536
    int d = flat & (DINNER - 1);
    int s = (flat >> 11) & (NSTATE - 1);
    int b = flat >> 15;
    float h = 0.0f;
    #pragma unroll
    for (int ch = 0; ch < NCHUNK; ++ch) {
        size_t o = (((size_t)ch * BATCH + b) * NSTATE + s) * DINNER + d;
        hst[o] = h;
        float2 pc = PC[o];
        h = pc.x * h + pc.y;
    }
}

__global__ __launch_bounds__(256)
void scanC_kernel(float* dty, const float* __restrict__ u,
                  const float* __restrict__ xdbl, const float* __restrict__ A_log,
                  const float* __restrict__ hst)
{
    int flat = blockIdx.x * 256 + threadIdx.x;      // B*DI = 4096
    int chunk = blockIdx.y;
    int d = flat & (DINNER - 1);
    int b = flat >> 11;
    float Aa[NSTATE], h[NSTATE];
    #pragma unroll
    for (int s = 0; s < NSTATE; ++s) {
        Aa[s] = -expf(A_log[d * NSTATE + s]);
        h[s] = hst[(((size_t)chunk * BATCH + b) * NSTATE + s) * DINNER + d];
    }
    float* dtp = dty + ((size_t)b * SEQ_L) * DINNER + d;
    const float* up  = u  + ((size_t)b * SEQ_L) * DINNER + d;
    const float* xdp = xdbl + (size_t)b * SEQ_L * 96 + DTRANK;
    int t0 = chunk * CHLEN;
    #pragma unroll 2
    for (int t = t0; t < t0 + CHLEN; ++t) {
        float dtv = dtp[(size_t)t * DINNER];
        float uv  = up [(size_t)t * DINNER];
        float du = dtv * uv;
        float Bv[NSTATE], Cv[NSTATE];
        *(float4*)&Bv[0]  = *(const float4*)(xdp + t * 96);
        *(float4*)&Bv[4]  = *(const float4*)(xdp + t * 96 + 4);
        *(float4*)&Bv[8]  = *(const float4*)(xdp + t * 96 + 8);
        *(float4*)&Bv[12] = *(const float4*)(xdp + t * 96 + 12);
        *(float4*)&Cv[0]  = *(const float4*)(xdp + t * 96 + 16);
        *(float4*)&Cv[4]  = *(const float4*)(xdp + t * 96 + 20);
        *(float4*)&Cv[8]  = *(const float4*)(xdp + t * 96 + 24);
        *(float4*)&Cv[12] = *(const float4*)(xdp + t * 96 + 28);
        float y = 0.0f;
        #pragma unroll
        for (int s = 0; s < NSTATE; ++s) {
            float e = __expf(dtv * Aa[s]);
            h[s] = fmaf(h[s], e, du * Bv[s]);
            y = fmaf(h[s], Cv[s], y);
        }
        dtp[(size_t)t * DINNER] = y;
    }
}

// ---------------- y = (y + u*D) * silu(z) -> bf16  (z bf16) ------------------
__global__ __launch_bounds__(256)
void gate_b_kernel(const float* __restrict__ y, const float* __restrict__ u,
                   const float* __restrict__ Dp, const u16* __restrict__ xzb,
                   u16* __restrict__ yb)
{
    int i4 = blockIdx.x * 256 + threadIdx.x;        // B*L*DI/4 = 2M
    int d4 = (i4 & 511) << 2;
    int row = i4 >> 9;
    float4 yv = *(const float4*)(y + (size_t)i4 * 4);
    float4 uv = *(const float4*)(u + (size_t)i4 * 4);
    ushort4 zb = *(const ushort4*)(xzb + (size_t)row * (2*DINNER) + DINNER + d4);
    float4 dv = *(const float4*)(Dp + d4);
    ushort4 o;
    o.x = f2b((yv.x + uv.x * dv.x) * silu_f(b2f(zb.x)));
    o.y = f2b((yv.y + uv.y * dv.y) * silu_f(b2f(zb.y)));
    o.z = f2b((yv.z + uv.z * dv.z) * silu_f(b2f(zb.z)));
    o.w = f2b((yv.w + uv.w * dv.w) * silu_f(b2f(zb.w)));
    *(ushort4*)(yb + (size_t)i4 * 4) = o;
}

// ---------------- f32 tiled GEMM with optional split-K -----------------------
#define BM 64
#define BN 64
#define BK 16

template<int TRANSB, int EPI>
__global__ __launch_bounds__(256)
void gemm_kernel(const float* __restrict__ A, int lda,
                 const float* __restrict__ B, int ldb,
                 float* __restrict__ C, int ldc,
                 int M, int N, int Kc, const float* __restrict__ bias,
                 long long sCz)
{
    __shared__ float As[BK][BM + 4];
    __shared__ float Bs[BK][BN + 4];
    C += (size_t)blockIdx.z * sCz;
    int kOff = blockIdx.z * Kc;
    int m0 = blockIdx.y * BM, n0 = blockIdx.x * BN;
    int t = threadIdx.x;
    int tx = t & 15, ty = t >> 4;
    int rA = t >> 2, c4 = (t & 3) << 2;
    float acc[4][4] = {};
    for (int k0 = kOff; k0 < kOff + Kc; k0 += BK) {
        float4 av = make_float4(0.f,0.f,0.f,0.f);
        if (m0 + rA < M) av = *(const float4*)(A + (size_t)(m0 + rA) * lda + k0 + c4);
        As[c4+0][rA] = av.x; As[c4+1][rA] = av.y; As[c4+2][rA] = av.z; As[c4+3][rA] = av.w;
        float4 bv = make_float4(0.f,0.f,0.f,0.f);
        if (n0 + rA < N) bv = *(const float4*)(B + (size_t)(n0 + rA) * ldb + k0 + c4);
        Bs[c4+0][rA] = bv.x; Bs[c4+1][rA] = bv.y; Bs[c4+2][rA] = bv.z; Bs[c4+3][rA] = bv.w;
        __syncthreads();
        #pragma unroll
        for (int kk = 0; kk < BK; ++kk) {
            float4 a4 = *(const float4*)&As[kk][ty << 2];
            float4 b4 = *(const float4*)&Bs[kk][tx << 2];
            float a[4] = {a4.x, a4.y, a4.z, a4.w};
            float b[4] = {b4.x, b4.y, b4.z, b4.w};
            #pragma unroll
            for (int i = 0; i < 4; ++i)
                #pragma unroll
                for (int j = 0; j < 4; ++j)
                    acc[i][j] = fmaf(a[i], b[j], acc[i][j]);
        }
        __syncthreads();
    }
    #pragma unroll
    for (int i = 0; i < 4; ++i) {
        int m = m0 + (ty << 2) + i;
        if (m >= M) continue;
        #pragma unroll
        for (int j = 0; j < 4; ++j) {
            int n = n0 + (tx << 2) + j;
            if (n >= N) continue;
            float v = acc[i][j];
            if (EPI == 1) {
                float xv = v + bias[n];
                v = fmaxf(xv, 0.0f) + log1pf(expf(-fabsf(xv)));
            }
            C[(size_t)m * ldc + n] = v;
        }
    }
}

// ---------------- deterministic 8-way split-K reduce -------------------------
__global__ __launch_bounds__(256)
void reduce8_kernel(const float* __restrict__ p, float* __restrict__ o, int n)
{
    int i = blockIdx.x * 256 + threadIdx.x;
    if (i >= n) return;
    float s = 0.0f;
    #pragma unroll
    for (int z = 0; z < 8; ++z) s += p[(size_t)z * n + i];
    o[i] = s;
}

// ---------------- bf16 MFMA NT GEMM (m97 structure) --------------------------
// C[m,n] = sum_k A[m,k]*B[n,k], A:[M,K] bf16 row-major, B:[N,K] bf16 row-major.
// 128x128 tile, 4 waves, BK=64, global_load_lds staging, swizzled LDS.
// EPI: 0 = f32 store, 1 = bf16 store, 2 = f32 Src+acc store,
//      3 = bf16 store of acc * decay_mask(m,n),
//      4 = f32 store of softplus(acc + Src[n])   (Src = bias)
// TRI: 1 = skip blocks with n0 > m0 (output strictly lower-tri + diag; for
//          the masked scores GEMM — skipped tiles are never read downstream),
//      2 = cap K at m0+128 (A columns k >= m0+128 are known-zero; scores@v)
template<int EPI, int SWZ = 0, int TRI = 0>
__global__ __launch_bounds__(256)
void mfma_nt_kernel(const u16* __restrict__ A, int lda, long long sA,
                    const u16* __restrict__ B, int ldb, long long sB,
                    float* __restrict__ Cf, u16* __restrict__ Cb, int ldc, long long sC,
                    int K, const float* __restrict__ Src)
{
    __shared__ u16 As[128 * 64];
    __shared__ u16 Bs[128 * 64];
    int bz = blockIdx.z;
    A += (size_t)bz * sA; B += (size_t)bz * sB;
    if (EPI == 1 || EPI == 3) Cb += (size_t)bz * sC; else Cf += (size_t)bz * sC;
    if (EPI == 2) Src += (size_t)bz * sC;
    int bx = blockIdx.x, by = blockIdx.y;
    if (SWZ) {
        int gx = gridDim.x;
        int nwg = gx * gridDim.y;
        int flat = by * gx + bx;
        int swz = (flat & 7) * (nwg >> 3) + (flat >> 3);   // nwg % 8 == 0
        bx = swz % gx; by = swz / gx;
    }
    int m0 = by * 128, n0 = bx * 128;
    if (TRI == 1 && n0 > m0) return;        // zero tile: never computed nor read
    int t = threadIdx.x;
    int lane = t & 63, w = t >> 6;
    int wm = (w >> 1) * 64, wn = (w & 1) * 64;
    int l15 = lane & 15, lhi = lane >> 4;

    int lrow = lane >> 3;                                   // 0..7
    int scol = ((lane & 7) ^ lrow) << 3;                    // pre-swizzled source col (u16)

    f32x4 acc[4][4] = {};
    int Keff = (TRI == 2) ? (m0 + 128 < K ? m0 + 128 : K) : K;
    const int nk = Keff >> 6;

    for (int kt = 0; kt < nk; ++kt) {
        int kb = kt << 6;
        #pragma unroll
        for (int q = 0; q < 4; ++q) {
            int c = (q << 2) + w;                           // chunk 0..15
            int row = (c << 3) + lrow;
            GLL16(A + (size_t)(m0 + row) * lda + kb + scol, &As[c << 9]);
            GLL16(B + (size_t)(n0 + row) * ldb + kb + scol, &Bs[c << 9]);
        }
        __syncthreads();
        #pragma unroll
        for (int ks = 0; ks < 2; ++ks) {
            int csw = (ks * 32 + lhi * 8) ^ ((l15 & 7) << 3);  // swizzled u16 col
            bf16x8 af[4], bfr[4];
            #pragma unroll
            for (int f = 0; f < 4; ++f) {
                af[f]  = *(const bf16x8*)&As[(wm + f*16 + l15) * 64 + csw];
                bfr[f] = *(const bf16x8*)&Bs[(wn + f*16 + l15) * 64 + csw];
            }
            #pragma unroll
            for (int i = 0; i < 4; ++i)
                #pragma unroll
                for (int j = 0; j < 4; ++j)
                    acc[i][j] = __builtin_amdgcn_mfma_f32_16x16x32_bf16(
                                    af[i], bfr[j], acc[i][j], 0, 0, 0);
        }
        __syncthreads();
    }
    int rb0 = m0 + wm + lhi * 4;
    int cb0 = n0 + wn + l15;
    #pragma unroll
    for (int mf = 0; mf < 4; ++mf) {
        #pragma unroll
        for (int nf = 0; nf < 4; ++nf) {
            #pragma unroll
            for (int i = 0; i < 4; ++i) {
                int r = rb0 + mf * 16 + i;
                int cc = cb0 + nf * 16;
                float v = acc[mf][nf][i];
                if (EPI == 0) {
                    Cf[(size_t)r * ldc + cc] = v;
                } else if (EPI == 1) {
                    Cb[(size_t)r * ldc + cc] = f2b(v);
                } else if (EPI == 2) {
                    Cf[(size_t)r * ldc + cc] = Src[(size_t)r * ldc + cc] + v;
                } else if (EPI == 4) {
                    float xv = v + Src[cc];
                    Cf[(size_t)r * ldc + cc] = fmaxf(xv, 0.0f) + log1pf(expf(-fabsf(xv)));
                } else {
                    float wv = (cc < r) ? ETA_C * exp2f((float)(r - 1 - cc) * LOG2_DECAY) : 0.0f;
                    Cb[(size_t)r * ldc + cc] = f2b(v * wv);
                }
            }
        }
    }
}

extern "C" void kernel_launch(void* const* d_in, const int* in_sizes, int n_in,
                              void* d_out, int out_size, void* d_ws, size_t ws_size,
                              hipStream_t stream)
{
    const float* x        = (const float*)d_in[0];
    const float* norm_w   = (const float*)d_in[1];
    const float* in_proj  = (const float*)d_in[2];
    const float* conv_w   = (const float*)d_in[3];
    const float* conv_b   = (const float*)d_in[4];
    const float* x_proj   = (const float*)d_in[5];
    const float* dt_projw = (const float*)d_in[6];
    const float* dt_projb = (const float*)d_in[7];
    const float* A_log    = (const float*)d_in[8];
    const float* D_param  = (const float*)d_in[9];
    const float* out_proj = (const float*)d_in[10];
    const float* hebb_w   = (const float*)d_in[11];
    const float* Wk       = (const float*)d_in[12];
    const float* Wv       = (const float*)d_in[13];
    float* out = (float*)d_out;

    // ---- workspace layout (float units, M1 = 1Mi floats) ----
    float* ws = (float*)d_ws;
    const size_t M1 = 1024 * 1024;
    u16*   xnb  = (u16*)ws;
    u16*   opb  = (u16*)ws;
    u16*   xzb  = (u16*)(ws + 2*M1);
    u16*   xnb2 = (u16*)(ws + 2*M1);
    u16*   kb16 = (u16*)(ws + 4*M1);
    u16*   vb16 = (u16*)(ws + 6*M1);
    u16*   vT16 = (u16*)(ws + 8*M1);
    u16*   scb16= (u16*)(ws + 10*M1);
    u16*   wkT  = (u16*)(ws + 14*M1);
    u16*   wvT  = (u16*)(ws + 14*M1 + M1/2);
    float* ubuf = ws + 18*M1;
    float* xdbl = ws + 26*M1;
    float* dtb  = ws + 26*M1 + M1/2;
    u16*   ipb  = (u16*)dtb;
    float* pbuf = ws + 34*M1 + M1/2;                 // 3M floats
    u16*   xdb16 = (u16*)(ws + 34*M1 + M1/2);        // 256K u16
    u16*   dtw16 = (u16*)(ws + 34*M1 + M1/2 + 128*1024);  // 128K u16
    float2* PCbuf = (float2*)(ws + 34*M1 + M1/2);    // 2M float2
    float* hst  = ws + 38*M1 + M1/2;                 // 2M floats
    u16*   ybb  = (u16*)(ws + 36*M1 + M1/2);
    size_t need = (40*M1 + M1/2) * sizeof(float);    // 162 MiB
    if (ws_size < need) return;

    dim3 blk(256);
    const long long LD  = (long long)SEQ_L * D_MODEL;   // 2M
    const long long LL  = (long long)SEQ_L * SEQ_L;     // 4M
    const int NXP = MTOK * 96;                          // 393216

    // 1. xnb = bf16(rmsnorm(x))
    rmsnorm_b_kernel<<<MTOK, blk, 0, stream>>>(x, norm_w, xnb);
    // 2. ipb = bf16(in_proj_w)
    cvt_bf16_kernel<<<(2*DINNER*D_MODEL/4 + 255)/256, blk, 0, stream>>>(in_proj, ipb, 2*DINNER*D_MODEL/4);
    // 3. xzb = bf16(xnb @ ipb^T)  [4096x4096, K=1024]
    mfma_nt_kernel<1><<<dim3(32, 32, 1), blk, 0, stream>>>(
        xnb, D_MODEL, 0, ipb, D_MODEL, 0, nullptr, xzb, 2*DINNER, 0, D_MODEL, nullptr);
    // 4. u = silu(conv(xm)+b)  (bf16 in, f32 out)
    conv_silu_kernel<<<(MTOK*DINNER/4)/256, blk, 0, stream>>>(xzb, conv_w, conv_b, ubuf);
    // 5. xdbl = u @ x_proj^T  [4096x96, K=2048] f32, split-K 8 -> reduce
    gemm_kernel<1,0><<<dim3(2, MTOK/BM, 8), blk, 0, stream>>>(
        ubuf, DINNER, x_proj, DINNER, pbuf, 96, MTOK, 96, DINNER/8, nullptr, (long long)NXP);
    reduce8_kernel<<<(NXP + 255)/256, blk, 0, stream>>>(pbuf, xdbl, NXP);
    // 6. dt = softplus(xdbl[:,:64] @ dt_proj^T + b) via bf16 MFMA  [4096x2048, K=64]
    cvt_bf16_kernel<<<(DINNER*DTRANK/4 + 255)/256, blk, 0, stream>>>(dt_projw, dtw16, DINNER*DTRANK/4);
    cvt_slice64_kernel<<<(MTOK*16)/256, blk, 0, stream>>>(xdbl, xdb16);
    mfma_nt_kernel<4><<<dim3(DINNER/128, MTOK/128, 1), blk, 0, stream>>>(
        xdb16, DTRANK, 0, dtw16, DTRANK, 0, dtb, nullptr, DINNER, 0, DTRANK, dt_projb);
    // 7. chunked selective scan (lane-owns-channel): dtb(dt) -> dtb(y)
    scanA_kernel<<<dim3(16, NCHUNK), blk, 0, stream>>>(dtb, ubuf, xdbl, A_log, PCbuf);
    scanB_kernel<<<256, blk, 0, stream>>>(PCbuf, hst);
    scanC_kernel<<<dim3(16, NCHUNK), blk, 0, stream>>>(dtb, ubuf, xdbl, A_log, hst);
    // 8. ybb = bf16((y + u*D) * silu(z))  (z bf16)
    gate_b_kernel<<<(MTOK*DINNER/4)/256, blk, 0, stream>>>(dtb, ubuf, D_param, xzb, ybb);
    // 8b. opb = bf16(out_proj_w); wkT/wvT = bf16(Wk^T / Wv^T)
    cvt_bf16_kernel<<<(D_MODEL*DINNER/4 + 255)/256, blk, 0, stream>>>(out_proj, opb, D_MODEL*DINNER/4);
    transpose_b16_kernel<float><<<dim3(32, 32, 1), blk, 0, stream>>>(Wk, wkT, D_MODEL, D_MODEL, 0, 0);
    transpose_b16_kernel<float><<<dim3(32, 32, 1), blk, 0, stream>>>(Wv, wvT, D_MODEL, D_MODEL, 0, 0);
    // 9. out = x + ybb @ opb^T  [4096x1024, K=2048]
    mfma_nt_kernel<2><<<dim3(8, 32, 1), blk, 0, stream>>>(
        ybb, DINNER, 0, opb, DINNER, 0, out, nullptr, D_MODEL, 0, DINNER, x);
    // 10. xnb2 = bf16(rmsnorm(out))
    rmsnorm_b_kernel<<<MTOK, blk, 0, stream>>>(out, hebb_w, xnb2);
    // 11. kb16 = xnb2 @ wkT^T  (= xn @ Wk)  [4096x1024, K=1024] bf16
    mfma_nt_kernel<1><<<dim3(8, 32, 1), blk, 0, stream>>>(
        xnb2, D_MODEL, 0, wkT, D_MODEL, 0, nullptr, kb16, D_MODEL, 0, D_MODEL, nullptr);
    // 12. vb16 = xnb2 @ wvT^T  [4096x1024, K=1024] bf16
    mfma_nt_kernel<1><<<dim3(8, 32, 1), blk, 0, stream>>>(
        xnb2, D_MODEL, 0, wvT, D_MODEL, 0, nullptr, vb16, D_MODEL, 0, D_MODEL, nullptr);
    // 13. vT16[b] = vb16[b]^T  ([2048x1024] -> [1024x2048])
    transpose_b16_kernel<u16><<<dim3(32, 64, BATCH), blk, 0, stream>>>(
        vb16, vT16, SEQ_L, D_MODEL, LD, LD);
    // 14. scb16[b] = decay_mask .* (xnb2[b] @ kb16[b]^T), lower-tri tiles only
    mfma_nt_kernel<3,0,1><<<dim3(16, 16, BATCH), blk, 0, stream>>>(
        xnb2, D_MODEL, LD, kb16, D_MODEL, LD, nullptr, scb16, SEQ_L, LL, D_MODEL, nullptr);
    // 15. out[b] += scb16[b] @ vT16[b]^T, K capped at m0+128 (scb upper = 0)
    mfma_nt_kernel<2,0,2><<<dim3(8, 16, BATCH), blk, 0, stream>>>(
        scb16, SEQ_L, LL, vT16, SEQ_L, LD, out, nullptr, D_MODEL, LD, SEQ_L, out);
}

// Round 12
// 409.677 us; speedup vs baseline: 6.4077x; 1.0577x over previous
//
#include <hip/hip_runtime.h>
#include <hip/hip_bf16.h>
#include <math.h>

#define D_MODEL 1024
#define SEQ_L   2048
#define BATCH   2
#define NSTATE  16
#define DCONV   4
#define DINNER  2048
#define DTRANK  64
#define ETA_C   0.1f
#define DECAY_C 0.95f
#define EPS_C   1e-5f
#define MTOK    (BATCH*SEQ_L)   // 4096
#define LOG2_DECAY (-0.07400058144377693f)

typedef unsigned short u16;
typedef __attribute__((ext_vector_type(8))) short bf16x8;
typedef __attribute__((ext_vector_type(4))) float f32x4;

__device__ inline u16 f2b(float f) {
    __hip_bfloat16 h = __float2bfloat16(f);
    return *reinterpret_cast<u16*>(&h);
}
__device__ inline float b2f(u16 u) {
    unsigned int x = ((unsigned int)u) << 16;
    return __uint_as_float(x);
}
__device__ inline float silu_f(float z) { return z / (1.0f + expf(-z)); }

// global->LDS direct DMA, 16B per lane. LDS dest = wave-uniform base + lane*16.
#define GLL16(gsrc, ldst) \
    __builtin_amdgcn_global_load_lds((const __attribute__((address_space(1))) void*)(gsrc), \
                                     (__attribute__((address_space(3))) void*)(ldst), 16, 0, 0)

// ---------------- rmsnorm -> bf16 out: one block per row ---------------------
__global__ __launch_bounds__(256)
void rmsnorm_b_kernel(const float* __restrict__ in, const float* __restrict__ w,
                      u16* __restrict__ outb)
{
    int row = blockIdx.x;
    int t = threadIdx.x;
    const float4* ip = (const float4*)(in + (size_t)row * D_MODEL);
    float4 v = ip[t];
    float ss = v.x*v.x + v.y*v.y + v.z*v.z + v.w*v.w;
    #pragma unroll
    for (int m = 1; m < 64; m <<= 1) ss += __shfl_xor(ss, m);
    __shared__ float red[4];
    if ((t & 63) == 0) red[t >> 6] = ss;
    __syncthreads();
    float total = red[0] + red[1] + red[2] + red[3];
    float sc = rsqrtf(total * (1.0f / D_MODEL) + EPS_C);
    float4 wv = ((const float4*)w)[t];
    ushort4 o;
    o.x = f2b(v.x * sc * wv.x); o.y = f2b(v.y * sc * wv.y);
    o.z = f2b(v.z * sc * wv.z); o.w = f2b(v.w * sc * wv.w);
    ((ushort4*)(outb + (size_t)row * D_MODEL))[t] = o;
}

// ---------------- plain f32 -> bf16 convert (vector4) ------------------------
__global__ __launch_bounds__(256)
void cvt_bf16_kernel(const float* __restrict__ in, u16* __restrict__ out, int n4)
{
    int i = blockIdx.x * 256 + threadIdx.x;
    if (i >= n4) return;
    float4 v = *(const float4*)(in + (size_t)i * 4);
    ushort4 o; o.x = f2b(v.x); o.y = f2b(v.y); o.z = f2b(v.z); o.w = f2b(v.w);
    *(ushort4*)(out + (size_t)i * 4) = o;
}

// ---------------- cvt slice: [R][96] f32 cols 0..63 -> [R][64] bf16 ----------
__global__ __launch_bounds__(256)
void cvt_slice64_kernel(const float* __restrict__ in, u16* __restrict__ out)
{
    int i = blockIdx.x * 256 + threadIdx.x;     // R*16
    int row = i >> 4, c4 = (i & 15) << 2;
    float4 v = *(const float4*)(in + (size_t)row * 96 + c4);
    ushort4 o; o.x = f2b(v.x); o.y = f2b(v.y); o.z = f2b(v.z); o.w = f2b(v.w);
    *(ushort4*)(out + (size_t)row * 64 + c4) = o;
}

// ---------------- tiled transpose -> bf16 (f32 or bf16 input), ld params -----
__device__ inline u16 to_b16(float v) { return f2b(v); }
__device__ inline u16 to_b16(u16 v)   { return v; }

template<typename TIN>
__global__ __launch_bounds__(256)
void transpose_b16_kernel(const TIN* __restrict__ in, u16* __restrict__ outT,
                          int ldIn, int ldOut, long long sIn, long long sOut)
{
    __shared__ u16 tile[32][34];
    in   += (size_t)blockIdx.z * sIn;
    outT += (size_t)blockIdx.z * sOut;
    int c0 = blockIdx.x * 32, r0 = blockIdx.y * 32;
    int tx = threadIdx.x & 31, ty = threadIdx.x >> 5;   // ty 0..7
    #pragma unroll
    for (int i = 0; i < 4; ++i)
        tile[ty + 8*i][tx] = to_b16(in[(size_t)(r0 + ty + 8*i) * ldIn + c0 + tx]);
    __syncthreads();
    #pragma unroll
    for (int i = 0; i < 4; ++i)
        outT[(size_t)(c0 + ty + 8*i) * ldOut + r0 + tx] = tile[tx][ty + 8*i];
}

// ---------------- depthwise causal conv (DC=4) + silu, bf16 in, f32 out ------
__global__ __launch_bounds__(256)
void conv_silu_kernel(const u16* __restrict__ xzb, const float* __restrict__ cw,
                      const float* __restrict__ cb, float* __restrict__ u)
{
    int i4 = blockIdx.x * 256 + threadIdx.x;        // B*L*DI/4 = 2M
    int d4 = (i4 & 511) << 2;                       // d in [0,2048) step 4
    int row = i4 >> 9;                              // b*L + l
    int l = row & (SEQ_L - 1);
    const u16* base = xzb + (size_t)row * (2*DINNER) + d4;
    float4 cbv = *(const float4*)(cb + d4);
    float s[4] = {cbv.x, cbv.y, cbv.z, cbv.w};
    float4 w0 = *(const float4*)(cw + (d4+0)*DCONV);
    float4 w1 = *(const float4*)(cw + (d4+1)*DCONV);
    float4 w2 = *(const float4*)(cw + (d4+2)*DCONV);
    float4 w3 = *(const float4*)(cw + (d4+3)*DCONV);
    const float* wj[4] = {(const float*)&w0, (const float*)&w1,
                          (const float*)&w2, (const float*)&w3};
    #pragma unroll
    for (int j = 0; j < DCONV; ++j) {
        int lj = l - (DCONV-1) + j;
        if (lj >= 0) {
            ushort4 xv = *(const ushort4*)(base + (size_t)(lj - l) * (2*DINNER));
            s[0] = fmaf(wj[0][j], b2f(xv.x), s[0]);
            s[1] = fmaf(wj[1][j], b2f(xv.y), s[1]);
            s[2] = fmaf(wj[2][j], b2f(xv.z), s[2]);
            s[3] = fmaf(wj[3][j], b2f(xv.w), s[3]);
        }
    }
    float4 o;
    o.x = s[0] / (1.0f + expf(-s[0]));
    o.y = s[1] / (1.0f + expf(-s[1]));
    o.z = s[2] / (1.0f + expf(-s[2]));
    o.w = s[3] / (1.0f + expf(-s[3]));
    *(float4*)(u + (size_t)i4 * 4) = o;
}

// ---------------- chunked selective scan (3 passes), lane-owns-channel -------
#define NCHUNK 32
#define CHLEN  64

__global__ __launch_bounds__(256)
void scanA_kernel(const float* __restrict__ dt, const float* __restrict__ u,
                  const float* __restrict__ xdbl, const float* __restrict__ A_log,
                  float2* __restrict__ PC)
{
    int flat = blockIdx.x * 256 + threadIdx.x;      // B*DI = 4096
    int chunk = blockIdx.y;
    int d = flat & (DINNER - 1);
    int b = flat >> 11;
    float Aa[NSTATE], Pv[NSTATE], cv[NSTATE];
    #pragma unroll
    for (int s = 0; s < NSTATE; ++s) {
        Aa[s] = -expf(A_log[d * NSTATE + s]);
        Pv[s] = 1.0f; cv[s] = 0.0f;
    }
    const float* dtp = dt + ((size_t)b * SEQ_L) * DINNER + d;
    const float* up  = u  + ((size_t)b * SEQ_L) * DINNER + d;
    const float* xdp = xdbl + (size_t)b * SEQ_L * 96 + DTRANK;
    int t0 = chunk * CHLEN;
    #pragma unroll 2
    for (int t = t0; t < t0 + CHLEN; ++t) {
        float dtv = dtp[(size_t)t * DINNER];
        float uv  = up [(size_t)t * DINNER];
        float du = dtv * uv;
        float Bv[NSTATE];
        *(float4*)&Bv[0]  = *(const float4*)(xdp + t * 96);
        *(float4*)&Bv[4]  = *(const float4*)(xdp + t * 96 + 4);
        *(float4*)&Bv[8]  = *(const float4*)(xdp + t * 96 + 8);
        *(float4*)&Bv[12] = *(const float4*)(xdp + t * 96 + 12);
        #pragma unroll
        for (int s = 0; s < NSTATE; ++s) {
            float e = __expf(dtv * Aa[s]);
            Pv[s] *= e;
            cv[s] = fmaf(cv[s], e, du * Bv[s]);
        }
    }
    #pragma unroll
    for (int s = 0; s < NSTATE; ++s) {
        size_t o = (((size_t)chunk * BATCH + b) * NSTATE + s) * DINNER + d;
        PC[o] = make_float2(Pv[s], cv[s]);
    }
}

__global__ __launch_bounds__(256)
void scanB_kernel(const float2* __restrict__ PC, float* __restrict__ hst)
{
    int flat = blockIdx.x * 256 + threadIdx.x;      // B*NSTATE*DINNER = 65536
    int d = flat & (DINNER - 1);
    int s = (flat >> 11) & (NSTATE - 1);
    int b = flat >> 15;
    float h = 0.0f;
    #pragma unroll
    for (int ch = 0; ch < NCHUNK; ++ch) {
        size_t o = (((size_t)ch * BATCH + b) * NSTATE + s) * DINNER + d;
        hst[o] = h;
        float2 pc = PC[o];
        h = pc.x * h + pc.y;
    }
}

// pass C fused with gate: y -> ybb = bf16((y + u*D) * silu(z)); dt left intact
__global__ __launch_bounds__(256)
void scanC_gate_kernel(const float* __restrict__ dt, const float* __restrict__ u,
                       const float* __restrict__ xdbl, const float* __restrict__ A_log,
                       const float* __restrict__ hst, const float* __restrict__ Dp,
                       const u16* __restrict__ xzb, u16* __restrict__ ybb)
{
    int flat = blockIdx.x * 256 + threadIdx.x;      // B*DI = 4096
    int chunk = blockIdx.y;
    int d = flat & (DINNER - 1);
    int b = flat >> 11;
    float Aa[NSTATE], h[NSTATE];
    #pragma unroll
    for (int s = 0; s < NSTATE; ++s) {
        Aa[s] = -expf(A_log[d * NSTATE + s]);
        h[s] = hst[(((size_t)chunk * BATCH + b) * NSTATE + s) * DINNER + d];
    }
    float Dv = Dp[d];
    const float* dtp = dt + ((size_t)b * SEQ_L) * DINNER + d;
    const float* up  = u  + ((size_t)b * SEQ_L) * DINNER + d;
    const float* xdp = xdbl + (size_t)b * SEQ_L * 96 + DTRANK;
    const u16* zp = xzb + ((size_t)b * SEQ_L) * (2*DINNER) + DINNER + d;
    u16* yp = ybb + ((size_t)b * SEQ_L) * DINNER + d;
    int t0 = chunk * CHLEN;
    #pragma unroll 2
    for (int t = t0; t < t0 + CHLEN; ++t) {
        float dtv = dtp[(size_t)t * DINNER];
        float uv  = up [(size_t)t * DINNER];
        float du = dtv * uv;
        float Bv[NSTATE], Cv[NSTATE];
        *(float4*)&Bv[0]  = *(const float4*)(xdp + t * 96);
        *(float4*)&Bv[4]  = *(const float4*)(xdp + t * 96 + 4);
        *(float4*)&Bv[8]  = *(const float4*)(xdp + t * 96 + 8);
        *(float4*)&Bv[12] = *(const float4*)(xdp + t * 96 + 12);
        *(float4*)&Cv[0]  = *(const float4*)(xdp + t * 96 + 16);
        *(float4*)&Cv[4]  = *(const float4*)(xdp + t * 96 + 20);
        *(float4*)&Cv[8]  = *(const float4*)(xdp + t * 96 + 24);
        *(float4*)&Cv[12] = *(const float4*)(xdp + t * 96 + 28);
        float y = 0.0f;
        #pragma unroll
        for (int s = 0; s < NSTATE; ++s) {
            float e = __expf(dtv * Aa[s]);
            h[s] = fmaf(h[s], e, du * Bv[s]);
            y = fmaf(h[s], Cv[s], y);
        }
        float z = b2f(zp[(size_t)t * (2*DINNER)]);
        yp[(size_t)t * DINNER] = f2b((y + uv * Dv) * silu_f(z));
    }
}

// ---------------- f32 tiled GEMM with optional split-K -----------------------
#define BM 64
#define BN 64
#define BK 16

template<int TRANSB, int EPI>
__global__ __launch_bounds__(256)
void gemm_kernel(const float* __restrict__ A, int lda,
                 const float* __restrict__ B, int ldb,
                 float* __restrict__ C, int ldc,
                 int M, int N, int Kc, const float* __restrict__ bias,
                 long long sCz)
{
    __shared__ float As[BK][BM + 4];
    __shared__ float Bs[BK][BN + 4];
    C += (size_t)blockIdx.z * sCz;
    int kOff = blockIdx.z * Kc;
    int m0 = blockIdx.y * BM, n0 = blockIdx.x * BN;
    int t = threadIdx.x;
    int tx = t & 15, ty = t >> 4;
    int rA = t >> 2, c4 = (t & 3) << 2;
    float acc[4][4] = {};
    for (int k0 = kOff; k0 < kOff + Kc; k0 += BK) {
        float4 av = make_float4(0.f,0.f,0.f,0.f);
        if (m0 + rA < M) av = *(const float4*)(A + (size_t)(m0 + rA) * lda + k0 + c4);
        As[c4+0][rA] = av.x; As[c4+1][rA] = av.y; As[c4+2][rA] = av.z; As[c4+3][rA] = av.w;
        float4 bv = make_float4(0.f,0.f,0.f,0.f);
        if (n0 + rA < N) bv = *(const float4*)(B + (size_t)(n0 + rA) * ldb + k0 + c4);
        Bs[c4+0][rA] = bv.x; Bs[c4+1][rA] = bv.y; Bs[c4+2][rA] = bv.z; Bs[c4+3][rA] = bv.w;
        __syncthreads();
        #pragma unroll
        for (int kk = 0; kk < BK; ++kk) {
            float4 a4 = *(const float4*)&As[kk][ty << 2];
            float4 b4 = *(const float4*)&Bs[kk][tx << 2];
            float a[4] = {a4.x, a4.y, a4.z, a4.w};
            float b[4] = {b4.x, b4.y, b4.z, b4.w};
            #pragma unroll
            for (int i = 0; i < 4; ++i)
                #pragma unroll
                for (int j = 0; j < 4; ++j)
                    acc[i][j] = fmaf(a[i], b[j], acc[i][j]);
        }
        __syncthreads();
    }
    #pragma unroll
    for (int i = 0; i < 4; ++i) {
        int m = m0 + (ty << 2) + i;
        if (m >= M) continue;
        #pragma unroll
        for (int j = 0; j < 4; ++j) {
            int n = n0 + (tx << 2) + j;
            if (n >= N) continue;
            float v = acc[i][j];
            if (EPI == 1) {
                float xv = v + bias[n];
                v = fmaxf(xv, 0.0f) + log1pf(expf(-fabsf(xv)));
            }
            C[(size_t)m * ldc + n] = v;
        }
    }
}

// ---------------- deterministic 8-way split-K reduce -------------------------
__global__ __launch_bounds__(256)
void reduce8_kernel(const float* __restrict__ p, float* __restrict__ o, int n)
{
    int i = blockIdx.x * 256 + threadIdx.x;
    if (i >= n) return;
    float s = 0.0f;
    #pragma unroll
    for (int z = 0; z < 8; ++z) s += p[(size_t)z * n + i];
    o[i] = s;
}

// ---------------- bf16 MFMA NT GEMM (m97 structure) --------------------------
// C[m,n] = sum_k A[m,k]*B[n,k], A:[M,K] bf16 row-major, B:[N,K] bf16 row-major.
// EPI: 0 = f32 store, 1 = bf16 store, 2 = f32 Src+acc store,
//      3 = bf16 store of acc * decay_mask(m,n),
//      4 = f32 store of softplus(acc + Src[n])   (Src = bias)
// TRI: 1 = skip blocks with n0 > m0; 2 = cap K at m0+128 (A upper-tri zero)
template<int EPI, int SWZ = 0, int TRI = 0>
__global__ __launch_bounds__(256)
void mfma_nt_kernel(const u16* __restrict__ A, int lda, long long sA,
                    const u16* __restrict__ B, int ldb, long long sB,
                    float* __restrict__ Cf, u16* __restrict__ Cb, int ldc, long long sC,
                    int K, const float* __restrict__ Src)
{
    __shared__ u16 As[128 * 64];
    __shared__ u16 Bs[128 * 64];
    int bz = blockIdx.z;
    A += (size_t)bz * sA; B += (size_t)bz * sB;
    if (EPI == 1 || EPI == 3) Cb += (size_t)bz * sC; else Cf += (size_t)bz * sC;
    if (EPI == 2) Src += (size_t)bz * sC;
    int bx = blockIdx.x, by = blockIdx.y;
    if (SWZ) {
        int gx = gridDim.x;
        int nwg = gx * gridDim.y;
        int flat = by * gx + bx;
        int swz = (flat & 7) * (nwg >> 3) + (flat >> 3);
        bx = swz % gx; by = swz / gx;
    }
    int m0 = by * 128, n0 = bx * 128;
    if (TRI == 1 && n0 > m0) return;
    int t = threadIdx.x;
    int lane = t & 63, w = t >> 6;
    int wm = (w >> 1) * 64, wn = (w & 1) * 64;
    int l15 = lane & 15, lhi = lane >> 4;

    int lrow = lane >> 3;                                   // 0..7
    int scol = ((lane & 7) ^ lrow) << 3;                    // pre-swizzled source col (u16)

    f32x4 acc[4][4] = {};
    int Keff = (TRI == 2) ? (m0 + 128 < K ? m0 + 128 : K) : K;
    const int nk = Keff >> 6;

    for (int kt = 0; kt < nk; ++kt) {
        int kb = kt << 6;
        #pragma unroll
        for (int q = 0; q < 4; ++q) {
            int c = (q << 2) + w;                           // chunk 0..15
            int row = (c << 3) + lrow;
            GLL16(A + (size_t)(m0 + row) * lda + kb + scol, &As[c << 9]);
            GLL16(B + (size_t)(n0 + row) * ldb + kb + scol, &Bs[c << 9]);
        }
        __syncthreads();
        #pragma unroll
        for (int ks = 0; ks < 2; ++ks) {
            int csw = (ks * 32 + lhi * 8) ^ ((l15 & 7) << 3);  // swizzled u16 col
            bf16x8 af[4], bfr[4];
            #pragma unroll
            for (int f = 0; f < 4; ++f) {
                af[f]  = *(const bf16x8*)&As[(wm + f*16 + l15) * 64 + csw];
                bfr[f] = *(const bf16x8*)&Bs[(wn + f*16 + l15) * 64 + csw];
            }
            #pragma unroll
            for (int i = 0; i < 4; ++i)
                #pragma unroll
                for (int j = 0; j < 4; ++j)
                    acc[i][j] = __builtin_amdgcn_mfma_f32_16x16x32_bf16(
                                    af[i], bfr[j], acc[i][j], 0, 0, 0);
        }
        __syncthreads();
    }
    int rb0 = m0 + wm + lhi * 4;
    int cb0 = n0 + wn + l15;
    #pragma unroll
    for (int mf = 0; mf < 4; ++mf) {
        #pragma unroll
        for (int nf = 0; nf < 4; ++nf) {
            #pragma unroll
            for (int i = 0; i < 4; ++i) {
                int r = rb0 + mf * 16 + i;
                int cc = cb0 + nf * 16;
                float v = acc[mf][nf][i];
                if (EPI == 0) {
                    Cf[(size_t)r * ldc + cc] = v;
                } else if (EPI == 1) {
                    Cb[(size_t)r * ldc + cc] = f2b(v);
                } else if (EPI == 2) {
                    Cf[(size_t)r * ldc + cc] = Src[(size_t)r * ldc + cc] + v;
                } else if (EPI == 4) {
                    float xv = v + Src[cc];
                    Cf[(size_t)r * ldc + cc] = fmaxf(xv, 0.0f) + log1pf(expf(-fabsf(xv)));
                } else {
                    float wv = (cc < r) ? ETA_C * exp2f((float)(r - 1 - cc) * LOG2_DECAY) : 0.0f;
                    Cb[(size_t)r * ldc + cc] = f2b(v * wv);
                }
            }
        }
    }
}

extern "C" void kernel_launch(void* const* d_in, const int* in_sizes, int n_in,
                              void* d_out, int out_size, void* d_ws, size_t ws_size,
                              hipStream_t stream)
{
    const float* x        = (const float*)d_in[0];
    const float* norm_w   = (const float*)d_in[1];
    const float* in_proj  = (const float*)d_in[2];
    const float* conv_w   = (const float*)d_in[3];
    const float* conv_b   = (const float*)d_in[4];
    const float* x_proj   = (const float*)d_in[5];
    const float* dt_projw = (const float*)d_in[6];
    const float* dt_projb = (const float*)d_in[7];
    const float* A_log    = (const float*)d_in[8];
    const float* D_param  = (const float*)d_in[9];
    const float* out_proj = (const float*)d_in[10];
    const float* hebb_w   = (const float*)d_in[11];
    const float* Wk       = (const float*)d_in[12];
    const float* Wv       = (const float*)d_in[13];
    float* out = (float*)d_out;

    // ---- workspace layout (float units, M1 = 1Mi floats) ----
    // [0,1M): xnb bf16 head -> later opb; [1M,2M): xnb tail (dead after step 3)
    // [2M,10M): xzb bf16 [4096][4096] (dead after scanC_gate)
    //   then: xnb2 [2M,4M) | kvb16 [4M,8M) | vT16 [8M,10M)
    // [10M,14M): PCbuf float2 (scanA->scanB) -> then scb16 bf16 [10M,14M)
    // [14M,16M): hst f32 (scanB->scanC) -> then wkvT bf16 [14M,15M)
    // [18M,26M): u f32
    // [26M,26.5M): xdbl f32
    // [26.5M,34.5M): dtb f32 (ipb bf16 before dt written)
    // [34.5M,37.5M): pbuf (split-K partials) / xdb16+dtw16 -> then ybb bf16 [34.5M,38.5M)
    float* ws = (float*)d_ws;
    const size_t M1 = 1024 * 1024;
    u16*   xnb  = (u16*)ws;
    u16*   opb  = (u16*)ws;
    u16*   xzb  = (u16*)(ws + 2*M1);
    u16*   xnb2 = (u16*)(ws + 2*M1);
    u16*   kvb16= (u16*)(ws + 4*M1);                 // [4096][2048] bf16
    u16*   vT16 = (u16*)(ws + 8*M1);                 // [B][1024][2048]
    float2* PCbuf = (float2*)(ws + 10*M1);           // 2M float2
    u16*   scb16= (u16*)(ws + 10*M1);                // [B][2048][2048] bf16
    float* hst  = ws + 14*M1;                        // 2M floats
    u16*   wkvT = (u16*)(ws + 14*M1);                // [2048][1024] bf16
    float* ubuf = ws + 18*M1;
    float* xdbl = ws + 26*M1;
    float* dtb  = ws + 26*M1 + M1/2;
    u16*   ipb  = (u16*)dtb;
    float* pbuf = ws + 34*M1 + M1/2;                 // 3M floats
    u16*   xdb16 = (u16*)(ws + 34*M1 + M1/2);        // 256K u16
    u16*   dtw16 = (u16*)(ws + 34*M1 + M1/2 + 128*1024);  // 128K u16
    u16*   ybb  = (u16*)(ws + 34*M1 + M1/2);         // [4096][2048] bf16 (4M floats)
    size_t need = (40*M1 + M1/2) * sizeof(float);    // 162 MiB
    if (ws_size < need) return;

    dim3 blk(256);
    const long long LD  = (long long)SEQ_L * D_MODEL;   // 2M
    const long long LL  = (long long)SEQ_L * SEQ_L;     // 4M
    const int NXP = MTOK * 96;                          // 393216

    // 1. xnb = bf16(rmsnorm(x))
    rmsnorm_b_kernel<<<MTOK, blk, 0, stream>>>(x, norm_w, xnb);
    // 2. ipb = bf16(in_proj_w)
    cvt_bf16_kernel<<<(2*DINNER*D_MODEL/4 + 255)/256, blk, 0, stream>>>(in_proj, ipb, 2*DINNER*D_MODEL/4);
    // 3. xzb = bf16(xnb @ ipb^T)  [4096x4096, K=1024]
    mfma_nt_kernel<1><<<dim3(32, 32, 1), blk, 0, stream>>>(
        xnb, D_MODEL, 0, ipb, D_MODEL, 0, nullptr, xzb, 2*DINNER, 0, D_MODEL, nullptr);
    // 4. u = silu(conv(xm)+b)
    conv_silu_kernel<<<(MTOK*DINNER/4)/256, blk, 0, stream>>>(xzb, conv_w, conv_b, ubuf);
    // 5. xdbl = u @ x_proj^T  [4096x96, K=2048] f32, split-K 8 -> reduce
    gemm_kernel<1,0><<<dim3(2, MTOK/BM, 8), blk, 0, stream>>>(
        ubuf, DINNER, x_proj, DINNER, pbuf, 96, MTOK, 96, DINNER/8, nullptr, (long long)NXP);
    reduce8_kernel<<<(NXP + 255)/256, blk, 0, stream>>>(pbuf, xdbl, NXP);
    // 6. dt = softplus(xdbl[:,:64] @ dt_proj^T + b) via bf16 MFMA
    cvt_bf16_kernel<<<(DINNER*DTRANK/4 + 255)/256, blk, 0, stream>>>(dt_projw, dtw16, DINNER*DTRANK/4);
    cvt_slice64_kernel<<<(MTOK*16)/256, blk, 0, stream>>>(xdbl, xdb16);
    mfma_nt_kernel<4><<<dim3(DINNER/128, MTOK/128, 1), blk, 0, stream>>>(
        xdb16, DTRANK, 0, dtw16, DTRANK, 0, dtb, nullptr, DINNER, 0, DTRANK, dt_projb);
    // 7. chunked selective scan; pass C fused with gate -> ybb bf16
    scanA_kernel<<<dim3(16, NCHUNK), blk, 0, stream>>>(dtb, ubuf, xdbl, A_log, PCbuf);
    scanB_kernel<<<256, blk, 0, stream>>>(PCbuf, hst);
    scanC_gate_kernel<<<dim3(16, NCHUNK), blk, 0, stream>>>(
        dtb, ubuf, xdbl, A_log, hst, D_param, xzb, ybb);
    // 8b. opb = bf16(out_proj_w); wkvT = bf16([Wk|Wv]^T) (k rows 0..1023, v rows 1024..2047)
    cvt_bf16_kernel<<<(D_MODEL*DINNER/4 + 255)/256, blk, 0, stream>>>(out_proj, opb, D_MODEL*DINNER/4);
    transpose_b16_kernel<float><<<dim3(32, 32, 1), blk, 0, stream>>>(Wk, wkvT, D_MODEL, D_MODEL, 0, 0);
    transpose_b16_kernel<float><<<dim3(32, 32, 1), blk, 0, stream>>>(Wv, wkvT + (size_t)D_MODEL*D_MODEL, D_MODEL, D_MODEL, 0, 0);
    // 9. out = x + ybb @ opb^T  [4096x1024, K=2048]
    mfma_nt_kernel<2><<<dim3(8, 32, 1), blk, 0, stream>>>(
        ybb, DINNER, 0, opb, DINNER, 0, out, nullptr, D_MODEL, 0, DINNER, x);
    // 10. xnb2 = bf16(rmsnorm(out))
    rmsnorm_b_kernel<<<MTOK, blk, 0, stream>>>(out, hebb_w, xnb2);
    // 11. kvb16 = xnb2 @ wkvT^T  (= [xn@Wk | xn@Wv])  [4096x2048, K=1024]
    mfma_nt_kernel<1><<<dim3(16, 32, 1), blk, 0, stream>>>(
        xnb2, D_MODEL, 0, wkvT, D_MODEL, 0, nullptr, kvb16, 2*D_MODEL, 0, D_MODEL, nullptr);
    // 13. vT16[b] = v[b]^T  (v = kvb16 cols 1024..2047; [2048x1024] -> [1024x2048])
    transpose_b16_kernel<u16><<<dim3(32, 64, BATCH), blk, 0, stream>>>(
        kvb16 + D_MODEL, vT16, 2*D_MODEL, SEQ_L, LL, LD);
    // 14. scb16[b] = decay_mask .* (xnb2[b] @ k[b]^T), lower-tri tiles only
    mfma_nt_kernel<3,0,1><<<dim3(16, 16, BATCH), blk, 0, stream>>>(
        xnb2, D_MODEL, LD, kvb16, 2*D_MODEL, LL, nullptr, scb16, SEQ_L, LL, D_MODEL, nullptr);
    // 15. out[b] += scb16[b] @ vT16[b]^T, K capped at m0+128
    mfma_nt_kernel<2,0,2><<<dim3(8, 16, BATCH), blk, 0, stream>>>(
        scb16, SEQ_L, LL, vT16, SEQ_L, LD, out, nullptr, D_MODEL, LD, SEQ_L, out);
}